// Round 1
// baseline (222.126 us; speedup 1.0000x reference)
//
#include <hip/hip_runtime.h>
#include <cstddef>

// Problem constants (B,C,H,W)=(4,32,64,64), D_STATE=16, D_CONV=4
// Mamba1: L=4096, d_model=128, d_in=256, dt_rank=8, xdbl width 40
// Mamba2: L=32,  d_model=2,   d_in=4,   dt_rank=1, xdbl width 33

__device__ __forceinline__ float siluf(float x) { return x / (1.f + __expf(-x)); }
__device__ __forceinline__ float softplusf(float x) { return (x > 20.f) ? x : log1pf(__expf(x)); }

// ---------------- K0: build fop (B, L, 128) from fo1 (B,C,H,W) ----------------
__global__ __launch_bounds__(256) void k_build_fop(const float* __restrict__ fo1,
                                                   float* __restrict__ fop) {
  int idx = blockIdx.x * 256 + threadIdx.x;   // total 4*4096*128 = 2^21
  int j = idx & 127;
  int l = (idx >> 7) & 4095;
  int b = idx >> 19;
  int g = j >> 5, c = j & 31;
  const float* base = fo1 + (size_t)(b * 32 + c) * 4096;
  int li;
  if (g == 0)      li = l;
  else if (g == 1) li = 4095 - l;
  else if (g == 2) li = ((l & 63) << 6) + (l >> 6);            // (h=l%64)*64 + l/64
  else { int i2 = 4095 - l; li = ((i2 & 63) << 6) + (i2 >> 6); }
  fop[idx] = base[li];
}

// ---------------- generic fp32 GEMM: C[M,N] = A[M,K](lda) @ W[N,K]^T ----------------
// block 256 threads, tile 64x64, BK=32, 4x4 per thread
__global__ __launch_bounds__(256) void k_gemm_nt(const float* __restrict__ A,
                                                 const float* __restrict__ W,
                                                 float* __restrict__ C,
                                                 int M, int N, int K, int lda) {
  __shared__ float As[32][68];
  __shared__ float Ws[32][68];
  int tid = threadIdx.x;
  int bm = blockIdx.x * 64;
  int bn = blockIdx.y * 64;
  int tx = tid & 15, ty = tid >> 4;
  float acc[4][4] = {};
  for (int k0 = 0; k0 < K; k0 += 32) {
#pragma unroll
    for (int it = 0; it < 2; ++it) {
      int idx = tid + it * 256;     // 512 float4 loads per tile
      int r = idx >> 3;             // 0..63
      int kq = idx & 7;             // 0..7 -> k = kq*4..kq*4+3
      float4 v = *(const float4*)&A[(size_t)(bm + r) * lda + k0 + kq * 4];
      As[kq * 4 + 0][r] = v.x; As[kq * 4 + 1][r] = v.y;
      As[kq * 4 + 2][r] = v.z; As[kq * 4 + 3][r] = v.w;
      int n = bn + r;
      float4 w = make_float4(0.f, 0.f, 0.f, 0.f);
      if (n < N) w = *(const float4*)&W[(size_t)n * K + k0 + kq * 4];
      Ws[kq * 4 + 0][r] = w.x; Ws[kq * 4 + 1][r] = w.y;
      Ws[kq * 4 + 2][r] = w.z; Ws[kq * 4 + 3][r] = w.w;
    }
    __syncthreads();
#pragma unroll
    for (int k = 0; k < 32; ++k) {
      float4 a = *(const float4*)&As[k][ty * 4];
      float4 w = *(const float4*)&Ws[k][tx * 4];
      float av[4] = {a.x, a.y, a.z, a.w};
      float wv[4] = {w.x, w.y, w.z, w.w};
#pragma unroll
      for (int i = 0; i < 4; ++i)
#pragma unroll
        for (int j = 0; j < 4; ++j)
          acc[i][j] = fmaf(av[i], wv[j], acc[i][j]);
    }
    __syncthreads();
  }
#pragma unroll
  for (int i = 0; i < 4; ++i) {
    size_t m = bm + ty * 4 + i;
#pragma unroll
    for (int j = 0; j < 4; ++j) {
      int n = bn + tx * 4 + j;
      if (n < N) C[m * N + n] = acc[i][j];
    }
  }
}

// ---------------- K2: causal depthwise conv(K=4) + silu -> xa (B,L,256) ----------------
__global__ __launch_bounds__(256) void k_conv_silu(const float* __restrict__ xz,
                                                   const float* __restrict__ convw,
                                                   const float* __restrict__ convb,
                                                   float* __restrict__ xa) {
  int row = blockIdx.x;        // b*L + l
  int l = row & 4095;
  int d = threadIdx.x;
  float4 w = *(const float4*)&convw[d * 4];
  float acc = convb[d];
  const float* p = xz + (size_t)row * 512 + d;   // xc = xz[..., :256]
  if (l >= 3) acc = fmaf(w.x, p[-3 * 512], acc);
  if (l >= 2) acc = fmaf(w.y, p[-2 * 512], acc);
  if (l >= 1) acc = fmaf(w.z, p[-1 * 512], acc);
  acc = fmaf(w.w, p[0], acc);
  xa[(size_t)row * 256 + d] = siluf(acc);
}

// ---------------- K3: dt = softplus(xdbl[:, :8] @ Wdt^T + dtb) ----------------
__global__ __launch_bounds__(256) void k_dt(const float* __restrict__ xdbl,
                                            const float* __restrict__ Wdt,
                                            const float* __restrict__ dtb,
                                            float* __restrict__ dt) {
  int row = blockIdx.x;
  int d = threadIdx.x;
  const float* xr = xdbl + (size_t)row * 40;
  float4 x0 = *(const float4*)xr;
  float4 x1 = *(const float4*)(xr + 4);
  float4 w0 = *(const float4*)&Wdt[d * 8];
  float4 w1 = *(const float4*)&Wdt[d * 8 + 4];
  float s = dtb[d];
  s = fmaf(x0.x, w0.x, s); s = fmaf(x0.y, w0.y, s);
  s = fmaf(x0.z, w0.z, s); s = fmaf(x0.w, w0.w, s);
  s = fmaf(x1.x, w1.x, s); s = fmaf(x1.y, w1.y, s);
  s = fmaf(x1.z, w1.z, s); s = fmaf(x1.w, w1.w, s);
  dt[(size_t)row * 256 + d] = softplusf(s);
}

// ---------------- scan: chunked (64 chunks x 64 steps), 4 n-states/thread ----------------
// thread: (b, d, ngroup); block 256 = 64 d x 4 ng; grid = 4b * 64ch * 4dblk
__global__ __launch_bounds__(256) void k_scan_p1(const float* __restrict__ dt,
                                                 const float* __restrict__ xa,
                                                 const float* __restrict__ xdbl,
                                                 const float* __restrict__ Alog,
                                                 float* __restrict__ Pb,
                                                 float* __restrict__ Qb) {
  int tid = threadIdx.x;
  int blk = blockIdx.x;
  int dblk = blk & 3, ch = (blk >> 2) & 63, b = blk >> 8;
  int dl = tid >> 2, ng = tid & 3;
  int d = dblk * 64 + dl, n0 = ng * 4;
  float4 al = *(const float4*)&Alog[d * 16 + n0];
  float A0 = -__expf(al.x), A1 = -__expf(al.y), A2 = -__expf(al.z), A3 = -__expf(al.w);
  float P0 = 1.f, P1 = 1.f, P2 = 1.f, P3 = 1.f;
  float Q0 = 0.f, Q1 = 0.f, Q2 = 0.f, Q3 = 0.f;
  size_t row = (size_t)b * 4096 + ch * 64;
  const float* dtp = dt + row * 256 + d;
  const float* xap = xa + row * 256 + d;
  const float* bmp = xdbl + row * 40 + 8 + n0;
#pragma unroll 4
  for (int s = 0; s < 64; ++s) {
    float dtv = dtp[s * 256];
    float xav = xap[s * 256];
    float4 bm = *(const float4*)(bmp + s * 40);
    float du = dtv * xav;
    float e0 = __expf(dtv * A0), e1 = __expf(dtv * A1);
    float e2 = __expf(dtv * A2), e3 = __expf(dtv * A3);
    Q0 = fmaf(e0, Q0, du * bm.x); P0 *= e0;
    Q1 = fmaf(e1, Q1, du * bm.y); P1 *= e1;
    Q2 = fmaf(e2, Q2, du * bm.z); P2 *= e2;
    Q3 = fmaf(e3, Q3, du * bm.w); P3 *= e3;
  }
  size_t o = (((size_t)b * 256 + d) * 64 + ch) * 16 + n0;
  *(float4*)&Pb[o] = make_float4(P0, P1, P2, P3);
  *(float4*)&Qb[o] = make_float4(Q0, Q1, Q2, Q3);
}

__global__ __launch_bounds__(256) void k_scan_p2(const float* __restrict__ Pb,
                                                 const float* __restrict__ Qb,
                                                 float* __restrict__ Hin) {
  int t = blockIdx.x * 256 + threadIdx.x;   // 4096 = 4b * 256d * 4ng
  if (t >= 4096) return;
  int ng = t & 3, d = (t >> 2) & 255, b = t >> 10;
  int n0 = ng * 4;
  float h0 = 0.f, h1 = 0.f, h2 = 0.f, h3 = 0.f;
  size_t base = (((size_t)b * 256 + d) * 64) * 16 + n0;
  for (int ch = 0; ch < 64; ++ch) {
    size_t o = base + (size_t)ch * 16;
    *(float4*)&Hin[o] = make_float4(h0, h1, h2, h3);
    float4 p = *(const float4*)&Pb[o];
    float4 q = *(const float4*)&Qb[o];
    h0 = fmaf(p.x, h0, q.x); h1 = fmaf(p.y, h1, q.y);
    h2 = fmaf(p.z, h2, q.z); h3 = fmaf(p.w, h3, q.w);
  }
}

// P3: recompute with known chunk-entry state; writes ym in-place into xz[..., :256]
__global__ __launch_bounds__(256) void k_scan_p3(const float* __restrict__ dt,
                                                 const float* __restrict__ xa,
                                                 const float* __restrict__ xdbl,
                                                 const float* __restrict__ Alog,
                                                 const float* __restrict__ Hin,
                                                 const float* __restrict__ Dp,
                                                 float* __restrict__ xz) {
  int tid = threadIdx.x;
  int blk = blockIdx.x;
  int dblk = blk & 3, ch = (blk >> 2) & 63, b = blk >> 8;
  int dl = tid >> 2, ng = tid & 3;
  int d = dblk * 64 + dl, n0 = ng * 4;
  float4 al = *(const float4*)&Alog[d * 16 + n0];
  float A0 = -__expf(al.x), A1 = -__expf(al.y), A2 = -__expf(al.z), A3 = -__expf(al.w);
  size_t o = (((size_t)b * 256 + d) * 64 + ch) * 16 + n0;
  float4 h = *(const float4*)&Hin[o];
  float Dd = Dp[d];
  size_t row = (size_t)b * 4096 + ch * 64;
  const float* dtp = dt + row * 256 + d;
  const float* xap = xa + row * 256 + d;
  const float* bmp = xdbl + row * 40 + 8 + n0;
  const float* cmp = xdbl + row * 40 + 24 + n0;
  const float* zp  = xz + row * 512 + 256 + d;
  float* wp        = xz + row * 512 + d;
#pragma unroll 4
  for (int s = 0; s < 64; ++s) {
    float dtv = dtp[s * 256];
    float xav = xap[s * 256];
    float4 bm = *(const float4*)(bmp + s * 40);
    float4 cm = *(const float4*)(cmp + s * 40);
    float du = dtv * xav;
    float e0 = __expf(dtv * A0), e1 = __expf(dtv * A1);
    float e2 = __expf(dtv * A2), e3 = __expf(dtv * A3);
    h.x = fmaf(e0, h.x, du * bm.x);
    h.y = fmaf(e1, h.y, du * bm.y);
    h.z = fmaf(e2, h.z, du * bm.z);
    h.w = fmaf(e3, h.w, du * bm.w);
    float yp = h.x * cm.x + h.y * cm.y + h.z * cm.z + h.w * cm.w;
    yp += __shfl_xor(yp, 1);
    yp += __shfl_xor(yp, 2);
    if (ng == 0) {
      float z = zp[s * 512];
      float y = yp + Dd * xav;
      wp[s * 512] = y * siluf(z);
    }
  }
}

// ---------------- WoutEff[c,d] = sum_g Wout[g*32+c, d] ----------------
__global__ __launch_bounds__(256) void k_wouteff(const float* __restrict__ Wout,
                                                 float* __restrict__ We) {
  int i = blockIdx.x * 256 + threadIdx.x;  // 8192
  int c = i >> 8, d = i & 255;
  We[i] = Wout[(size_t)c * 256 + d] + Wout[(size_t)(c + 32) * 256 + d] +
          Wout[(size_t)(c + 64) * 256 + d] + Wout[(size_t)(c + 96) * 256 + d];
}

// ---------------- residual (B,C,HW) = out1[b,l,c] * fo2 ----------------
__global__ __launch_bounds__(256) void k_residual(const float* __restrict__ out1,
                                                  const float* __restrict__ fo2,
                                                  float* __restrict__ res) {
  int idx = blockIdx.x * 256 + threadIdx.x;   // 524288
  int l = idx & 4095;
  int c = (idx >> 12) & 31;
  int b = idx >> 17;
  res[idx] = out1[((size_t)b * 4096 + l) * 32 + c] * fo2[idx];
}

// ---------------- foc[b,c] = mean over HW ----------------
__global__ __launch_bounds__(256) void k_foc(const float* __restrict__ res,
                                             float* __restrict__ foc) {
  int bc = blockIdx.x;
  int t = threadIdx.x;
  const float* p = res + (size_t)bc * 4096;
  float s = 0.f;
  for (int i = t; i < 4096; i += 256) s += p[i];
  __shared__ float red[256];
  red[t] = s;
  __syncthreads();
  for (int off = 128; off > 0; off >>= 1) {
    if (t < off) red[t] += red[t + off];
    __syncthreads();
  }
  if (t == 0) foc[bc] = red[0] * (1.f / 4096.f);
}

// ---------------- mamba2 (tiny): one block, 256 threads ----------------
__global__ __launch_bounds__(256) void k_mamba2(const float* __restrict__ foc,
                                                const float* __restrict__ Win2,
                                                const float* __restrict__ convw2,
                                                const float* __restrict__ convb2,
                                                const float* __restrict__ Wx2,
                                                const float* __restrict__ Wdt2,
                                                const float* __restrict__ dtb2,
                                                const float* __restrict__ Alog2,
                                                const float* __restrict__ D2,
                                                const float* __restrict__ Wout2,
                                                float* __restrict__ scale) {
  __shared__ float foc_s[128];
  __shared__ float xz2_s[4][32][8];
  __shared__ float xa2_s[4][32][4];
  __shared__ float xdbl2_s[4][32][33];
  __shared__ float dt2_s[4][32][4];
  __shared__ float ym2_s[4][32][4];
  int t = threadIdx.x;
  if (t < 128) foc_s[t] = foc[t];
  __syncthreads();
  // xz2 = x2 @ Win2^T ; x2[b,l,0]=foc[b,l], x2[b,l,1]=foc[b,31-l]
  for (int i = t; i < 1024; i += 256) {
    int j = i & 7, l = (i >> 3) & 31, b = i >> 8;
    float x0 = foc_s[b * 32 + l], x1 = foc_s[b * 32 + 31 - l];
    xz2_s[b][l][j] = x0 * Win2[j * 2] + x1 * Win2[j * 2 + 1];
  }
  __syncthreads();
  // conv + silu on xc2 = xz2[..., :4]
  for (int i = t; i < 512; i += 256) {
    int d = i & 3, l = (i >> 2) & 31, b = i >> 7;
    float acc = convb2[d];
#pragma unroll
    for (int k = 0; k < 4; ++k) {
      int ls = l + k - 3;
      if (ls >= 0) acc = fmaf(convw2[d * 4 + k], xz2_s[b][ls][d], acc);
    }
    xa2_s[b][l][d] = siluf(acc);
  }
  __syncthreads();
  // xdbl2 = xa2 @ Wx2^T  (33 outputs)
  for (int i = t; i < 4224; i += 256) {
    int r = i % 33, l = (i / 33) & 31, b = i / 1056;
    float s = 0.f;
#pragma unroll
    for (int d = 0; d < 4; ++d) s = fmaf(xa2_s[b][l][d], Wx2[r * 4 + d], s);
    xdbl2_s[b][l][r] = s;
  }
  __syncthreads();
  // dt2 = softplus(xdbl2[...,0] * Wdt2 + dtb2)
  for (int i = t; i < 512; i += 256) {
    int d = i & 3, l = (i >> 2) & 31, b = i >> 7;
    float s = xdbl2_s[b][l][0] * Wdt2[d] + dtb2[d];
    dt2_s[b][l][d] = softplusf(s);
  }
  __syncthreads();
  // scan: t = b*64 + d*16 + n (one wave per b)
  {
    int n = t & 15, d = (t >> 4) & 3, b = t >> 6;
    float A = -__expf(Alog2[d * 16 + n]);
    float h = 0.f;
    for (int l = 0; l < 32; ++l) {
      float dtv = dt2_s[b][l][d];
      float xav = xa2_s[b][l][d];
      float e = __expf(dtv * A);
      h = fmaf(e, h, dtv * xdbl2_s[b][l][1 + n] * xav);
      float yp = h * xdbl2_s[b][l][17 + n];
      yp += __shfl_xor(yp, 1);
      yp += __shfl_xor(yp, 2);
      yp += __shfl_xor(yp, 4);
      yp += __shfl_xor(yp, 8);
      if (n == 0) {
        float z = xz2_s[b][l][4 + d];
        float y = yp + D2[d] * xav;
        ym2_s[b][l][d] = y * siluf(z);
      }
    }
  }
  __syncthreads();
  // scale[b,l] = sum_d ym2 * (Wout2[0,d]+Wout2[1,d])
  if (t < 128) {
    int l = t & 31, b = t >> 5;
    float s = 0.f;
#pragma unroll
    for (int d = 0; d < 4; ++d) s = fmaf(ym2_s[b][l][d], Wout2[d] + Wout2[4 + d], s);
    scale[t] = s;
  }
}

// ---------------- final: out = residual * (1 + scale[b,c]) ----------------
__global__ __launch_bounds__(256) void k_final(const float* __restrict__ res,
                                               const float* __restrict__ scale,
                                               float* __restrict__ out) {
  int idx = blockIdx.x * 256 + threadIdx.x;
  out[idx] = res[idx] * (1.f + scale[idx >> 12]);
}

extern "C" void kernel_launch(void* const* d_in, const int* in_sizes, int n_in,
                              void* d_out, int out_size, void* d_ws, size_t ws_size,
                              hipStream_t stream) {
  const float* fo1    = (const float*)d_in[0];
  const float* fo2    = (const float*)d_in[1];
  const float* Win    = (const float*)d_in[2];
  const float* convw  = (const float*)d_in[3];
  const float* convb  = (const float*)d_in[4];
  const float* Wx     = (const float*)d_in[5];
  const float* Wdt    = (const float*)d_in[6];
  const float* dtb    = (const float*)d_in[7];
  const float* Alog   = (const float*)d_in[8];
  const float* Dp     = (const float*)d_in[9];
  const float* Wout   = (const float*)d_in[10];
  const float* Win2   = (const float*)d_in[11];
  const float* convw2 = (const float*)d_in[12];
  const float* convb2 = (const float*)d_in[13];
  const float* Wx2    = (const float*)d_in[14];
  const float* Wdt2   = (const float*)d_in[15];
  const float* dtb2   = (const float*)d_in[16];
  const float* Alog2  = (const float*)d_in[17];
  const float* D2     = (const float*)d_in[18];
  const float* Wout2  = (const float*)d_in[19];

  float* ws = (float*)d_ws;
  float* fop  = ws;                 // 2,097,152 floats (reused as xdbl after G1)
  float* xz   = ws + 2097152;       // 8,388,608  (xc | z); ym written over xc in P3
  float* xa   = ws + 10485760;      // 4,194,304
  float* dt   = ws + 14680064;      // 4,194,304
  float* Pb   = ws + 18874368;      // 1,048,576
  float* Qb   = ws + 19922944;      // 1,048,576
  float* Hin  = ws + 20971520;      // 1,048,576
  float* out1 = ws + 22020096;      //   524,288
  float* We   = ws + 22544384;      //     8,192
  float* res  = ws + 22552576;      //   524,288
  float* foc  = ws + 23076864;      //       128
  float* scl  = ws + 23076992;      //       128
  if (ws_size < (size_t)23077120 * sizeof(float)) return;  // need ~88 MB scratch
  float* xdbl = fop;

  hipLaunchKernelGGL(k_build_fop, dim3(8192), dim3(256), 0, stream, fo1, fop);
  hipLaunchKernelGGL(k_gemm_nt, dim3(256, 8), dim3(256), 0, stream,
                     fop, Win, xz, 16384, 512, 128, 128);
  hipLaunchKernelGGL(k_conv_silu, dim3(16384), dim3(256), 0, stream, xz, convw, convb, xa);
  hipLaunchKernelGGL(k_gemm_nt, dim3(256, 1), dim3(256), 0, stream,
                     xa, Wx, xdbl, 16384, 40, 256, 256);
  hipLaunchKernelGGL(k_dt, dim3(16384), dim3(256), 0, stream, xdbl, Wdt, dtb, dt);
  hipLaunchKernelGGL(k_scan_p1, dim3(1024), dim3(256), 0, stream, dt, xa, xdbl, Alog, Pb, Qb);
  hipLaunchKernelGGL(k_scan_p2, dim3(16), dim3(256), 0, stream, Pb, Qb, Hin);
  hipLaunchKernelGGL(k_scan_p3, dim3(1024), dim3(256), 0, stream, dt, xa, xdbl, Alog, Hin, Dp, xz);
  hipLaunchKernelGGL(k_wouteff, dim3(32), dim3(256), 0, stream, Wout, We);
  hipLaunchKernelGGL(k_gemm_nt, dim3(256, 1), dim3(256), 0, stream,
                     xz, We, out1, 16384, 32, 256, 512);
  hipLaunchKernelGGL(k_residual, dim3(2048), dim3(256), 0, stream, out1, fo2, res);
  hipLaunchKernelGGL(k_foc, dim3(128), dim3(256), 0, stream, res, foc);
  hipLaunchKernelGGL(k_mamba2, dim3(1), dim3(256), 0, stream, foc, Win2, convw2, convb2,
                     Wx2, Wdt2, dtb2, Alog2, D2, Wout2, scl);
  hipLaunchKernelGGL(k_final, dim3(2048), dim3(256), 0, stream, res, scl, (float*)d_out);
}

// Round 2
// 217.337 us; speedup vs baseline: 1.0220x; 1.0220x over previous
//
#include <hip/hip_runtime.h>
#include <cstddef>

// Problem constants (B,C,H,W)=(4,32,64,64), D_STATE=16, D_CONV=4
// Mamba1: L=4096, d_model=128, d_in=256, dt_rank=8, xdbl width 40
// Mamba2: L=32,  d_model=2,   d_in=4,   dt_rank=1, xdbl width 33
// Scan: chunked 3-phase, CHUNK=32 -> 128 chunks, full occupancy (524288 threads)

__device__ __forceinline__ float siluf(float x) { return x / (1.f + __expf(-x)); }
__device__ __forceinline__ float softplusf(float x) { return (x > 20.f) ? x : log1pf(__expf(x)); }

// ---------------- K0: build fop (B, L, 128) from fo1 (B,C,H,W) ----------------
__global__ __launch_bounds__(256) void k_build_fop(const float* __restrict__ fo1,
                                                   float* __restrict__ fop) {
  int idx = blockIdx.x * 256 + threadIdx.x;   // total 4*4096*128 = 2^21
  int j = idx & 127;
  int l = (idx >> 7) & 4095;
  int b = idx >> 19;
  int g = j >> 5, c = j & 31;
  const float* base = fo1 + (size_t)(b * 32 + c) * 4096;
  int li;
  if (g == 0)      li = l;
  else if (g == 1) li = 4095 - l;
  else if (g == 2) li = ((l & 63) << 6) + (l >> 6);            // (h=l%64)*64 + l/64
  else { int i2 = 4095 - l; li = ((i2 & 63) << 6) + (i2 >> 6); }
  fop[idx] = base[li];
}

// ---------------- generic fp32 GEMM: C[M,N] = A[M,K](lda) @ W[N,K]^T ----------------
__global__ __launch_bounds__(256) void k_gemm_nt(const float* __restrict__ A,
                                                 const float* __restrict__ W,
                                                 float* __restrict__ C,
                                                 int M, int N, int K, int lda) {
  __shared__ float As[32][68];
  __shared__ float Ws[32][68];
  int tid = threadIdx.x;
  int bm = blockIdx.x * 64;
  int bn = blockIdx.y * 64;
  int tx = tid & 15, ty = tid >> 4;
  float acc[4][4] = {};
  for (int k0 = 0; k0 < K; k0 += 32) {
#pragma unroll
    for (int it = 0; it < 2; ++it) {
      int idx = tid + it * 256;     // 512 float4 loads per tile
      int r = idx >> 3;             // 0..63
      int kq = idx & 7;             // 0..7 -> k = kq*4..kq*4+3
      float4 v = *(const float4*)&A[(size_t)(bm + r) * lda + k0 + kq * 4];
      As[kq * 4 + 0][r] = v.x; As[kq * 4 + 1][r] = v.y;
      As[kq * 4 + 2][r] = v.z; As[kq * 4 + 3][r] = v.w;
      int n = bn + r;
      float4 w = make_float4(0.f, 0.f, 0.f, 0.f);
      if (n < N) w = *(const float4*)&W[(size_t)n * K + k0 + kq * 4];
      Ws[kq * 4 + 0][r] = w.x; Ws[kq * 4 + 1][r] = w.y;
      Ws[kq * 4 + 2][r] = w.z; Ws[kq * 4 + 3][r] = w.w;
    }
    __syncthreads();
#pragma unroll
    for (int k = 0; k < 32; ++k) {
      float4 a = *(const float4*)&As[k][ty * 4];
      float4 w = *(const float4*)&Ws[k][tx * 4];
      float av[4] = {a.x, a.y, a.z, a.w};
      float wv[4] = {w.x, w.y, w.z, w.w};
#pragma unroll
      for (int i = 0; i < 4; ++i)
#pragma unroll
        for (int j = 0; j < 4; ++j)
          acc[i][j] = fmaf(av[i], wv[j], acc[i][j]);
    }
    __syncthreads();
  }
#pragma unroll
  for (int i = 0; i < 4; ++i) {
    size_t m = bm + ty * 4 + i;
#pragma unroll
    for (int j = 0; j < 4; ++j) {
      int n = bn + tx * 4 + j;
      if (n < N) C[m * N + n] = acc[i][j];
    }
  }
}

// ---------------- K2: causal depthwise conv(K=4) + silu -> xa (B,L,256) ----------------
__global__ __launch_bounds__(256) void k_conv_silu(const float* __restrict__ xz,
                                                   const float* __restrict__ convw,
                                                   const float* __restrict__ convb,
                                                   float* __restrict__ xa) {
  int row = blockIdx.x;        // b*L + l
  int l = row & 4095;
  int d = threadIdx.x;
  float4 w = *(const float4*)&convw[d * 4];
  float acc = convb[d];
  const float* p = xz + (size_t)row * 512 + d;   // xc = xz[..., :256]
  if (l >= 3) acc = fmaf(w.x, p[-3 * 512], acc);
  if (l >= 2) acc = fmaf(w.y, p[-2 * 512], acc);
  if (l >= 1) acc = fmaf(w.z, p[-1 * 512], acc);
  acc = fmaf(w.w, p[0], acc);
  xa[(size_t)row * 256 + d] = siluf(acc);
}

// ---------------- scan phase 1: per-chunk (P = prod dA, Q = chunk-local h) ----------------
// CHUNK=32; thread: (b, d, ngroup); block 256 = 64 d x 4 ng
// grid = b(4) * ch(128) * dblk(4) = 2048 blocks
// dt recomputed in-loop from xdbl[:, :8] (fused k_dt)
__global__ __launch_bounds__(256) void k_scan_p1(const float* __restrict__ xa,
                                                 const float* __restrict__ xdbl,
                                                 const float* __restrict__ Wdt,
                                                 const float* __restrict__ dtb,
                                                 const float* __restrict__ Alog,
                                                 float* __restrict__ Pb,
                                                 float* __restrict__ Qb) {
  int tid = threadIdx.x;
  int blk = blockIdx.x;
  int dblk = blk & 3, ch = (blk >> 2) & 127, b = blk >> 9;
  int dl = tid >> 2, ng = tid & 3;
  int d = dblk * 64 + dl, n0 = ng * 4;
  float4 al = *(const float4*)&Alog[d * 16 + n0];
  float A0 = -__expf(al.x), A1 = -__expf(al.y), A2 = -__expf(al.z), A3 = -__expf(al.w);
  float4 w0 = *(const float4*)&Wdt[d * 8];
  float4 w1 = *(const float4*)&Wdt[d * 8 + 4];
  float bias = dtb[d];
  float P0 = 1.f, P1 = 1.f, P2 = 1.f, P3 = 1.f;
  float Q0 = 0.f, Q1 = 0.f, Q2 = 0.f, Q3 = 0.f;
  size_t row = (size_t)b * 4096 + ch * 32;
  const float* xap = xa + row * 256 + d;
  const float* xr = xdbl + row * 40;
#pragma unroll 4
  for (int s = 0; s < 32; ++s) {
    float4 x0 = *(const float4*)(xr + s * 40);
    float4 x1 = *(const float4*)(xr + s * 40 + 4);
    float4 bm = *(const float4*)(xr + s * 40 + 8 + n0);
    float xav = xap[s * 256];
    float t = bias;
    t = fmaf(x0.x, w0.x, t); t = fmaf(x0.y, w0.y, t);
    t = fmaf(x0.z, w0.z, t); t = fmaf(x0.w, w0.w, t);
    t = fmaf(x1.x, w1.x, t); t = fmaf(x1.y, w1.y, t);
    t = fmaf(x1.z, w1.z, t); t = fmaf(x1.w, w1.w, t);
    float ex = __expf(t);
    float dtv = (t > 20.f) ? t : __logf(1.f + ex);
    float du = dtv * xav;
    float e0 = __expf(dtv * A0), e1 = __expf(dtv * A1);
    float e2 = __expf(dtv * A2), e3 = __expf(dtv * A3);
    Q0 = fmaf(e0, Q0, du * bm.x); P0 *= e0;
    Q1 = fmaf(e1, Q1, du * bm.y); P1 *= e1;
    Q2 = fmaf(e2, Q2, du * bm.z); P2 *= e2;
    Q3 = fmaf(e3, Q3, du * bm.w); P3 *= e3;
  }
  size_t o = (((size_t)b * 256 + d) * 128 + ch) * 16 + n0;
  *(float4*)&Pb[o] = make_float4(P0, P1, P2, P3);
  *(float4*)&Qb[o] = make_float4(Q0, Q1, Q2, Q3);
}

// ---------------- scan phase 2: serial combine over 128 chunks ----------------
__global__ __launch_bounds__(256) void k_scan_p2(const float* __restrict__ Pb,
                                                 const float* __restrict__ Qb,
                                                 float* __restrict__ Hin) {
  int t = blockIdx.x * 256 + threadIdx.x;   // 4096 = 4b * 256d * 4ng
  if (t >= 4096) return;
  int ng = t & 3, d = (t >> 2) & 255, b = t >> 10;
  int n0 = ng * 4;
  float h0 = 0.f, h1 = 0.f, h2 = 0.f, h3 = 0.f;
  size_t base = (((size_t)b * 256 + d) * 128) * 16 + n0;
  for (int ch = 0; ch < 128; ++ch) {
    size_t o = base + (size_t)ch * 16;
    *(float4*)&Hin[o] = make_float4(h0, h1, h2, h3);
    float4 p = *(const float4*)&Pb[o];
    float4 q = *(const float4*)&Qb[o];
    h0 = fmaf(p.x, h0, q.x); h1 = fmaf(p.y, h1, q.y);
    h2 = fmaf(p.z, h2, q.z); h3 = fmaf(p.w, h3, q.w);
  }
}

// ---------------- scan phase 3: recompute with chunk-entry state; ym -> xz[..., :256] ----------------
__global__ __launch_bounds__(256) void k_scan_p3(const float* __restrict__ xa,
                                                 const float* __restrict__ xdbl,
                                                 const float* __restrict__ Wdt,
                                                 const float* __restrict__ dtb,
                                                 const float* __restrict__ Alog,
                                                 const float* __restrict__ Hin,
                                                 const float* __restrict__ Dp,
                                                 float* __restrict__ xz) {
  int tid = threadIdx.x;
  int blk = blockIdx.x;
  int dblk = blk & 3, ch = (blk >> 2) & 127, b = blk >> 9;
  int dl = tid >> 2, ng = tid & 3;
  int d = dblk * 64 + dl, n0 = ng * 4;
  float4 al = *(const float4*)&Alog[d * 16 + n0];
  float A0 = -__expf(al.x), A1 = -__expf(al.y), A2 = -__expf(al.z), A3 = -__expf(al.w);
  float4 w0 = *(const float4*)&Wdt[d * 8];
  float4 w1 = *(const float4*)&Wdt[d * 8 + 4];
  float bias = dtb[d];
  size_t o = (((size_t)b * 256 + d) * 128 + ch) * 16 + n0;
  float4 h = *(const float4*)&Hin[o];
  float Dd = Dp[d];
  size_t row = (size_t)b * 4096 + ch * 32;
  const float* xap = xa + row * 256 + d;
  const float* xr = xdbl + row * 40;
  const float* zp  = xz + row * 512 + 256 + d;
  float* wp        = xz + row * 512 + d;
#pragma unroll 4
  for (int s = 0; s < 32; ++s) {
    float4 x0 = *(const float4*)(xr + s * 40);
    float4 x1 = *(const float4*)(xr + s * 40 + 4);
    float4 bm = *(const float4*)(xr + s * 40 + 8 + n0);
    float4 cm = *(const float4*)(xr + s * 40 + 24 + n0);
    float xav = xap[s * 256];
    float t = bias;
    t = fmaf(x0.x, w0.x, t); t = fmaf(x0.y, w0.y, t);
    t = fmaf(x0.z, w0.z, t); t = fmaf(x0.w, w0.w, t);
    t = fmaf(x1.x, w1.x, t); t = fmaf(x1.y, w1.y, t);
    t = fmaf(x1.z, w1.z, t); t = fmaf(x1.w, w1.w, t);
    float ex = __expf(t);
    float dtv = (t > 20.f) ? t : __logf(1.f + ex);
    float du = dtv * xav;
    float e0 = __expf(dtv * A0), e1 = __expf(dtv * A1);
    float e2 = __expf(dtv * A2), e3 = __expf(dtv * A3);
    h.x = fmaf(e0, h.x, du * bm.x);
    h.y = fmaf(e1, h.y, du * bm.y);
    h.z = fmaf(e2, h.z, du * bm.z);
    h.w = fmaf(e3, h.w, du * bm.w);
    float yp = h.x * cm.x + h.y * cm.y + h.z * cm.z + h.w * cm.w;
    yp += __shfl_xor(yp, 1);
    yp += __shfl_xor(yp, 2);
    if (ng == 0) {
      float z = zp[s * 512];
      float y = yp + Dd * xav;
      wp[s * 512] = y * siluf(z);
    }
  }
}

// ---------------- WoutEff[c,d] = sum_g Wout[g*32+c, d] ----------------
__global__ __launch_bounds__(256) void k_wouteff(const float* __restrict__ Wout,
                                                 float* __restrict__ We) {
  int i = blockIdx.x * 256 + threadIdx.x;  // 8192
  int c = i >> 8, d = i & 255;
  We[i] = Wout[(size_t)c * 256 + d] + Wout[(size_t)(c + 32) * 256 + d] +
          Wout[(size_t)(c + 64) * 256 + d] + Wout[(size_t)(c + 96) * 256 + d];
}

// ---------------- residual (B,C,HW) = out1[b,l,c] * fo2 ----------------
__global__ __launch_bounds__(256) void k_residual(const float* __restrict__ out1,
                                                  const float* __restrict__ fo2,
                                                  float* __restrict__ res) {
  int idx = blockIdx.x * 256 + threadIdx.x;   // 524288
  int l = idx & 4095;
  int c = (idx >> 12) & 31;
  int b = idx >> 17;
  res[idx] = out1[((size_t)b * 4096 + l) * 32 + c] * fo2[idx];
}

// ---------------- foc[b,c] = mean over HW ----------------
__global__ __launch_bounds__(256) void k_foc(const float* __restrict__ res,
                                             float* __restrict__ foc) {
  int bc = blockIdx.x;
  int t = threadIdx.x;
  const float* p = res + (size_t)bc * 4096;
  float s = 0.f;
  for (int i = t; i < 4096; i += 256) s += p[i];
  __shared__ float red[256];
  red[t] = s;
  __syncthreads();
  for (int off = 128; off > 0; off >>= 1) {
    if (t < off) red[t] += red[t + off];
    __syncthreads();
  }
  if (t == 0) foc[bc] = red[0] * (1.f / 4096.f);
}

// ---------------- mamba2 (tiny): one block, 256 threads ----------------
__global__ __launch_bounds__(256) void k_mamba2(const float* __restrict__ foc,
                                                const float* __restrict__ Win2,
                                                const float* __restrict__ convw2,
                                                const float* __restrict__ convb2,
                                                const float* __restrict__ Wx2,
                                                const float* __restrict__ Wdt2,
                                                const float* __restrict__ dtb2,
                                                const float* __restrict__ Alog2,
                                                const float* __restrict__ D2,
                                                const float* __restrict__ Wout2,
                                                float* __restrict__ scale) {
  __shared__ float foc_s[128];
  __shared__ float xz2_s[4][32][8];
  __shared__ float xa2_s[4][32][4];
  __shared__ float xdbl2_s[4][32][33];
  __shared__ float dt2_s[4][32][4];
  __shared__ float ym2_s[4][32][4];
  int t = threadIdx.x;
  if (t < 128) foc_s[t] = foc[t];
  __syncthreads();
  for (int i = t; i < 1024; i += 256) {
    int j = i & 7, l = (i >> 3) & 31, b = i >> 8;
    float x0 = foc_s[b * 32 + l], x1 = foc_s[b * 32 + 31 - l];
    xz2_s[b][l][j] = x0 * Win2[j * 2] + x1 * Win2[j * 2 + 1];
  }
  __syncthreads();
  for (int i = t; i < 512; i += 256) {
    int d = i & 3, l = (i >> 2) & 31, b = i >> 7;
    float acc = convb2[d];
#pragma unroll
    for (int k = 0; k < 4; ++k) {
      int ls = l + k - 3;
      if (ls >= 0) acc = fmaf(convw2[d * 4 + k], xz2_s[b][ls][d], acc);
    }
    xa2_s[b][l][d] = siluf(acc);
  }
  __syncthreads();
  for (int i = t; i < 4224; i += 256) {
    int r = i % 33, l = (i / 33) & 31, b = i / 1056;
    float s = 0.f;
#pragma unroll
    for (int d = 0; d < 4; ++d) s = fmaf(xa2_s[b][l][d], Wx2[r * 4 + d], s);
    xdbl2_s[b][l][r] = s;
  }
  __syncthreads();
  for (int i = t; i < 512; i += 256) {
    int d = i & 3, l = (i >> 2) & 31, b = i >> 7;
    float s = xdbl2_s[b][l][0] * Wdt2[d] + dtb2[d];
    dt2_s[b][l][d] = softplusf(s);
  }
  __syncthreads();
  {
    int n = t & 15, d = (t >> 4) & 3, b = t >> 6;
    float A = -__expf(Alog2[d * 16 + n]);
    float h = 0.f;
    for (int l = 0; l < 32; ++l) {
      float dtv = dt2_s[b][l][d];
      float xav = xa2_s[b][l][d];
      float e = __expf(dtv * A);
      h = fmaf(e, h, dtv * xdbl2_s[b][l][1 + n] * xav);
      float yp = h * xdbl2_s[b][l][17 + n];
      yp += __shfl_xor(yp, 1);
      yp += __shfl_xor(yp, 2);
      yp += __shfl_xor(yp, 4);
      yp += __shfl_xor(yp, 8);
      if (n == 0) {
        float z = xz2_s[b][l][4 + d];
        float y = yp + D2[d] * xav;
        ym2_s[b][l][d] = y * siluf(z);
      }
    }
  }
  __syncthreads();
  if (t < 128) {
    int l = t & 31, b = t >> 5;
    float s = 0.f;
#pragma unroll
    for (int d = 0; d < 4; ++d) s = fmaf(ym2_s[b][l][d], Wout2[d] + Wout2[4 + d], s);
    scale[t] = s;
  }
}

// ---------------- final: out = residual * (1 + scale[b,c]) ----------------
__global__ __launch_bounds__(256) void k_final(const float* __restrict__ res,
                                               const float* __restrict__ scale,
                                               float* __restrict__ out) {
  int idx = blockIdx.x * 256 + threadIdx.x;
  out[idx] = res[idx] * (1.f + scale[idx >> 12]);
}

extern "C" void kernel_launch(void* const* d_in, const int* in_sizes, int n_in,
                              void* d_out, int out_size, void* d_ws, size_t ws_size,
                              hipStream_t stream) {
  const float* fo1    = (const float*)d_in[0];
  const float* fo2    = (const float*)d_in[1];
  const float* Win    = (const float*)d_in[2];
  const float* convw  = (const float*)d_in[3];
  const float* convb  = (const float*)d_in[4];
  const float* Wx     = (const float*)d_in[5];
  const float* Wdt    = (const float*)d_in[6];
  const float* dtb    = (const float*)d_in[7];
  const float* Alog   = (const float*)d_in[8];
  const float* Dp     = (const float*)d_in[9];
  const float* Wout   = (const float*)d_in[10];
  const float* Win2   = (const float*)d_in[11];
  const float* convw2 = (const float*)d_in[12];
  const float* convb2 = (const float*)d_in[13];
  const float* Wx2    = (const float*)d_in[14];
  const float* Wdt2   = (const float*)d_in[15];
  const float* dtb2   = (const float*)d_in[16];
  const float* Alog2  = (const float*)d_in[17];
  const float* D2     = (const float*)d_in[18];
  const float* Wout2  = (const float*)d_in[19];

  float* ws = (float*)d_ws;
  float* fop  = ws;                 // 2,097,152 floats (reused as xdbl after G1)
  float* xz   = ws + 2097152;       // 8,388,608  (xc | z); ym written over xc in P3
  float* xa   = ws + 10485760;      // 4,194,304
  float* Pb   = ws + 14680064;      // 2,097,152
  float* Qb   = ws + 16777216;      // 2,097,152
  float* Hin  = ws + 18874368;      // 2,097,152
  float* out1 = ws + 20971520;      //   524,288
  float* We   = ws + 21495808;      //     8,192
  float* res  = ws + 21504000;      //   524,288
  float* foc  = ws + 22028288;      //       128
  float* scl  = ws + 22028416;      //       128
  if (ws_size < (size_t)22028544 * sizeof(float)) return;  // need ~84 MB scratch
  float* xdbl = fop;

  hipLaunchKernelGGL(k_build_fop, dim3(8192), dim3(256), 0, stream, fo1, fop);
  hipLaunchKernelGGL(k_gemm_nt, dim3(256, 8), dim3(256), 0, stream,
                     fop, Win, xz, 16384, 512, 128, 128);
  hipLaunchKernelGGL(k_conv_silu, dim3(16384), dim3(256), 0, stream, xz, convw, convb, xa);
  hipLaunchKernelGGL(k_gemm_nt, dim3(256, 1), dim3(256), 0, stream,
                     xa, Wx, xdbl, 16384, 40, 256, 256);
  hipLaunchKernelGGL(k_scan_p1, dim3(2048), dim3(256), 0, stream,
                     xa, xdbl, Wdt, dtb, Alog, Pb, Qb);
  hipLaunchKernelGGL(k_scan_p2, dim3(16), dim3(256), 0, stream, Pb, Qb, Hin);
  hipLaunchKernelGGL(k_scan_p3, dim3(2048), dim3(256), 0, stream,
                     xa, xdbl, Wdt, dtb, Alog, Hin, Dp, xz);
  hipLaunchKernelGGL(k_wouteff, dim3(32), dim3(256), 0, stream, Wout, We);
  hipLaunchKernelGGL(k_gemm_nt, dim3(256, 1), dim3(256), 0, stream,
                     xz, We, out1, 16384, 32, 256, 512);
  hipLaunchKernelGGL(k_residual, dim3(2048), dim3(256), 0, stream, out1, fo2, res);
  hipLaunchKernelGGL(k_foc, dim3(128), dim3(256), 0, stream, res, foc);
  hipLaunchKernelGGL(k_mamba2, dim3(1), dim3(256), 0, stream, foc, Win2, convw2, convb2,
                     Wx2, Wdt2, dtb2, Alog2, D2, Wout2, scl);
  hipLaunchKernelGGL(k_final, dim3(2048), dim3(256), 0, stream, res, scl, (float*)d_out);
}

// Round 3
// 191.352 us; speedup vs baseline: 1.1608x; 1.1358x over previous
//
#include <hip/hip_runtime.h>
#include <cstddef>

// (B,C,H,W)=(4,32,64,64), D_STATE=16, D_CONV=4
// Mamba1: L=4096, d_model=128, d_in=256, dt_rank=8, xdbl width 40
// Scan: chunked 3-phase, CHUNK=32 -> 128 chunks, LDS-resident inner loop

typedef __attribute__((ext_vector_type(8))) short short8v;
typedef __attribute__((ext_vector_type(4))) float f32x4;

__device__ __forceinline__ float siluf(float x) { return x / (1.f + __expf(-x)); }
__device__ __forceinline__ float softplusf(float x) { return (x > 20.f) ? x : log1pf(__expf(x)); }
__device__ __forceinline__ unsigned short f2bf(float f) {
  union { float f; unsigned int u; } v; v.f = f;
  unsigned int r = v.u + 0x7fff + ((v.u >> 16) & 1);
  return (unsigned short)(r >> 16);
}

// ---------------- K0: build fop (B, L, 128) bf16 from fo1 (B,C,H,W) ----------------
__global__ __launch_bounds__(256) void k_build_fop(const float* __restrict__ fo1,
                                                   unsigned short* __restrict__ fopb) {
  int idx = blockIdx.x * 256 + threadIdx.x;   // 2^21
  int j = idx & 127;
  int l = (idx >> 7) & 4095;
  int b = idx >> 19;
  int g = j >> 5, c = j & 31;
  const float* base = fo1 + (size_t)(b * 32 + c) * 4096;
  int li;
  if (g == 0)      li = l;
  else if (g == 1) li = 4095 - l;
  else if (g == 2) li = ((l & 63) << 6) + (l >> 6);
  else { int i2 = 4095 - l; li = ((i2 & 63) << 6) + (i2 >> 6); }
  fopb[idx] = f2bf(base[li]);
}

// ---------------- GEMM1: xz[16384][512] = fopb[16384][128] @ Win[512][128]^T (bf16 MFMA) ----
// block 256 = 4 waves; tile 128M x 64N; K=128 single LDS stage; wave tile 64x32
__global__ __launch_bounds__(256) void k_gemm1_mfma(const unsigned short* __restrict__ A,
                                                    const float* __restrict__ Win,
                                                    float* __restrict__ C) {
  __shared__ unsigned short As[128][136];   // pad 8 bf16 -> row 272B
  __shared__ unsigned short Bs[64][136];
  int t = threadIdx.x;
  int bm = blockIdx.x * 128, bn = blockIdx.y * 64;
#pragma unroll
  for (int it = 0; it < 8; ++it) {          // A: 128 rows x 16 chunks of 8 bf16
    int idx = t + it * 256;
    int r = idx >> 4, kc = idx & 15;
    short8v v = *(const short8v*)&A[(size_t)(bm + r) * 128 + kc * 8];
    *(short8v*)&As[r][kc * 8] = v;
  }
#pragma unroll
  for (int it = 0; it < 8; ++it) {          // B: 64 rows x 32 chunks of 4 fp32 -> bf16
    int idx = t + it * 256;
    int r = idx >> 5, kq = idx & 31;
    float4 w = *(const float4*)&Win[(size_t)(bn + r) * 128 + kq * 4];
    ushort4 h;
    h.x = f2bf(w.x); h.y = f2bf(w.y); h.z = f2bf(w.z); h.w = f2bf(w.w);
    *(ushort4*)&Bs[r][kq * 4] = h;
  }
  __syncthreads();
  int lane = t & 63, w = t >> 6;
  int wm = (w & 1) * 64, wn = (w >> 1) * 32;
  int lr = lane & 15, lg = lane >> 4;
  f32x4 acc[4][2] = {};
#pragma unroll
  for (int k0 = 0; k0 < 128; k0 += 32) {
    short8v a[4], b[2];
#pragma unroll
    for (int mf = 0; mf < 4; ++mf)
      a[mf] = *(const short8v*)&As[wm + mf * 16 + lr][k0 + lg * 8];
#pragma unroll
    for (int nf = 0; nf < 2; ++nf)
      b[nf] = *(const short8v*)&Bs[wn + nf * 16 + lr][k0 + lg * 8];
#pragma unroll
    for (int mf = 0; mf < 4; ++mf)
#pragma unroll
      for (int nf = 0; nf < 2; ++nf)
        acc[mf][nf] = __builtin_amdgcn_mfma_f32_16x16x32_bf16(a[mf], b[nf], acc[mf][nf], 0, 0, 0);
  }
#pragma unroll
  for (int mf = 0; mf < 4; ++mf)
#pragma unroll
    for (int nf = 0; nf < 2; ++nf)
#pragma unroll
      for (int r = 0; r < 4; ++r) {
        size_t row = bm + wm + mf * 16 + lg * 4 + r;
        C[row * 512 + bn + wn + nf * 16 + lr] = acc[mf][nf][r];
      }
}

// ---------------- generic fp32 GEMM (used for GEMM2): C[M,N] = A[M,K](lda) @ W[N,K]^T ----
__global__ __launch_bounds__(256) void k_gemm_nt(const float* __restrict__ A,
                                                 const float* __restrict__ W,
                                                 float* __restrict__ C,
                                                 int M, int N, int K, int lda) {
  __shared__ float As[32][68];
  __shared__ float Ws[32][68];
  int tid = threadIdx.x;
  int bm = blockIdx.x * 64;
  int bn = blockIdx.y * 64;
  int tx = tid & 15, ty = tid >> 4;
  float acc[4][4] = {};
  for (int k0 = 0; k0 < K; k0 += 32) {
#pragma unroll
    for (int it = 0; it < 2; ++it) {
      int idx = tid + it * 256;
      int r = idx >> 3;
      int kq = idx & 7;
      float4 v = *(const float4*)&A[(size_t)(bm + r) * lda + k0 + kq * 4];
      As[kq * 4 + 0][r] = v.x; As[kq * 4 + 1][r] = v.y;
      As[kq * 4 + 2][r] = v.z; As[kq * 4 + 3][r] = v.w;
      int n = bn + r;
      float4 w = make_float4(0.f, 0.f, 0.f, 0.f);
      if (n < N) w = *(const float4*)&W[(size_t)n * K + k0 + kq * 4];
      Ws[kq * 4 + 0][r] = w.x; Ws[kq * 4 + 1][r] = w.y;
      Ws[kq * 4 + 2][r] = w.z; Ws[kq * 4 + 3][r] = w.w;
    }
    __syncthreads();
#pragma unroll
    for (int k = 0; k < 32; ++k) {
      float4 a = *(const float4*)&As[k][ty * 4];
      float4 w = *(const float4*)&Ws[k][tx * 4];
      float av[4] = {a.x, a.y, a.z, a.w};
      float wv[4] = {w.x, w.y, w.z, w.w};
#pragma unroll
      for (int i = 0; i < 4; ++i)
#pragma unroll
        for (int j = 0; j < 4; ++j)
          acc[i][j] = fmaf(av[i], wv[j], acc[i][j]);
    }
    __syncthreads();
  }
#pragma unroll
  for (int i = 0; i < 4; ++i) {
    size_t m = bm + ty * 4 + i;
#pragma unroll
    for (int j = 0; j < 4; ++j) {
      int n = bn + tx * 4 + j;
      if (n < N) C[m * N + n] = acc[i][j];
    }
  }
}

// ---------------- conv K=4 causal + silu -> xa ----------------
__global__ __launch_bounds__(256) void k_conv_silu(const float* __restrict__ xz,
                                                   const float* __restrict__ convw,
                                                   const float* __restrict__ convb,
                                                   float* __restrict__ xa) {
  int row = blockIdx.x;
  int l = row & 4095;
  int d = threadIdx.x;
  float4 w = *(const float4*)&convw[d * 4];
  float acc = convb[d];
  const float* p = xz + (size_t)row * 512 + d;
  if (l >= 3) acc = fmaf(w.x, p[-3 * 512], acc);
  if (l >= 2) acc = fmaf(w.y, p[-2 * 512], acc);
  if (l >= 1) acc = fmaf(w.z, p[-1 * 512], acc);
  acc = fmaf(w.w, p[0], acc);
  xa[(size_t)row * 256 + d] = siluf(acc);
}

// ---------------- scan phase 1 (LDS-resident): P,Q per chunk ----------------
// block: (b, ch, dblk); 256 thr = 4 waves; lane = d4(0..15) | ng(2b); wave covers 16 d
__global__ __launch_bounds__(256) void k_scan_p1(const float* __restrict__ xa,
                                                 const float* __restrict__ xdbl,
                                                 const float* __restrict__ Wdt,
                                                 const float* __restrict__ dtb,
                                                 const float* __restrict__ Alog,
                                                 float* __restrict__ Pb,
                                                 float* __restrict__ Qb) {
  __shared__ float xrow[32][40];
  __shared__ float xas[32][64];
  __shared__ float dts[32][64];
  int t = threadIdx.x;
  int blk = blockIdx.x;
  int dblk = blk & 3, ch = (blk >> 2) & 127, b = blk >> 9;
  size_t row0 = (size_t)b * 4096 + ch * 32;
  // stage xdbl rows [32][40]
  for (int idx = t; idx < 320; idx += 256) {
    int s = idx / 10, q = idx - s * 10;
    *(float4*)&xrow[s][q * 4] = *(const float4*)&xdbl[(row0 + s) * 40 + q * 4];
  }
  // stage xa slice [32][64]
#pragma unroll
  for (int it = 0; it < 2; ++it) {
    int idx = t + it * 256;
    int s = idx >> 4, dq = idx & 15;
    *(float4*)&xas[s][dq * 4] = *(const float4*)&xa[(row0 + s) * 256 + dblk * 64 + dq * 4];
  }
  __syncthreads();
  // dt: each wave handles 8 s values, lane = d_local (0..63)
  {
    int lane = t & 63, w = t >> 6;
    int dg = dblk * 64 + lane;
    float4 w0 = *(const float4*)&Wdt[dg * 8];
    float4 w1 = *(const float4*)&Wdt[dg * 8 + 4];
    float bias = dtb[dg];
#pragma unroll
    for (int js = 0; js < 8; ++js) {
      int s = w * 8 + js;
      float4 x0 = *(const float4*)&xrow[s][0];
      float4 x1 = *(const float4*)&xrow[s][4];
      float v = bias;
      v = fmaf(x0.x, w0.x, v); v = fmaf(x0.y, w0.y, v);
      v = fmaf(x0.z, w0.z, v); v = fmaf(x0.w, w0.w, v);
      v = fmaf(x1.x, w1.x, v); v = fmaf(x1.y, w1.y, v);
      v = fmaf(x1.z, w1.z, v); v = fmaf(x1.w, w1.w, v);
      dts[s][lane] = softplusf(v);
    }
  }
  __syncthreads();
  int lane = t & 63, w = t >> 6;
  int d4 = lane & 15, ng = lane >> 4;
  int d_local = w * 16 + d4;
  int d_all = dblk * 64 + d_local;
  int n0 = ng * 4;
  float4 al = *(const float4*)&Alog[d_all * 16 + n0];
  float A0 = -__expf(al.x), A1 = -__expf(al.y), A2 = -__expf(al.z), A3 = -__expf(al.w);
  float P0 = 1.f, P1 = 1.f, P2 = 1.f, P3 = 1.f;
  float Q0 = 0.f, Q1 = 0.f, Q2 = 0.f, Q3 = 0.f;
#pragma unroll 4
  for (int s = 0; s < 32; ++s) {
    float dtv = dts[s][d_local];
    float xav = xas[s][d_local];
    float4 bm = *(const float4*)&xrow[s][8 + n0];
    float du = dtv * xav;
    float e0 = __expf(dtv * A0), e1 = __expf(dtv * A1);
    float e2 = __expf(dtv * A2), e3 = __expf(dtv * A3);
    Q0 = fmaf(e0, Q0, du * bm.x); P0 *= e0;
    Q1 = fmaf(e1, Q1, du * bm.y); P1 *= e1;
    Q2 = fmaf(e2, Q2, du * bm.z); P2 *= e2;
    Q3 = fmaf(e3, Q3, du * bm.w); P3 *= e3;
  }
  size_t o = (((size_t)(b * 128 + ch)) * 256 + d_all) * 16 + n0;
  *(float4*)&Pb[o] = make_float4(P0, P1, P2, P3);
  *(float4*)&Qb[o] = make_float4(Q0, Q1, Q2, Q3);
}

// ---------------- scan phase 2: serial combine over 128 chunks ----------------
__global__ __launch_bounds__(256) void k_scan_p2(const float* __restrict__ Pb,
                                                 const float* __restrict__ Qb,
                                                 float* __restrict__ Hin) {
  int t = blockIdx.x * 256 + threadIdx.x;   // 4096
  if (t >= 4096) return;
  int ng = t & 3, d = (t >> 2) & 255, b = t >> 10;
  float h0 = 0.f, h1 = 0.f, h2 = 0.f, h3 = 0.f;
  size_t o = ((size_t)(b * 128)) * 4096 + d * 16 + ng * 4;
  for (int ch = 0; ch < 128; ++ch) {
    *(float4*)&Hin[o] = make_float4(h0, h1, h2, h3);
    float4 p = *(const float4*)&Pb[o];
    float4 q = *(const float4*)&Qb[o];
    h0 = fmaf(p.x, h0, q.x); h1 = fmaf(p.y, h1, q.y);
    h2 = fmaf(p.z, h2, q.z); h3 = fmaf(p.w, h3, q.w);
    o += 4096;
  }
}

// ---------------- scan phase 3: recompute with entry state; ym -> xz[..., :256] ----------------
__global__ __launch_bounds__(256) void k_scan_p3(const float* __restrict__ xa,
                                                 const float* __restrict__ xdbl,
                                                 const float* __restrict__ Wdt,
                                                 const float* __restrict__ dtb,
                                                 const float* __restrict__ Alog,
                                                 const float* __restrict__ Hin,
                                                 const float* __restrict__ Dp,
                                                 float* __restrict__ xz) {
  __shared__ float xrow[32][40];
  __shared__ float xas[32][64];
  __shared__ float dts[32][64];
  int t = threadIdx.x;
  int blk = blockIdx.x;
  int dblk = blk & 3, ch = (blk >> 2) & 127, b = blk >> 9;
  size_t row0 = (size_t)b * 4096 + ch * 32;
  for (int idx = t; idx < 320; idx += 256) {
    int s = idx / 10, q = idx - s * 10;
    *(float4*)&xrow[s][q * 4] = *(const float4*)&xdbl[(row0 + s) * 40 + q * 4];
  }
#pragma unroll
  for (int it = 0; it < 2; ++it) {
    int idx = t + it * 256;
    int s = idx >> 4, dq = idx & 15;
    *(float4*)&xas[s][dq * 4] = *(const float4*)&xa[(row0 + s) * 256 + dblk * 64 + dq * 4];
  }
  __syncthreads();
  {
    int lane = t & 63, w = t >> 6;
    int dg = dblk * 64 + lane;
    float4 w0 = *(const float4*)&Wdt[dg * 8];
    float4 w1 = *(const float4*)&Wdt[dg * 8 + 4];
    float bias = dtb[dg];
#pragma unroll
    for (int js = 0; js < 8; ++js) {
      int s = w * 8 + js;
      float4 x0 = *(const float4*)&xrow[s][0];
      float4 x1 = *(const float4*)&xrow[s][4];
      float v = bias;
      v = fmaf(x0.x, w0.x, v); v = fmaf(x0.y, w0.y, v);
      v = fmaf(x0.z, w0.z, v); v = fmaf(x0.w, w0.w, v);
      v = fmaf(x1.x, w1.x, v); v = fmaf(x1.y, w1.y, v);
      v = fmaf(x1.z, w1.z, v); v = fmaf(x1.w, w1.w, v);
      dts[s][lane] = softplusf(v);
    }
  }
  __syncthreads();
  int lane = t & 63, w = t >> 6;
  int d4 = lane & 15, ng = lane >> 4;
  int d_local = w * 16 + d4;
  int d_all = dblk * 64 + d_local;
  int n0 = ng * 4;
  float4 al = *(const float4*)&Alog[d_all * 16 + n0];
  float A0 = -__expf(al.x), A1 = -__expf(al.y), A2 = -__expf(al.z), A3 = -__expf(al.w);
  size_t o = (((size_t)(b * 128 + ch)) * 256 + d_all) * 16 + n0;
  float4 h = *(const float4*)&Hin[o];
  float Dd = Dp[d_all];
  const float* zp = xz + (row0)*512 + 256 + d_all;
  float* wp = xz + (row0)*512 + d_all;
#pragma unroll 4
  for (int s = 0; s < 32; ++s) {
    float dtv = dts[s][d_local];
    float xav = xas[s][d_local];
    float4 bm = *(const float4*)&xrow[s][8 + n0];
    float4 cm = *(const float4*)&xrow[s][24 + n0];
    float du = dtv * xav;
    float e0 = __expf(dtv * A0), e1 = __expf(dtv * A1);
    float e2 = __expf(dtv * A2), e3 = __expf(dtv * A3);
    h.x = fmaf(e0, h.x, du * bm.x);
    h.y = fmaf(e1, h.y, du * bm.y);
    h.z = fmaf(e2, h.z, du * bm.z);
    h.w = fmaf(e3, h.w, du * bm.w);
    float yp = h.x * cm.x + h.y * cm.y + h.z * cm.z + h.w * cm.w;
    yp += __shfl_xor(yp, 16);
    yp += __shfl_xor(yp, 32);
    if (ng == 0) {
      float z = zp[s * 512];
      float y = yp + Dd * xav;
      wp[s * 512] = y * siluf(z);
    }
  }
}

// ---------------- GEMM3: out1T[32][16384] = (ym @ WoutEff^T)^T, WoutEff fused ----------------
__global__ __launch_bounds__(256) void k_gemm3(const float* __restrict__ A,      // xz (ym in cols 0..255, lda=512)
                                               const float* __restrict__ Wout,   // [128][256]
                                               float* __restrict__ CT) {         // [32][16384]
  __shared__ float As[32][68];
  __shared__ float Ws[32][68];
  int tid = threadIdx.x;
  int bm = blockIdx.x * 64;
  int tx = tid & 15, ty = tid >> 4;
  float acc[4][4] = {};
  for (int k0 = 0; k0 < 256; k0 += 32) {
#pragma unroll
    for (int it = 0; it < 2; ++it) {
      int idx = tid + it * 256;
      int r = idx >> 3;
      int kq = idx & 7;
      float4 v = *(const float4*)&A[(size_t)(bm + r) * 512 + k0 + kq * 4];
      As[kq * 4 + 0][r] = v.x; As[kq * 4 + 1][r] = v.y;
      As[kq * 4 + 2][r] = v.z; As[kq * 4 + 3][r] = v.w;
      float4 w = make_float4(0.f, 0.f, 0.f, 0.f);
      if (r < 32) {
#pragma unroll
        for (int g = 0; g < 4; ++g) {
          float4 wg = *(const float4*)&Wout[(size_t)(r + g * 32) * 256 + k0 + kq * 4];
          w.x += wg.x; w.y += wg.y; w.z += wg.z; w.w += wg.w;
        }
      }
      Ws[kq * 4 + 0][r] = w.x; Ws[kq * 4 + 1][r] = w.y;
      Ws[kq * 4 + 2][r] = w.z; Ws[kq * 4 + 3][r] = w.w;
    }
    __syncthreads();
#pragma unroll
    for (int k = 0; k < 32; ++k) {
      float4 a = *(const float4*)&As[k][ty * 4];
      float4 w = *(const float4*)&Ws[k][tx * 4];
      float av[4] = {a.x, a.y, a.z, a.w};
      float wv[4] = {w.x, w.y, w.z, w.w};
#pragma unroll
      for (int i = 0; i < 4; ++i)
#pragma unroll
        for (int j = 0; j < 4; ++j)
          acc[i][j] = fmaf(av[i], wv[j], acc[i][j]);
    }
    __syncthreads();
  }
#pragma unroll
  for (int j = 0; j < 4; ++j) {
    int n = tx * 4 + j;
    if (n < 32) {
      float4 v = make_float4(acc[0][j], acc[1][j], acc[2][j], acc[3][j]);
      *(float4*)&CT[(size_t)n * 16384 + bm + ty * 4] = v;
    }
  }
}

// ---------------- residual + foc (fused): res = out1T*fo2; foc = mean ----------------
__global__ __launch_bounds__(256) void k_res_foc(const float* __restrict__ CT,
                                                 const float* __restrict__ fo2,
                                                 float* __restrict__ res,
                                                 float* __restrict__ foc) {
  int bc = blockIdx.x;        // b*32 + c
  int b = bc >> 5, c = bc & 31;
  int t = threadIdx.x;
  const float* src = CT + (size_t)c * 16384 + (size_t)b * 4096;
  const float* f2 = fo2 + (size_t)bc * 4096;
  float* rp = res + (size_t)bc * 4096;
  float s = 0.f;
  for (int i = t * 4; i < 4096; i += 1024) {
    float4 a = *(const float4*)&src[i];
    float4 f = *(const float4*)&f2[i];
    float4 r = make_float4(a.x * f.x, a.y * f.y, a.z * f.z, a.w * f.w);
    *(float4*)&rp[i] = r;
    s += r.x + r.y + r.z + r.w;
  }
  __shared__ float red[256];
  red[t] = s;
  __syncthreads();
  for (int off = 128; off > 0; off >>= 1) {
    if (t < off) red[t] += red[t + off];
    __syncthreads();
  }
  if (t == 0) foc[bc] = red[0] * (1.f / 4096.f);
}

// ---------------- mamba2 (tiny): one block ----------------
__global__ __launch_bounds__(256) void k_mamba2(const float* __restrict__ foc,
                                                const float* __restrict__ Win2,
                                                const float* __restrict__ convw2,
                                                const float* __restrict__ convb2,
                                                const float* __restrict__ Wx2,
                                                const float* __restrict__ Wdt2,
                                                const float* __restrict__ dtb2,
                                                const float* __restrict__ Alog2,
                                                const float* __restrict__ D2,
                                                const float* __restrict__ Wout2,
                                                float* __restrict__ scale) {
  __shared__ float foc_s[128];
  __shared__ float xz2_s[4][32][8];
  __shared__ float xa2_s[4][32][4];
  __shared__ float xdbl2_s[4][32][33];
  __shared__ float dt2_s[4][32][4];
  __shared__ float ym2_s[4][32][4];
  int t = threadIdx.x;
  if (t < 128) foc_s[t] = foc[t];
  __syncthreads();
  for (int i = t; i < 1024; i += 256) {
    int j = i & 7, l = (i >> 3) & 31, b = i >> 8;
    float x0 = foc_s[b * 32 + l], x1 = foc_s[b * 32 + 31 - l];
    xz2_s[b][l][j] = x0 * Win2[j * 2] + x1 * Win2[j * 2 + 1];
  }
  __syncthreads();
  for (int i = t; i < 512; i += 256) {
    int d = i & 3, l = (i >> 2) & 31, b = i >> 7;
    float acc = convb2[d];
#pragma unroll
    for (int k = 0; k < 4; ++k) {
      int ls = l + k - 3;
      if (ls >= 0) acc = fmaf(convw2[d * 4 + k], xz2_s[b][ls][d], acc);
    }
    xa2_s[b][l][d] = siluf(acc);
  }
  __syncthreads();
  for (int i = t; i < 4224; i += 256) {
    int r = i % 33, l = (i / 33) & 31, b = i / 1056;
    float s = 0.f;
#pragma unroll
    for (int d = 0; d < 4; ++d) s = fmaf(xa2_s[b][l][d], Wx2[r * 4 + d], s);
    xdbl2_s[b][l][r] = s;
  }
  __syncthreads();
  for (int i = t; i < 512; i += 256) {
    int d = i & 3, l = (i >> 2) & 31, b = i >> 7;
    float s = xdbl2_s[b][l][0] * Wdt2[d] + dtb2[d];
    dt2_s[b][l][d] = softplusf(s);
  }
  __syncthreads();
  {
    int n = t & 15, d = (t >> 4) & 3, b = t >> 6;
    float A = -__expf(Alog2[d * 16 + n]);
    float h = 0.f;
    for (int l = 0; l < 32; ++l) {
      float dtv = dt2_s[b][l][d];
      float xav = xa2_s[b][l][d];
      float e = __expf(dtv * A);
      h = fmaf(e, h, dtv * xdbl2_s[b][l][1 + n] * xav);
      float yp = h * xdbl2_s[b][l][17 + n];
      yp += __shfl_xor(yp, 1);
      yp += __shfl_xor(yp, 2);
      yp += __shfl_xor(yp, 4);
      yp += __shfl_xor(yp, 8);
      if (n == 0) {
        float z = xz2_s[b][l][4 + d];
        float y = yp + D2[d] * xav;
        ym2_s[b][l][d] = y * siluf(z);
      }
    }
  }
  __syncthreads();
  if (t < 128) {
    int l = t & 31, b = t >> 5;
    float s = 0.f;
#pragma unroll
    for (int d = 0; d < 4; ++d) s = fmaf(ym2_s[b][l][d], Wout2[d] + Wout2[4 + d], s);
    scale[t] = s;
  }
}

// ---------------- final: out = res * (1 + scale[b,c]) ----------------
__global__ __launch_bounds__(256) void k_final(const float* __restrict__ res,
                                               const float* __restrict__ scale,
                                               float* __restrict__ out) {
  int idx = blockIdx.x * 256 + threadIdx.x;
  out[idx] = res[idx] * (1.f + scale[idx >> 12]);
}

extern "C" void kernel_launch(void* const* d_in, const int* in_sizes, int n_in,
                              void* d_out, int out_size, void* d_ws, size_t ws_size,
                              hipStream_t stream) {
  const float* fo1    = (const float*)d_in[0];
  const float* fo2    = (const float*)d_in[1];
  const float* Win    = (const float*)d_in[2];
  const float* convw  = (const float*)d_in[3];
  const float* convb  = (const float*)d_in[4];
  const float* Wx     = (const float*)d_in[5];
  const float* Wdt    = (const float*)d_in[6];
  const float* dtb    = (const float*)d_in[7];
  const float* Alog   = (const float*)d_in[8];
  const float* Dp     = (const float*)d_in[9];
  const float* Wout   = (const float*)d_in[10];
  const float* Win2   = (const float*)d_in[11];
  const float* convw2 = (const float*)d_in[12];
  const float* convb2 = (const float*)d_in[13];
  const float* Wx2    = (const float*)d_in[14];
  const float* Wdt2   = (const float*)d_in[15];
  const float* dtb2   = (const float*)d_in[16];
  const float* Alog2  = (const float*)d_in[17];
  const float* D2     = (const float*)d_in[18];
  const float* Wout2  = (const float*)d_in[19];

  float* ws = (float*)d_ws;
  // fopb (bf16, 2M elems = 1,048,576 float-slots), later reused as xdbl (655,360 floats)
  unsigned short* fopb = (unsigned short*)ws;
  float* xdbl = ws;                      // alias: gemm2 writes after gemm1 consumed fopb
  float* xz   = ws + 1048576;            // 8,388,608
  float* xa   = ws + 9437184;            // 4,194,304
  float* Pb   = ws + 13631488;           // 2,097,152
  float* Qb   = ws + 15728640;           // 2,097,152
  float* Hin  = ws + 17825792;           // 2,097,152
  float* o1T  = ws + 19922944;           //   524,288
  float* res  = ws + 20447232;           //   524,288
  float* foc  = ws + 20971520;           //       128
  float* scl  = ws + 20971648;           //       128
  if (ws_size < (size_t)20971776 * sizeof(float)) return;  // ~80 MB scratch

  hipLaunchKernelGGL(k_build_fop, dim3(8192), dim3(256), 0, stream, fo1, fopb);
  hipLaunchKernelGGL(k_gemm1_mfma, dim3(128, 8), dim3(256), 0, stream, fopb, Win, xz);
  hipLaunchKernelGGL(k_conv_silu, dim3(16384), dim3(256), 0, stream, xz, convw, convb, xa);
  hipLaunchKernelGGL(k_gemm_nt, dim3(256, 1), dim3(256), 0, stream,
                     xa, Wx, xdbl, 16384, 40, 256, 256);
  hipLaunchKernelGGL(k_scan_p1, dim3(2048), dim3(256), 0, stream,
                     xa, xdbl, Wdt, dtb, Alog, Pb, Qb);
  hipLaunchKernelGGL(k_scan_p2, dim3(16), dim3(256), 0, stream, Pb, Qb, Hin);
  hipLaunchKernelGGL(k_scan_p3, dim3(2048), dim3(256), 0, stream,
                     xa, xdbl, Wdt, dtb, Alog, Hin, Dp, xz);
  hipLaunchKernelGGL(k_gemm3, dim3(256), dim3(256), 0, stream, xz, Wout, o1T);
  hipLaunchKernelGGL(k_res_foc, dim3(128), dim3(256), 0, stream, o1T, fo2, res, foc);
  hipLaunchKernelGGL(k_mamba2, dim3(1), dim3(256), 0, stream, foc, Win2, convw2, convb2,
                     Wx2, Wdt2, dtb2, Alog2, D2, Wout2, scl);
  hipLaunchKernelGGL(k_final, dim3(2048), dim3(256), 0, stream, res, scl, (float*)d_out);
}

// Round 4
// 176.867 us; speedup vs baseline: 1.2559x; 1.0819x over previous
//
#include <hip/hip_runtime.h>
#include <cstddef>

// (B,C,H,W)=(4,32,64,64), D_STATE=16, D_CONV=4
// Mamba1: L=4096, d_model=128, d_in=256, dt_rank=8, xdbl width 40
// Scan: chunked 3-phase, CHUNK=32 -> 128 chunks, LDS-resident inner loop

typedef __attribute__((ext_vector_type(8))) short short8v;
typedef __attribute__((ext_vector_type(4))) float f32x4;

__device__ __forceinline__ float siluf(float x) { return x / (1.f + __expf(-x)); }
__device__ __forceinline__ float softplusf(float x) { return (x > 20.f) ? x : log1pf(__expf(x)); }
__device__ __forceinline__ unsigned short f2bf(float f) {
  union { float f; unsigned int u; } v; v.f = f;
  unsigned int r = v.u + 0x7fff + ((v.u >> 16) & 1);
  return (unsigned short)(r >> 16);
}

// ---------------- K0: build fop (B, L, 128) bf16 from fo1 (B,C,H,W) ----------------
__global__ __launch_bounds__(256) void k_build_fop(const float* __restrict__ fo1,
                                                   unsigned short* __restrict__ fopb) {
  int idx = blockIdx.x * 256 + threadIdx.x;   // 2^21
  int j = idx & 127;
  int l = (idx >> 7) & 4095;
  int b = idx >> 19;
  int g = j >> 5, c = j & 31;
  const float* base = fo1 + (size_t)(b * 32 + c) * 4096;
  int li;
  if (g == 0)      li = l;
  else if (g == 1) li = 4095 - l;
  else if (g == 2) li = ((l & 63) << 6) + (l >> 6);
  else { int i2 = 4095 - l; li = ((i2 & 63) << 6) + (i2 >> 6); }
  fopb[idx] = f2bf(base[li]);
}

// ---------------- GEMM1: xz[16384][512] = fopb[16384][128] @ Win[512][128]^T (bf16 MFMA) ----
__global__ __launch_bounds__(256) void k_gemm1_mfma(const unsigned short* __restrict__ A,
                                                    const float* __restrict__ Win,
                                                    float* __restrict__ C) {
  __shared__ unsigned short As[128][136];
  __shared__ unsigned short Bs[64][136];
  int t = threadIdx.x;
  int bm = blockIdx.x * 128, bn = blockIdx.y * 64;
#pragma unroll
  for (int it = 0; it < 8; ++it) {
    int idx = t + it * 256;
    int r = idx >> 4, kc = idx & 15;
    short8v v = *(const short8v*)&A[(size_t)(bm + r) * 128 + kc * 8];
    *(short8v*)&As[r][kc * 8] = v;
  }
#pragma unroll
  for (int it = 0; it < 8; ++it) {
    int idx = t + it * 256;
    int r = idx >> 5, kq = idx & 31;
    float4 w = *(const float4*)&Win[(size_t)(bn + r) * 128 + kq * 4];
    ushort4 h;
    h.x = f2bf(w.x); h.y = f2bf(w.y); h.z = f2bf(w.z); h.w = f2bf(w.w);
    *(ushort4*)&Bs[r][kq * 4] = h;
  }
  __syncthreads();
  int lane = t & 63, w = t >> 6;
  int wm = (w & 1) * 64, wn = (w >> 1) * 32;
  int lr = lane & 15, lg = lane >> 4;
  f32x4 acc[4][2] = {};
#pragma unroll
  for (int k0 = 0; k0 < 128; k0 += 32) {
    short8v a[4], b[2];
#pragma unroll
    for (int mf = 0; mf < 4; ++mf)
      a[mf] = *(const short8v*)&As[wm + mf * 16 + lr][k0 + lg * 8];
#pragma unroll
    for (int nf = 0; nf < 2; ++nf)
      b[nf] = *(const short8v*)&Bs[wn + nf * 16 + lr][k0 + lg * 8];
#pragma unroll
    for (int mf = 0; mf < 4; ++mf)
#pragma unroll
      for (int nf = 0; nf < 2; ++nf)
        acc[mf][nf] = __builtin_amdgcn_mfma_f32_16x16x32_bf16(a[mf], b[nf], acc[mf][nf], 0, 0, 0);
  }
#pragma unroll
  for (int mf = 0; mf < 4; ++mf)
#pragma unroll
    for (int nf = 0; nf < 2; ++nf)
#pragma unroll
      for (int r = 0; r < 4; ++r) {
        size_t row = bm + wm + mf * 16 + lg * 4 + r;
        C[row * 512 + bn + wn + nf * 16 + lr] = acc[mf][nf][r];
      }
}

// ---------------- generic fp32 GEMM (GEMM2): C[M,N] = A[M,K](lda) @ W[N,K]^T ----
__global__ __launch_bounds__(256) void k_gemm_nt(const float* __restrict__ A,
                                                 const float* __restrict__ W,
                                                 float* __restrict__ C,
                                                 int M, int N, int K, int lda) {
  __shared__ float As[32][68];
  __shared__ float Ws[32][68];
  int tid = threadIdx.x;
  int bm = blockIdx.x * 64;
  int bn = blockIdx.y * 64;
  int tx = tid & 15, ty = tid >> 4;
  float acc[4][4] = {};
  for (int k0 = 0; k0 < K; k0 += 32) {
#pragma unroll
    for (int it = 0; it < 2; ++it) {
      int idx = tid + it * 256;
      int r = idx >> 3;
      int kq = idx & 7;
      float4 v = *(const float4*)&A[(size_t)(bm + r) * lda + k0 + kq * 4];
      As[kq * 4 + 0][r] = v.x; As[kq * 4 + 1][r] = v.y;
      As[kq * 4 + 2][r] = v.z; As[kq * 4 + 3][r] = v.w;
      int n = bn + r;
      float4 w = make_float4(0.f, 0.f, 0.f, 0.f);
      if (n < N) w = *(const float4*)&W[(size_t)n * K + k0 + kq * 4];
      Ws[kq * 4 + 0][r] = w.x; Ws[kq * 4 + 1][r] = w.y;
      Ws[kq * 4 + 2][r] = w.z; Ws[kq * 4 + 3][r] = w.w;
    }
    __syncthreads();
#pragma unroll
    for (int k = 0; k < 32; ++k) {
      float4 a = *(const float4*)&As[k][ty * 4];
      float4 w = *(const float4*)&Ws[k][tx * 4];
      float av[4] = {a.x, a.y, a.z, a.w};
      float wv[4] = {w.x, w.y, w.z, w.w};
#pragma unroll
      for (int i = 0; i < 4; ++i)
#pragma unroll
        for (int j = 0; j < 4; ++j)
          acc[i][j] = fmaf(av[i], wv[j], acc[i][j]);
    }
    __syncthreads();
  }
#pragma unroll
  for (int i = 0; i < 4; ++i) {
    size_t m = bm + ty * 4 + i;
#pragma unroll
    for (int j = 0; j < 4; ++j) {
      int n = bn + tx * 4 + j;
      if (n < N) C[m * N + n] = acc[i][j];
    }
  }
}

// ---------------- conv K=4 causal + silu -> xa ----------------
__global__ __launch_bounds__(256) void k_conv_silu(const float* __restrict__ xz,
                                                   const float* __restrict__ convw,
                                                   const float* __restrict__ convb,
                                                   float* __restrict__ xa) {
  int row = blockIdx.x;
  int l = row & 4095;
  int d = threadIdx.x;
  float4 w = *(const float4*)&convw[d * 4];
  float acc = convb[d];
  const float* p = xz + (size_t)row * 512 + d;
  if (l >= 3) acc = fmaf(w.x, p[-3 * 512], acc);
  if (l >= 2) acc = fmaf(w.y, p[-2 * 512], acc);
  if (l >= 1) acc = fmaf(w.z, p[-1 * 512], acc);
  acc = fmaf(w.w, p[0], acc);
  xa[(size_t)row * 256 + d] = siluf(acc);
}

// ---------------- scan phase 1 (LDS-resident): P,Q per chunk ----------------
__global__ __launch_bounds__(256) void k_scan_p1(const float* __restrict__ xa,
                                                 const float* __restrict__ xdbl,
                                                 const float* __restrict__ Wdt,
                                                 const float* __restrict__ dtb,
                                                 const float* __restrict__ Alog,
                                                 float* __restrict__ Pb,
                                                 float* __restrict__ Qb) {
  __shared__ float xrow[32][40];
  __shared__ float xas[32][64];
  __shared__ float dts[32][64];
  int t = threadIdx.x;
  int blk = blockIdx.x;
  int dblk = blk & 3, ch = (blk >> 2) & 127, b = blk >> 9;
  size_t row0 = (size_t)b * 4096 + ch * 32;
  for (int idx = t; idx < 320; idx += 256) {
    int s = idx / 10, q = idx - s * 10;
    *(float4*)&xrow[s][q * 4] = *(const float4*)&xdbl[(row0 + s) * 40 + q * 4];
  }
#pragma unroll
  for (int it = 0; it < 2; ++it) {
    int idx = t + it * 256;
    int s = idx >> 4, dq = idx & 15;
    *(float4*)&xas[s][dq * 4] = *(const float4*)&xa[(row0 + s) * 256 + dblk * 64 + dq * 4];
  }
  __syncthreads();
  {
    int lane = t & 63, w = t >> 6;
    int dg = dblk * 64 + lane;
    float4 w0 = *(const float4*)&Wdt[dg * 8];
    float4 w1 = *(const float4*)&Wdt[dg * 8 + 4];
    float bias = dtb[dg];
#pragma unroll
    for (int js = 0; js < 8; ++js) {
      int s = w * 8 + js;
      float4 x0 = *(const float4*)&xrow[s][0];
      float4 x1 = *(const float4*)&xrow[s][4];
      float v = bias;
      v = fmaf(x0.x, w0.x, v); v = fmaf(x0.y, w0.y, v);
      v = fmaf(x0.z, w0.z, v); v = fmaf(x0.w, w0.w, v);
      v = fmaf(x1.x, w1.x, v); v = fmaf(x1.y, w1.y, v);
      v = fmaf(x1.z, w1.z, v); v = fmaf(x1.w, w1.w, v);
      dts[s][lane] = softplusf(v);
    }
  }
  __syncthreads();
  int lane = t & 63, w = t >> 6;
  int d4 = lane & 15, ng = lane >> 4;
  int d_local = w * 16 + d4;
  int d_all = dblk * 64 + d_local;
  int n0 = ng * 4;
  float4 al = *(const float4*)&Alog[d_all * 16 + n0];
  float A0 = -__expf(al.x), A1 = -__expf(al.y), A2 = -__expf(al.z), A3 = -__expf(al.w);
  float P0 = 1.f, P1 = 1.f, P2 = 1.f, P3 = 1.f;
  float Q0 = 0.f, Q1 = 0.f, Q2 = 0.f, Q3 = 0.f;
#pragma unroll 4
  for (int s = 0; s < 32; ++s) {
    float dtv = dts[s][d_local];
    float xav = xas[s][d_local];
    float4 bm = *(const float4*)&xrow[s][8 + n0];
    float du = dtv * xav;
    float e0 = __expf(dtv * A0), e1 = __expf(dtv * A1);
    float e2 = __expf(dtv * A2), e3 = __expf(dtv * A3);
    Q0 = fmaf(e0, Q0, du * bm.x); P0 *= e0;
    Q1 = fmaf(e1, Q1, du * bm.y); P1 *= e1;
    Q2 = fmaf(e2, Q2, du * bm.z); P2 *= e2;
    Q3 = fmaf(e3, Q3, du * bm.w); P3 *= e3;
  }
  size_t o = (((size_t)(b * 128 + ch)) * 256 + d_all) * 16 + n0;
  *(float4*)&Pb[o] = make_float4(P0, P1, P2, P3);
  *(float4*)&Qb[o] = make_float4(Q0, Q1, Q2, Q3);
}

// ---------------- scan phase 2: serial combine over 128 chunks ----------------
__global__ __launch_bounds__(256) void k_scan_p2(const float* __restrict__ Pb,
                                                 const float* __restrict__ Qb,
                                                 float* __restrict__ Hin) {
  int t = blockIdx.x * 256 + threadIdx.x;   // 4096
  if (t >= 4096) return;
  int ng = t & 3, d = (t >> 2) & 255, b = t >> 10;
  float h0 = 0.f, h1 = 0.f, h2 = 0.f, h3 = 0.f;
  size_t o = ((size_t)(b * 128)) * 4096 + d * 16 + ng * 4;
#pragma unroll 4
  for (int ch = 0; ch < 128; ++ch) {
    *(float4*)&Hin[o] = make_float4(h0, h1, h2, h3);
    float4 p = *(const float4*)&Pb[o];
    float4 q = *(const float4*)&Qb[o];
    h0 = fmaf(p.x, h0, q.x); h1 = fmaf(p.y, h1, q.y);
    h2 = fmaf(p.z, h2, q.z); h3 = fmaf(p.w, h3, q.w);
    o += 4096;
  }
}

// ---------------- scan phase 3: lean loop; bulk epilogue for y*silu(z) ----------------
__global__ __launch_bounds__(256) void k_scan_p3(const float* __restrict__ xa,
                                                 const float* __restrict__ xdbl,
                                                 const float* __restrict__ Wdt,
                                                 const float* __restrict__ dtb,
                                                 const float* __restrict__ Alog,
                                                 const float* __restrict__ Hin,
                                                 const float* __restrict__ Dp,
                                                 float* __restrict__ xz) {
  __shared__ float xrow[32][40];
  __shared__ float xas[32][64];
  __shared__ float dts[32][64];
  __shared__ float ylds[32][64];
  int t = threadIdx.x;
  int blk = blockIdx.x;
  int dblk = blk & 3, ch = (blk >> 2) & 127, b = blk >> 9;
  size_t row0 = (size_t)b * 4096 + ch * 32;
  for (int idx = t; idx < 320; idx += 256) {
    int s = idx / 10, q = idx - s * 10;
    *(float4*)&xrow[s][q * 4] = *(const float4*)&xdbl[(row0 + s) * 40 + q * 4];
  }
#pragma unroll
  for (int it = 0; it < 2; ++it) {
    int idx = t + it * 256;
    int s = idx >> 4, dq = idx & 15;
    *(float4*)&xas[s][dq * 4] = *(const float4*)&xa[(row0 + s) * 256 + dblk * 64 + dq * 4];
  }
  __syncthreads();
  {
    int lane = t & 63, w = t >> 6;
    int dg = dblk * 64 + lane;
    float4 w0 = *(const float4*)&Wdt[dg * 8];
    float4 w1 = *(const float4*)&Wdt[dg * 8 + 4];
    float bias = dtb[dg];
#pragma unroll
    for (int js = 0; js < 8; ++js) {
      int s = w * 8 + js;
      float4 x0 = *(const float4*)&xrow[s][0];
      float4 x1 = *(const float4*)&xrow[s][4];
      float v = bias;
      v = fmaf(x0.x, w0.x, v); v = fmaf(x0.y, w0.y, v);
      v = fmaf(x0.z, w0.z, v); v = fmaf(x0.w, w0.w, v);
      v = fmaf(x1.x, w1.x, v); v = fmaf(x1.y, w1.y, v);
      v = fmaf(x1.z, w1.z, v); v = fmaf(x1.w, w1.w, v);
      dts[s][lane] = softplusf(v);
    }
  }
  __syncthreads();
  int lane = t & 63, w = t >> 6;
  int d4 = lane & 15, ng = lane >> 4;
  int d_local = w * 16 + d4;
  int d_all = dblk * 64 + d_local;
  int n0 = ng * 4;
  float4 al = *(const float4*)&Alog[d_all * 16 + n0];
  float A0 = -__expf(al.x), A1 = -__expf(al.y), A2 = -__expf(al.z), A3 = -__expf(al.w);
  size_t o = (((size_t)(b * 128 + ch)) * 256 + d_all) * 16 + n0;
  float4 h = *(const float4*)&Hin[o];
#pragma unroll 4
  for (int s = 0; s < 32; ++s) {
    float dtv = dts[s][d_local];
    float xav = xas[s][d_local];
    float4 bm = *(const float4*)&xrow[s][8 + n0];
    float4 cm = *(const float4*)&xrow[s][24 + n0];
    float du = dtv * xav;
    float e0 = __expf(dtv * A0), e1 = __expf(dtv * A1);
    float e2 = __expf(dtv * A2), e3 = __expf(dtv * A3);
    h.x = fmaf(e0, h.x, du * bm.x);
    h.y = fmaf(e1, h.y, du * bm.y);
    h.z = fmaf(e2, h.z, du * bm.z);
    h.w = fmaf(e3, h.w, du * bm.w);
    float yp = h.x * cm.x + h.y * cm.y + h.z * cm.z + h.w * cm.w;
    yp += __shfl_xor(yp, 16);
    yp += __shfl_xor(yp, 32);
    if (ng == 0) ylds[s][d_local] = yp;
  }
  __syncthreads();
  // bulk epilogue: y = ylds + D*xa; out = y * silu(z); coalesced z/stores
  {
    int dl = t & 63;
    int da = dblk * 64 + dl;
    float Dd = Dp[da];
#pragma unroll
    for (int it = 0; it < 8; ++it) {
      int s = (t >> 6) + it * 4;
      float yv = fmaf(Dd, xas[s][dl], ylds[s][dl]);
      float z = xz[(row0 + s) * 512 + 256 + da];
      xz[(row0 + s) * 512 + da] = yv * siluf(z);
    }
  }
}

// ---------------- GEMM3: out1T[32][16384] = (ym @ WoutEff^T)^T, WoutEff fused ----------------
__global__ __launch_bounds__(256) void k_gemm3(const float* __restrict__ A,
                                               const float* __restrict__ Wout,
                                               float* __restrict__ CT) {
  __shared__ float As[32][68];
  __shared__ float Ws[32][68];
  int tid = threadIdx.x;
  int bm = blockIdx.x * 64;
  int tx = tid & 15, ty = tid >> 4;
  float acc[4][4] = {};
  for (int k0 = 0; k0 < 256; k0 += 32) {
#pragma unroll
    for (int it = 0; it < 2; ++it) {
      int idx = tid + it * 256;
      int r = idx >> 3;
      int kq = idx & 7;
      float4 v = *(const float4*)&A[(size_t)(bm + r) * 512 + k0 + kq * 4];
      As[kq * 4 + 0][r] = v.x; As[kq * 4 + 1][r] = v.y;
      As[kq * 4 + 2][r] = v.z; As[kq * 4 + 3][r] = v.w;
      float4 w = make_float4(0.f, 0.f, 0.f, 0.f);
      if (r < 32) {
#pragma unroll
        for (int g = 0; g < 4; ++g) {
          float4 wg = *(const float4*)&Wout[(size_t)(r + g * 32) * 256 + k0 + kq * 4];
          w.x += wg.x; w.y += wg.y; w.z += wg.z; w.w += wg.w;
        }
      }
      Ws[kq * 4 + 0][r] = w.x; Ws[kq * 4 + 1][r] = w.y;
      Ws[kq * 4 + 2][r] = w.z; Ws[kq * 4 + 3][r] = w.w;
    }
    __syncthreads();
#pragma unroll
    for (int k = 0; k < 32; ++k) {
      float4 a = *(const float4*)&As[k][ty * 4];
      float4 w = *(const float4*)&Ws[k][tx * 4];
      float av[4] = {a.x, a.y, a.z, a.w};
      float wv[4] = {w.x, w.y, w.z, w.w};
#pragma unroll
      for (int i = 0; i < 4; ++i)
#pragma unroll
        for (int j = 0; j < 4; ++j)
          acc[i][j] = fmaf(av[i], wv[j], acc[i][j]);
    }
    __syncthreads();
  }
#pragma unroll
  for (int j = 0; j < 4; ++j) {
    int n = tx * 4 + j;
    if (n < 32) {
      float4 v = make_float4(acc[0][j], acc[1][j], acc[2][j], acc[3][j]);
      *(float4*)&CT[(size_t)n * 16384 + bm + ty * 4] = v;
    }
  }
}

// ---------------- residual + foc (fused) ----------------
__global__ __launch_bounds__(256) void k_res_foc(const float* __restrict__ CT,
                                                 const float* __restrict__ fo2,
                                                 float* __restrict__ res,
                                                 float* __restrict__ foc) {
  int bc = blockIdx.x;
  int b = bc >> 5, c = bc & 31;
  int t = threadIdx.x;
  const float* src = CT + (size_t)c * 16384 + (size_t)b * 4096;
  const float* f2 = fo2 + (size_t)bc * 4096;
  float* rp = res + (size_t)bc * 4096;
  float s = 0.f;
  for (int i = t * 4; i < 4096; i += 1024) {
    float4 a = *(const float4*)&src[i];
    float4 f = *(const float4*)&f2[i];
    float4 r = make_float4(a.x * f.x, a.y * f.y, a.z * f.z, a.w * f.w);
    *(float4*)&rp[i] = r;
    s += r.x + r.y + r.z + r.w;
  }
  __shared__ float red[256];
  red[t] = s;
  __syncthreads();
  for (int off = 128; off > 0; off >>= 1) {
    if (t < off) red[t] += red[t + off];
    __syncthreads();
  }
  if (t == 0) foc[bc] = red[0] * (1.f / 4096.f);
}

// ---------------- mamba2 (tiny): one block ----------------
__global__ __launch_bounds__(256) void k_mamba2(const float* __restrict__ foc,
                                                const float* __restrict__ Win2,
                                                const float* __restrict__ convw2,
                                                const float* __restrict__ convb2,
                                                const float* __restrict__ Wx2,
                                                const float* __restrict__ Wdt2,
                                                const float* __restrict__ dtb2,
                                                const float* __restrict__ Alog2,
                                                const float* __restrict__ D2,
                                                const float* __restrict__ Wout2,
                                                float* __restrict__ scale) {
  __shared__ float foc_s[128];
  __shared__ float xz2_s[4][32][8];
  __shared__ float xa2_s[4][32][4];
  __shared__ float xdbl2_s[4][32][33];
  __shared__ float dt2_s[4][32][4];
  __shared__ float ym2_s[4][32][4];
  int t = threadIdx.x;
  if (t < 128) foc_s[t] = foc[t];
  __syncthreads();
  for (int i = t; i < 1024; i += 256) {
    int j = i & 7, l = (i >> 3) & 31, b = i >> 8;
    float x0 = foc_s[b * 32 + l], x1 = foc_s[b * 32 + 31 - l];
    xz2_s[b][l][j] = x0 * Win2[j * 2] + x1 * Win2[j * 2 + 1];
  }
  __syncthreads();
  for (int i = t; i < 512; i += 256) {
    int d = i & 3, l = (i >> 2) & 31, b = i >> 7;
    float acc = convb2[d];
#pragma unroll
    for (int k = 0; k < 4; ++k) {
      int ls = l + k - 3;
      if (ls >= 0) acc = fmaf(convw2[d * 4 + k], xz2_s[b][ls][d], acc);
    }
    xa2_s[b][l][d] = siluf(acc);
  }
  __syncthreads();
  for (int i = t; i < 4224; i += 256) {
    int r = i % 33, l = (i / 33) & 31, b = i / 1056;
    float s = 0.f;
#pragma unroll
    for (int d = 0; d < 4; ++d) s = fmaf(xa2_s[b][l][d], Wx2[r * 4 + d], s);
    xdbl2_s[b][l][r] = s;
  }
  __syncthreads();
  for (int i = t; i < 512; i += 256) {
    int d = i & 3, l = (i >> 2) & 31, b = i >> 7;
    float s = xdbl2_s[b][l][0] * Wdt2[d] + dtb2[d];
    dt2_s[b][l][d] = softplusf(s);
  }
  __syncthreads();
  {
    int n = t & 15, d = (t >> 4) & 3, b = t >> 6;
    float A = -__expf(Alog2[d * 16 + n]);
    float h = 0.f;
    for (int l = 0; l < 32; ++l) {
      float dtv = dt2_s[b][l][d];
      float xav = xa2_s[b][l][d];
      float e = __expf(dtv * A);
      h = fmaf(e, h, dtv * xdbl2_s[b][l][1 + n] * xav);
      float yp = h * xdbl2_s[b][l][17 + n];
      yp += __shfl_xor(yp, 1);
      yp += __shfl_xor(yp, 2);
      yp += __shfl_xor(yp, 4);
      yp += __shfl_xor(yp, 8);
      if (n == 0) {
        float z = xz2_s[b][l][4 + d];
        float y = yp + D2[d] * xav;
        ym2_s[b][l][d] = y * siluf(z);
      }
    }
  }
  __syncthreads();
  if (t < 128) {
    int l = t & 31, b = t >> 5;
    float s = 0.f;
#pragma unroll
    for (int d = 0; d < 4; ++d) s = fmaf(ym2_s[b][l][d], Wout2[d] + Wout2[4 + d], s);
    scale[t] = s;
  }
}

// ---------------- final: out = res * (1 + scale[b,c]) ----------------
__global__ __launch_bounds__(256) void k_final(const float* __restrict__ res,
                                               const float* __restrict__ scale,
                                               float* __restrict__ out) {
  int idx = blockIdx.x * 256 + threadIdx.x;
  out[idx] = res[idx] * (1.f + scale[idx >> 12]);
}

extern "C" void kernel_launch(void* const* d_in, const int* in_sizes, int n_in,
                              void* d_out, int out_size, void* d_ws, size_t ws_size,
                              hipStream_t stream) {
  const float* fo1    = (const float*)d_in[0];
  const float* fo2    = (const float*)d_in[1];
  const float* Win    = (const float*)d_in[2];
  const float* convw  = (const float*)d_in[3];
  const float* convb  = (const float*)d_in[4];
  const float* Wx     = (const float*)d_in[5];
  const float* Wdt    = (const float*)d_in[6];
  const float* dtb    = (const float*)d_in[7];
  const float* Alog   = (const float*)d_in[8];
  const float* Dp     = (const float*)d_in[9];
  const float* Wout   = (const float*)d_in[10];
  const float* Win2   = (const float*)d_in[11];
  const float* convw2 = (const float*)d_in[12];
  const float* convb2 = (const float*)d_in[13];
  const float* Wx2    = (const float*)d_in[14];
  const float* Wdt2   = (const float*)d_in[15];
  const float* dtb2   = (const float*)d_in[16];
  const float* Alog2  = (const float*)d_in[17];
  const float* D2     = (const float*)d_in[18];
  const float* Wout2  = (const float*)d_in[19];

  float* ws = (float*)d_ws;
  unsigned short* fopb = (unsigned short*)ws;   // 2M bf16 = 1,048,576 float-slots
  float* xdbl = ws;                             // alias, reused after gemm1
  float* xz   = ws + 1048576;                   // 8,388,608
  float* xa   = ws + 9437184;                   // 4,194,304
  float* Pb   = ws + 13631488;                  // 2,097,152
  float* Qb   = ws + 15728640;                  // 2,097,152
  float* Hin  = ws + 17825792;                  // 2,097,152
  float* o1T  = ws + 19922944;                  //   524,288
  float* res  = ws + 20447232;                  //   524,288
  float* foc  = ws + 20971520;                  //       128
  float* scl  = ws + 20971648;                  //       128
  if (ws_size < (size_t)20971776 * sizeof(float)) return;

  hipLaunchKernelGGL(k_build_fop, dim3(8192), dim3(256), 0, stream, fo1, fopb);
  hipLaunchKernelGGL(k_gemm1_mfma, dim3(128, 8), dim3(256), 0, stream, fopb, Win, xz);
  hipLaunchKernelGGL(k_conv_silu, dim3(16384), dim3(256), 0, stream, xz, convw, convb, xa);
  hipLaunchKernelGGL(k_gemm_nt, dim3(256, 1), dim3(256), 0, stream,
                     xa, Wx, xdbl, 16384, 40, 256, 256);
  hipLaunchKernelGGL(k_scan_p1, dim3(2048), dim3(256), 0, stream,
                     xa, xdbl, Wdt, dtb, Alog, Pb, Qb);
  hipLaunchKernelGGL(k_scan_p2, dim3(16), dim3(256), 0, stream, Pb, Qb, Hin);
  hipLaunchKernelGGL(k_scan_p3, dim3(2048), dim3(256), 0, stream,
                     xa, xdbl, Wdt, dtb, Alog, Hin, Dp, xz);
  hipLaunchKernelGGL(k_gemm3, dim3(256), dim3(256), 0, stream, xz, Wout, o1T);
  hipLaunchKernelGGL(k_res_foc, dim3(128), dim3(256), 0, stream, o1T, fo2, res, foc);
  hipLaunchKernelGGL(k_mamba2, dim3(1), dim3(256), 0, stream, foc, Win2, convw2, convb2,
                     Wx2, Wdt2, dtb2, Alog2, D2, Wout2, scl);
  hipLaunchKernelGGL(k_final, dim3(2048), dim3(256), 0, stream, res, scl, (float*)d_out);
}

// Round 5
// 156.022 us; speedup vs baseline: 1.4237x; 1.1336x over previous
//
#include <hip/hip_runtime.h>
#include <cstddef>

// (B,C,H,W)=(4,32,64,64), D_STATE=16, D_CONV=4
// Mamba1: L=4096, d_model=128, d_in=256, dt_rank=8, xdbl width 40
// Scan v4: CHUNK=32, one thread per d (16 n-states in registers), 3-phase

typedef __attribute__((ext_vector_type(8))) short short8v;
typedef __attribute__((ext_vector_type(4))) float f32x4;

__device__ __forceinline__ float siluf(float x) { return x / (1.f + __expf(-x)); }
__device__ __forceinline__ float softplusf(float x) { return (x > 20.f) ? x : log1pf(__expf(x)); }
__device__ __forceinline__ unsigned short f2bf(float f) {
  union { float f; unsigned int u; } v; v.f = f;
  unsigned int r = v.u + 0x7fff + ((v.u >> 16) & 1);
  return (unsigned short)(r >> 16);
}

// ---------------- K0: build fop (B, L, 128) bf16 from fo1 (B,C,H,W) ----------------
__global__ __launch_bounds__(256) void k_build_fop(const float* __restrict__ fo1,
                                                   unsigned short* __restrict__ fopb) {
  int idx = blockIdx.x * 256 + threadIdx.x;   // 2^21
  int j = idx & 127;
  int l = (idx >> 7) & 4095;
  int b = idx >> 19;
  int g = j >> 5, c = j & 31;
  const float* base = fo1 + (size_t)(b * 32 + c) * 4096;
  int li;
  if (g == 0)      li = l;
  else if (g == 1) li = 4095 - l;
  else if (g == 2) li = ((l & 63) << 6) + (l >> 6);
  else { int i2 = 4095 - l; li = ((i2 & 63) << 6) + (i2 >> 6); }
  fopb[idx] = f2bf(base[li]);
}

// ---------------- GEMM1: xz[16384][512] = fopb @ Win^T (bf16 MFMA) ----------------
__global__ __launch_bounds__(256) void k_gemm1_mfma(const unsigned short* __restrict__ A,
                                                    const float* __restrict__ Win,
                                                    float* __restrict__ C) {
  __shared__ unsigned short As[128][136];
  __shared__ unsigned short Bs[64][136];
  int t = threadIdx.x;
  int bm = blockIdx.x * 128, bn = blockIdx.y * 64;
#pragma unroll
  for (int it = 0; it < 8; ++it) {
    int idx = t + it * 256;
    int r = idx >> 4, kc = idx & 15;
    short8v v = *(const short8v*)&A[(size_t)(bm + r) * 128 + kc * 8];
    *(short8v*)&As[r][kc * 8] = v;
  }
#pragma unroll
  for (int it = 0; it < 8; ++it) {
    int idx = t + it * 256;
    int r = idx >> 5, kq = idx & 31;
    float4 w = *(const float4*)&Win[(size_t)(bn + r) * 128 + kq * 4];
    ushort4 h;
    h.x = f2bf(w.x); h.y = f2bf(w.y); h.z = f2bf(w.z); h.w = f2bf(w.w);
    *(ushort4*)&Bs[r][kq * 4] = h;
  }
  __syncthreads();
  int lane = t & 63, w = t >> 6;
  int wm = (w & 1) * 64, wn = (w >> 1) * 32;
  int lr = lane & 15, lg = lane >> 4;
  f32x4 acc[4][2] = {};
#pragma unroll
  for (int k0 = 0; k0 < 128; k0 += 32) {
    short8v a[4], b[2];
#pragma unroll
    for (int mf = 0; mf < 4; ++mf)
      a[mf] = *(const short8v*)&As[wm + mf * 16 + lr][k0 + lg * 8];
#pragma unroll
    for (int nf = 0; nf < 2; ++nf)
      b[nf] = *(const short8v*)&Bs[wn + nf * 16 + lr][k0 + lg * 8];
#pragma unroll
    for (int mf = 0; mf < 4; ++mf)
#pragma unroll
      for (int nf = 0; nf < 2; ++nf)
        acc[mf][nf] = __builtin_amdgcn_mfma_f32_16x16x32_bf16(a[mf], b[nf], acc[mf][nf], 0, 0, 0);
  }
#pragma unroll
  for (int mf = 0; mf < 4; ++mf)
#pragma unroll
    for (int nf = 0; nf < 2; ++nf)
#pragma unroll
      for (int r = 0; r < 4; ++r) {
        size_t row = bm + wm + mf * 16 + lg * 4 + r;
        C[row * 512 + bn + wn + nf * 16 + lr] = acc[mf][nf][r];
      }
}

// ---------------- generic fp32 GEMM (GEMM2) ----------------
__global__ __launch_bounds__(256) void k_gemm_nt(const float* __restrict__ A,
                                                 const float* __restrict__ W,
                                                 float* __restrict__ C,
                                                 int M, int N, int K, int lda) {
  __shared__ float As[32][68];
  __shared__ float Ws[32][68];
  int tid = threadIdx.x;
  int bm = blockIdx.x * 64;
  int bn = blockIdx.y * 64;
  int tx = tid & 15, ty = tid >> 4;
  float acc[4][4] = {};
  for (int k0 = 0; k0 < K; k0 += 32) {
#pragma unroll
    for (int it = 0; it < 2; ++it) {
      int idx = tid + it * 256;
      int r = idx >> 3;
      int kq = idx & 7;
      float4 v = *(const float4*)&A[(size_t)(bm + r) * lda + k0 + kq * 4];
      As[kq * 4 + 0][r] = v.x; As[kq * 4 + 1][r] = v.y;
      As[kq * 4 + 2][r] = v.z; As[kq * 4 + 3][r] = v.w;
      int n = bn + r;
      float4 w = make_float4(0.f, 0.f, 0.f, 0.f);
      if (n < N) w = *(const float4*)&W[(size_t)n * K + k0 + kq * 4];
      Ws[kq * 4 + 0][r] = w.x; Ws[kq * 4 + 1][r] = w.y;
      Ws[kq * 4 + 2][r] = w.z; Ws[kq * 4 + 3][r] = w.w;
    }
    __syncthreads();
#pragma unroll
    for (int k = 0; k < 32; ++k) {
      float4 a = *(const float4*)&As[k][ty * 4];
      float4 w = *(const float4*)&Ws[k][tx * 4];
      float av[4] = {a.x, a.y, a.z, a.w};
      float wv[4] = {w.x, w.y, w.z, w.w};
#pragma unroll
      for (int i = 0; i < 4; ++i)
#pragma unroll
        for (int j = 0; j < 4; ++j)
          acc[i][j] = fmaf(av[i], wv[j], acc[i][j]);
    }
    __syncthreads();
  }
#pragma unroll
  for (int i = 0; i < 4; ++i) {
    size_t m = bm + ty * 4 + i;
#pragma unroll
    for (int j = 0; j < 4; ++j) {
      int n = bn + tx * 4 + j;
      if (n < N) C[m * N + n] = acc[i][j];
    }
  }
}

// ---------------- conv K=4 causal + silu -> xa ----------------
__global__ __launch_bounds__(256) void k_conv_silu(const float* __restrict__ xz,
                                                   const float* __restrict__ convw,
                                                   const float* __restrict__ convb,
                                                   float* __restrict__ xa) {
  int row = blockIdx.x;
  int l = row & 4095;
  int d = threadIdx.x;
  float4 w = *(const float4*)&convw[d * 4];
  float acc = convb[d];
  const float* p = xz + (size_t)row * 512 + d;
  if (l >= 3) acc = fmaf(w.x, p[-3 * 512], acc);
  if (l >= 2) acc = fmaf(w.y, p[-2 * 512], acc);
  if (l >= 1) acc = fmaf(w.z, p[-1 * 512], acc);
  acc = fmaf(w.w, p[0], acc);
  xa[(size_t)row * 256 + d] = siluf(acc);
}

// ---------------- scan phase 1 (v4): one thread per d, 16 n in regs ----------------
// grid = 4b * 128ch = 512 blocks; Pb/Qb layout [ch][b*4096 + d*16 + n]
__global__ __launch_bounds__(256) void k_scan_p1(const float* __restrict__ xa,
                                                 const float* __restrict__ xdbl,
                                                 const float* __restrict__ Wdt,
                                                 const float* __restrict__ dtb,
                                                 const float* __restrict__ Alog,
                                                 float* __restrict__ Pb,
                                                 float* __restrict__ Qb) {
  __shared__ f32x4 xrow[32][10];     // xdbl rows: dt(8) | B(16) | C(16)
  __shared__ float xas[32][256];
  int t = threadIdx.x;
  int blk = blockIdx.x;
  int ch = blk & 127, b = blk >> 7;
  size_t row0 = (size_t)b * 4096 + ch * 32;
  for (int i = t; i < 320; i += 256) {
    int s = i / 10, q = i - s * 10;
    xrow[s][q] = *(const f32x4*)&xdbl[(row0 + s) * 40 + q * 4];
  }
#pragma unroll
  for (int it = 0; it < 8; ++it) {
    int i = t + it * 256;
    int s = i >> 6, q = i & 63;
    *(f32x4*)&xas[s][q * 4] = *(const f32x4*)&xa[(row0 + s) * 256 + q * 4];
  }
  __syncthreads();
  int d = t;
  f32x4 w0 = *(const f32x4*)&Wdt[d * 8];
  f32x4 w1 = *(const f32x4*)&Wdt[d * 8 + 4];
  float bias = dtb[d];
  float A[16], P[16], Q[16];
#pragma unroll
  for (int g = 0; g < 4; ++g) {
    f32x4 al = *(const f32x4*)&Alog[d * 16 + g * 4];
#pragma unroll
    for (int j = 0; j < 4; ++j) {
      A[g * 4 + j] = -__expf(al[j]);
      P[g * 4 + j] = 1.f;
      Q[g * 4 + j] = 0.f;
    }
  }
#pragma unroll 2
  for (int s = 0; s < 32; ++s) {
    f32x4 x0 = xrow[s][0], x1 = xrow[s][1];
    float v = bias;
#pragma unroll
    for (int j = 0; j < 4; ++j) v = fmaf(x0[j], w0[j], v);
#pragma unroll
    for (int j = 0; j < 4; ++j) v = fmaf(x1[j], w1[j], v);
    float ex = __expf(v);
    float dtv = (v > 20.f) ? v : __logf(1.f + ex);
    float du = dtv * xas[s][d];
    f32x4 bm[4];
#pragma unroll
    for (int g = 0; g < 4; ++g) bm[g] = xrow[s][2 + g];
#pragma unroll
    for (int n = 0; n < 16; ++n) {
      float e = __expf(dtv * A[n]);
      Q[n] = fmaf(e, Q[n], du * bm[n >> 2][n & 3]);
      P[n] *= e;
    }
  }
  size_t ob = (size_t)ch * 16384 + b * 4096 + d * 16;
#pragma unroll
  for (int g = 0; g < 4; ++g) {
    *(f32x4*)&Pb[ob + g * 4] = *(f32x4*)&P[g * 4];
    *(f32x4*)&Qb[ob + g * 4] = *(f32x4*)&Q[g * 4];
  }
}

// ---------------- scan phase 2: serial combine, 1 thread per (b,d,n) ----------------
__global__ __launch_bounds__(256) void k_scan_p2(const float* __restrict__ Pb,
                                                 const float* __restrict__ Qb,
                                                 float* __restrict__ Hin) {
  int t = blockIdx.x * 256 + threadIdx.x;   // 16384
  float h = 0.f;
  size_t o = t;
#pragma unroll 8
  for (int ch = 0; ch < 128; ++ch) {
    Hin[o] = h;
    h = fmaf(Pb[o], h, Qb[o]);
    o += 16384;
  }
}

// ---------------- scan phase 3 (v4): recompute; ym written to separate buffer ----------------
__global__ __launch_bounds__(256) void k_scan_p3(const float* __restrict__ xa,
                                                 const float* __restrict__ xdbl,
                                                 const float* __restrict__ Wdt,
                                                 const float* __restrict__ dtb,
                                                 const float* __restrict__ Alog,
                                                 const float* __restrict__ Hin,
                                                 const float* __restrict__ Dp,
                                                 const float* __restrict__ xz,
                                                 float* __restrict__ ym) {
  __shared__ f32x4 xrow[32][10];
  __shared__ float xas[32][256];
  int t = threadIdx.x;
  int blk = blockIdx.x;
  int ch = blk & 127, b = blk >> 7;
  size_t row0 = (size_t)b * 4096 + ch * 32;
  for (int i = t; i < 320; i += 256) {
    int s = i / 10, q = i - s * 10;
    xrow[s][q] = *(const f32x4*)&xdbl[(row0 + s) * 40 + q * 4];
  }
#pragma unroll
  for (int it = 0; it < 8; ++it) {
    int i = t + it * 256;
    int s = i >> 6, q = i & 63;
    *(f32x4*)&xas[s][q * 4] = *(const f32x4*)&xa[(row0 + s) * 256 + q * 4];
  }
  __syncthreads();
  int d = t;
  f32x4 w0 = *(const f32x4*)&Wdt[d * 8];
  f32x4 w1 = *(const f32x4*)&Wdt[d * 8 + 4];
  float bias = dtb[d];
  float Dd = Dp[d];
  float A[16], h[16];
  size_t hb = (size_t)ch * 16384 + b * 4096 + d * 16;
#pragma unroll
  for (int g = 0; g < 4; ++g) {
    f32x4 al = *(const f32x4*)&Alog[d * 16 + g * 4];
    f32x4 hv = *(const f32x4*)&Hin[hb + g * 4];
#pragma unroll
    for (int j = 0; j < 4; ++j) {
      A[g * 4 + j] = -__expf(al[j]);
      h[g * 4 + j] = hv[j];
    }
  }
  const float* zp = xz + row0 * 512 + 256 + d;
  float* yo = ym + row0 * 256 + d;
#pragma unroll 2
  for (int s = 0; s < 32; ++s) {
    f32x4 x0 = xrow[s][0], x1 = xrow[s][1];
    float v = bias;
#pragma unroll
    for (int j = 0; j < 4; ++j) v = fmaf(x0[j], w0[j], v);
#pragma unroll
    for (int j = 0; j < 4; ++j) v = fmaf(x1[j], w1[j], v);
    float ex = __expf(v);
    float dtv = (v > 20.f) ? v : __logf(1.f + ex);
    float xav = xas[s][d];
    float du = dtv * xav;
    f32x4 bm[4], cm[4];
#pragma unroll
    for (int g = 0; g < 4; ++g) { bm[g] = xrow[s][2 + g]; cm[g] = xrow[s][6 + g]; }
    float y0 = 0.f, y1 = 0.f, y2 = 0.f, y3 = 0.f;
#pragma unroll
    for (int n = 0; n < 16; n += 4) {
      float e0 = __expf(dtv * A[n]);
      float e1 = __expf(dtv * A[n + 1]);
      float e2 = __expf(dtv * A[n + 2]);
      float e3 = __expf(dtv * A[n + 3]);
      f32x4 bv = bm[n >> 2], cv = cm[n >> 2];
      h[n]     = fmaf(e0, h[n],     du * bv[0]);
      h[n + 1] = fmaf(e1, h[n + 1], du * bv[1]);
      h[n + 2] = fmaf(e2, h[n + 2], du * bv[2]);
      h[n + 3] = fmaf(e3, h[n + 3], du * bv[3]);
      y0 = fmaf(h[n], cv[0], y0);
      y1 = fmaf(h[n + 1], cv[1], y1);
      y2 = fmaf(h[n + 2], cv[2], y2);
      y3 = fmaf(h[n + 3], cv[3], y3);
    }
    float y = (y0 + y1) + (y2 + y3) + Dd * xav;
    float z = zp[s * 512];
    yo[s * 256] = y * siluf(z);
  }
}

// ---------------- GEMM3: out1T[32][16384] = (ym @ WoutEff^T)^T, WoutEff fused ----------------
__global__ __launch_bounds__(256) void k_gemm3(const float* __restrict__ A,      // ym [16384][256]
                                               const float* __restrict__ Wout,
                                               float* __restrict__ CT) {
  __shared__ float As[32][68];
  __shared__ float Ws[32][68];
  int tid = threadIdx.x;
  int bm = blockIdx.x * 64;
  int tx = tid & 15, ty = tid >> 4;
  float acc[4][4] = {};
  for (int k0 = 0; k0 < 256; k0 += 32) {
#pragma unroll
    for (int it = 0; it < 2; ++it) {
      int idx = tid + it * 256;
      int r = idx >> 3;
      int kq = idx & 7;
      float4 v = *(const float4*)&A[(size_t)(bm + r) * 256 + k0 + kq * 4];
      As[kq * 4 + 0][r] = v.x; As[kq * 4 + 1][r] = v.y;
      As[kq * 4 + 2][r] = v.z; As[kq * 4 + 3][r] = v.w;
      float4 w = make_float4(0.f, 0.f, 0.f, 0.f);
      if (r < 32) {
#pragma unroll
        for (int g = 0; g < 4; ++g) {
          float4 wg = *(const float4*)&Wout[(size_t)(r + g * 32) * 256 + k0 + kq * 4];
          w.x += wg.x; w.y += wg.y; w.z += wg.z; w.w += wg.w;
        }
      }
      Ws[kq * 4 + 0][r] = w.x; Ws[kq * 4 + 1][r] = w.y;
      Ws[kq * 4 + 2][r] = w.z; Ws[kq * 4 + 3][r] = w.w;
    }
    __syncthreads();
#pragma unroll
    for (int k = 0; k < 32; ++k) {
      float4 a = *(const float4*)&As[k][ty * 4];
      float4 w = *(const float4*)&Ws[k][tx * 4];
      float av[4] = {a.x, a.y, a.z, a.w};
      float wv[4] = {w.x, w.y, w.z, w.w};
#pragma unroll
      for (int i = 0; i < 4; ++i)
#pragma unroll
        for (int j = 0; j < 4; ++j)
          acc[i][j] = fmaf(av[i], wv[j], acc[i][j]);
    }
    __syncthreads();
  }
#pragma unroll
  for (int j = 0; j < 4; ++j) {
    int n = tx * 4 + j;
    if (n < 32) {
      float4 v = make_float4(acc[0][j], acc[1][j], acc[2][j], acc[3][j]);
      *(float4*)&CT[(size_t)n * 16384 + bm + ty * 4] = v;
    }
  }
}

// ---------------- residual + foc (fused) ----------------
__global__ __launch_bounds__(256) void k_res_foc(const float* __restrict__ CT,
                                                 const float* __restrict__ fo2,
                                                 float* __restrict__ res,
                                                 float* __restrict__ foc) {
  int bc = blockIdx.x;
  int b = bc >> 5, c = bc & 31;
  int t = threadIdx.x;
  const float* src = CT + (size_t)c * 16384 + (size_t)b * 4096;
  const float* f2 = fo2 + (size_t)bc * 4096;
  float* rp = res + (size_t)bc * 4096;
  float s = 0.f;
  for (int i = t * 4; i < 4096; i += 1024) {
    float4 a = *(const float4*)&src[i];
    float4 f = *(const float4*)&f2[i];
    float4 r = make_float4(a.x * f.x, a.y * f.y, a.z * f.z, a.w * f.w);
    *(float4*)&rp[i] = r;
    s += r.x + r.y + r.z + r.w;
  }
  __shared__ float red[256];
  red[t] = s;
  __syncthreads();
  for (int off = 128; off > 0; off >>= 1) {
    if (t < off) red[t] += red[t + off];
    __syncthreads();
  }
  if (t == 0) foc[bc] = red[0] * (1.f / 4096.f);
}

// ---------------- mamba2 (tiny): one block ----------------
__global__ __launch_bounds__(256) void k_mamba2(const float* __restrict__ foc,
                                                const float* __restrict__ Win2,
                                                const float* __restrict__ convw2,
                                                const float* __restrict__ convb2,
                                                const float* __restrict__ Wx2,
                                                const float* __restrict__ Wdt2,
                                                const float* __restrict__ dtb2,
                                                const float* __restrict__ Alog2,
                                                const float* __restrict__ D2,
                                                const float* __restrict__ Wout2,
                                                float* __restrict__ scale) {
  __shared__ float foc_s[128];
  __shared__ float xz2_s[4][32][8];
  __shared__ float xa2_s[4][32][4];
  __shared__ float xdbl2_s[4][32][33];
  __shared__ float dt2_s[4][32][4];
  __shared__ float ym2_s[4][32][4];
  int t = threadIdx.x;
  if (t < 128) foc_s[t] = foc[t];
  __syncthreads();
  for (int i = t; i < 1024; i += 256) {
    int j = i & 7, l = (i >> 3) & 31, b = i >> 8;
    float x0 = foc_s[b * 32 + l], x1 = foc_s[b * 32 + 31 - l];
    xz2_s[b][l][j] = x0 * Win2[j * 2] + x1 * Win2[j * 2 + 1];
  }
  __syncthreads();
  for (int i = t; i < 512; i += 256) {
    int d = i & 3, l = (i >> 2) & 31, b = i >> 7;
    float acc = convb2[d];
#pragma unroll
    for (int k = 0; k < 4; ++k) {
      int ls = l + k - 3;
      if (ls >= 0) acc = fmaf(convw2[d * 4 + k], xz2_s[b][ls][d], acc);
    }
    xa2_s[b][l][d] = siluf(acc);
  }
  __syncthreads();
  for (int i = t; i < 4224; i += 256) {
    int r = i % 33, l = (i / 33) & 31, b = i / 1056;
    float s = 0.f;
#pragma unroll
    for (int d = 0; d < 4; ++d) s = fmaf(xa2_s[b][l][d], Wx2[r * 4 + d], s);
    xdbl2_s[b][l][r] = s;
  }
  __syncthreads();
  for (int i = t; i < 512; i += 256) {
    int d = i & 3, l = (i >> 2) & 31, b = i >> 7;
    float s = xdbl2_s[b][l][0] * Wdt2[d] + dtb2[d];
    dt2_s[b][l][d] = softplusf(s);
  }
  __syncthreads();
  {
    int n = t & 15, d = (t >> 4) & 3, b = t >> 6;
    float A = -__expf(Alog2[d * 16 + n]);
    float h = 0.f;
    for (int l = 0; l < 32; ++l) {
      float dtv = dt2_s[b][l][d];
      float xav = xa2_s[b][l][d];
      float e = __expf(dtv * A);
      h = fmaf(e, h, dtv * xdbl2_s[b][l][1 + n] * xav);
      float yp = h * xdbl2_s[b][l][17 + n];
      yp += __shfl_xor(yp, 1);
      yp += __shfl_xor(yp, 2);
      yp += __shfl_xor(yp, 4);
      yp += __shfl_xor(yp, 8);
      if (n == 0) {
        float z = xz2_s[b][l][4 + d];
        float y = yp + D2[d] * xav;
        ym2_s[b][l][d] = y * siluf(z);
      }
    }
  }
  __syncthreads();
  if (t < 128) {
    int l = t & 31, b = t >> 5;
    float s = 0.f;
#pragma unroll
    for (int d = 0; d < 4; ++d) s = fmaf(ym2_s[b][l][d], Wout2[d] + Wout2[4 + d], s);
    scale[t] = s;
  }
}

// ---------------- final: out = res * (1 + scale[b,c]) ----------------
__global__ __launch_bounds__(256) void k_final(const float* __restrict__ res,
                                               const float* __restrict__ scale,
                                               float* __restrict__ out) {
  int idx = blockIdx.x * 256 + threadIdx.x;
  out[idx] = res[idx] * (1.f + scale[idx >> 12]);
}

extern "C" void kernel_launch(void* const* d_in, const int* in_sizes, int n_in,
                              void* d_out, int out_size, void* d_ws, size_t ws_size,
                              hipStream_t stream) {
  const float* fo1    = (const float*)d_in[0];
  const float* fo2    = (const float*)d_in[1];
  const float* Win    = (const float*)d_in[2];
  const float* convw  = (const float*)d_in[3];
  const float* convb  = (const float*)d_in[4];
  const float* Wx     = (const float*)d_in[5];
  const float* Wdt    = (const float*)d_in[6];
  const float* dtb    = (const float*)d_in[7];
  const float* Alog   = (const float*)d_in[8];
  const float* Dp     = (const float*)d_in[9];
  const float* Wout   = (const float*)d_in[10];
  const float* Win2   = (const float*)d_in[11];
  const float* convw2 = (const float*)d_in[12];
  const float* convb2 = (const float*)d_in[13];
  const float* Wx2    = (const float*)d_in[14];
  const float* Wdt2   = (const float*)d_in[15];
  const float* dtb2   = (const float*)d_in[16];
  const float* Alog2  = (const float*)d_in[17];
  const float* D2     = (const float*)d_in[18];
  const float* Wout2  = (const float*)d_in[19];

  float* ws = (float*)d_ws;
  unsigned short* fopb = (unsigned short*)ws;   // 2M bf16 = 1,048,576 float-slots
  float* xdbl = ws;                             // alias, reused after gemm1
  float* xz   = ws + 1048576;                   // 8,388,608
  float* xa   = ws + 9437184;                   // 4,194,304
  float* Pb   = ws + 13631488;                  // 2,097,152  [ch][16384]
  float* Qb   = ws + 15728640;                  // 2,097,152
  float* Hin  = ws + 17825792;                  // 2,097,152
  float* ym   = ws + 19922944;                  // 4,194,304  [16384][256]
  float* o1T  = ws + 24117248;                  //   524,288
  float* res  = ws + 24641536;                  //   524,288
  float* foc  = ws + 25165824;                  //       128
  float* scl  = ws + 25165952;                  //       128
  if (ws_size < (size_t)25166080 * sizeof(float)) return;  // ~101 MB scratch

  hipLaunchKernelGGL(k_build_fop, dim3(8192), dim3(256), 0, stream, fo1, fopb);
  hipLaunchKernelGGL(k_gemm1_mfma, dim3(128, 8), dim3(256), 0, stream, fopb, Win, xz);
  hipLaunchKernelGGL(k_conv_silu, dim3(16384), dim3(256), 0, stream, xz, convw, convb, xa);
  hipLaunchKernelGGL(k_gemm_nt, dim3(256, 1), dim3(256), 0, stream,
                     xa, Wx, xdbl, 16384, 40, 256, 256);
  hipLaunchKernelGGL(k_scan_p1, dim3(512), dim3(256), 0, stream,
                     xa, xdbl, Wdt, dtb, Alog, Pb, Qb);
  hipLaunchKernelGGL(k_scan_p2, dim3(64), dim3(256), 0, stream, Pb, Qb, Hin);
  hipLaunchKernelGGL(k_scan_p3, dim3(512), dim3(256), 0, stream,
                     xa, xdbl, Wdt, dtb, Alog, Hin, Dp, xz, ym);
  hipLaunchKernelGGL(k_gemm3, dim3(256), dim3(256), 0, stream, ym, Wout, o1T);
  hipLaunchKernelGGL(k_res_foc, dim3(128), dim3(256), 0, stream, o1T, fo2, res, foc);
  hipLaunchKernelGGL(k_mamba2, dim3(1), dim3(256), 0, stream, foc, Win2, convw2, convb2,
                     Wx2, Wdt2, dtb2, Alog2, D2, Wout2, scl);
  hipLaunchKernelGGL(k_final, dim3(2048), dim3(256), 0, stream, res, scl, (float*)d_out);
}

// Round 6
// 146.702 us; speedup vs baseline: 1.5141x; 1.0635x over previous
//
#include <hip/hip_runtime.h>
#include <cstddef>

// (B,C,H,W)=(4,32,64,64), D_STATE=16, D_CONV=4
// Mamba1: L=4096, d_model=128, d_in=256, dt_rank=8, xdbl width 40
// Round 6: fused front (conv+gemm2+scan_p1), fused p3 (conv recompute),
//          bf16 ym + MFMA gemm3 fused with residual/foc partials.

typedef __attribute__((ext_vector_type(8))) short short8v;
typedef __attribute__((ext_vector_type(4))) float f32x4;

__device__ __forceinline__ float siluf(float x) { return x / (1.f + __expf(-x)); }
__device__ __forceinline__ float softplusf(float x) { return (x > 20.f) ? x : log1pf(__expf(x)); }
__device__ __forceinline__ unsigned short f2bf(float f) {
  union { float f; unsigned int u; } v; v.f = f;
  unsigned int r = v.u + 0x7fff + ((v.u >> 16) & 1);
  return (unsigned short)(r >> 16);
}

// ---------------- K0: build fop (B, L, 128) bf16 from fo1 (B,C,H,W) ----------------
__global__ __launch_bounds__(256) void k_build_fop(const float* __restrict__ fo1,
                                                   unsigned short* __restrict__ fopb) {
  int idx = blockIdx.x * 256 + threadIdx.x;   // 2^21
  int j = idx & 127;
  int l = (idx >> 7) & 4095;
  int b = idx >> 19;
  int g = j >> 5, c = j & 31;
  const float* base = fo1 + (size_t)(b * 32 + c) * 4096;
  int li;
  if (g == 0)      li = l;
  else if (g == 1) li = 4095 - l;
  else if (g == 2) li = ((l & 63) << 6) + (l >> 6);
  else { int i2 = 4095 - l; li = ((i2 & 63) << 6) + (i2 >> 6); }
  fopb[idx] = f2bf(base[li]);
}

// ---------------- GEMM1: xz[16384][512] = fopb @ Win^T (bf16 MFMA) ----------------
__global__ __launch_bounds__(256) void k_gemm1_mfma(const unsigned short* __restrict__ A,
                                                    const float* __restrict__ Win,
                                                    float* __restrict__ C) {
  __shared__ unsigned short As[128][136];
  __shared__ unsigned short Bs[64][136];
  int t = threadIdx.x;
  int bm = blockIdx.x * 128, bn = blockIdx.y * 64;
#pragma unroll
  for (int it = 0; it < 8; ++it) {
    int idx = t + it * 256;
    int r = idx >> 4, kc = idx & 15;
    short8v v = *(const short8v*)&A[(size_t)(bm + r) * 128 + kc * 8];
    *(short8v*)&As[r][kc * 8] = v;
  }
#pragma unroll
  for (int it = 0; it < 8; ++it) {
    int idx = t + it * 256;
    int r = idx >> 5, kq = idx & 31;
    float4 w = *(const float4*)&Win[(size_t)(bn + r) * 128 + kq * 4];
    ushort4 h;
    h.x = f2bf(w.x); h.y = f2bf(w.y); h.z = f2bf(w.z); h.w = f2bf(w.w);
    *(ushort4*)&Bs[r][kq * 4] = h;
  }
  __syncthreads();
  int lane = t & 63, w = t >> 6;
  int wm = (w & 1) * 64, wn = (w >> 1) * 32;
  int lr = lane & 15, lg = lane >> 4;
  f32x4 acc[4][2] = {};
#pragma unroll
  for (int k0 = 0; k0 < 128; k0 += 32) {
    short8v a[4], b[2];
#pragma unroll
    for (int mf = 0; mf < 4; ++mf)
      a[mf] = *(const short8v*)&As[wm + mf * 16 + lr][k0 + lg * 8];
#pragma unroll
    for (int nf = 0; nf < 2; ++nf)
      b[nf] = *(const short8v*)&Bs[wn + nf * 16 + lr][k0 + lg * 8];
#pragma unroll
    for (int mf = 0; mf < 4; ++mf)
#pragma unroll
      for (int nf = 0; nf < 2; ++nf)
        acc[mf][nf] = __builtin_amdgcn_mfma_f32_16x16x32_bf16(a[mf], b[nf], acc[mf][nf], 0, 0, 0);
  }
#pragma unroll
  for (int mf = 0; mf < 4; ++mf)
#pragma unroll
    for (int nf = 0; nf < 2; ++nf)
#pragma unroll
      for (int r = 0; r < 4; ++r) {
        size_t row = bm + wm + mf * 16 + lg * 4 + r;
        C[row * 512 + bn + wn + nf * 16 + lr] = acc[mf][nf][r];
      }
}

// ---------------- k_front: conv+silu + gemm2(Wx) + scan phase1 fused ----------------
// grid = 512 (b = blk>>7, ch = blk&127); 256 threads
__global__ __launch_bounds__(256) void k_front(const float* __restrict__ xz,
                                               const float* __restrict__ convw,
                                               const float* __restrict__ convb,
                                               const float* __restrict__ Wx,
                                               const float* __restrict__ Wdt,
                                               const float* __restrict__ dtb,
                                               const float* __restrict__ Alog,
                                               float* __restrict__ xdbl_g,
                                               float* __restrict__ Pb,
                                               float* __restrict__ Qb) {
  __shared__ float bufU[10400];        // xcs[35][260] then Wxs[40][260]
  __shared__ float xas[32][260];
  __shared__ float xdbl_s[32][40];
  int t = threadIdx.x;
  int blk = blockIdx.x;
  int ch = blk & 127, b = blk >> 7;
  size_t row0 = (size_t)b * 4096 + ch * 32;

  // phase 0: stage xc rows row0-3 .. row0+31 (zero-pad at chunk 0)
  for (int i = t; i < 8960; i += 256) {
    int rr = i >> 8, c = i & 255;
    float v = 0.f;
    if (ch > 0 || rr >= 3) v = xz[(row0 - 3 + rr) * 512 + c];
    bufU[rr * 260 + c] = v;
  }
  __syncthreads();
  // phase 1: conv + silu -> xas
  {
    int s = t >> 3, dg = t & 7;
#pragma unroll 8
    for (int j = 0; j < 32; ++j) {
      int d = dg + 8 * j;
      float4 w = *(const float4*)&convw[d * 4];
      float acc = convb[d];
      acc = fmaf(w.x, bufU[(s + 0) * 260 + d], acc);
      acc = fmaf(w.y, bufU[(s + 1) * 260 + d], acc);
      acc = fmaf(w.z, bufU[(s + 2) * 260 + d], acc);
      acc = fmaf(w.w, bufU[(s + 3) * 260 + d], acc);
      xas[s][d] = siluf(acc);
    }
  }
  __syncthreads();
  // phase 2: stage Wx[40][256] into bufU (stride 260)
  for (int i = t; i < 10400; i += 256) {
    int r = i / 260, c = i - r * 260;
    bufU[i] = (c < 256) ? Wx[r * 256 + c] : 0.f;
  }
  __syncthreads();
  // phase 3: gemm2  xdbl[s][r] = xa[s][:] . Wx[r][:]
  {
    int s = t >> 3, tg = t & 7;
    float a0 = 0.f, a1 = 0.f, a2 = 0.f, a3 = 0.f, a4 = 0.f;
    for (int d4 = 0; d4 < 64; ++d4) {
      f32x4 xv = *(const f32x4*)&xas[s][d4 * 4];
      f32x4 w0 = *(const f32x4*)&bufU[(tg) * 260 + d4 * 4];
      f32x4 w1 = *(const f32x4*)&bufU[(tg + 8) * 260 + d4 * 4];
      f32x4 w2 = *(const f32x4*)&bufU[(tg + 16) * 260 + d4 * 4];
      f32x4 w3 = *(const f32x4*)&bufU[(tg + 24) * 260 + d4 * 4];
      f32x4 w4 = *(const f32x4*)&bufU[(tg + 32) * 260 + d4 * 4];
#pragma unroll
      for (int j = 0; j < 4; ++j) {
        a0 = fmaf(xv[j], w0[j], a0);
        a1 = fmaf(xv[j], w1[j], a1);
        a2 = fmaf(xv[j], w2[j], a2);
        a3 = fmaf(xv[j], w3[j], a3);
        a4 = fmaf(xv[j], w4[j], a4);
      }
    }
    xdbl_s[s][tg]      = a0;
    xdbl_s[s][tg + 8]  = a1;
    xdbl_s[s][tg + 16] = a2;
    xdbl_s[s][tg + 24] = a3;
    xdbl_s[s][tg + 32] = a4;
  }
  __syncthreads();
  // phase 4: write xdbl to global (for p3) + scan p1
  for (int i = t; i < 1280; i += 256)
    xdbl_g[row0 * 40 + i] = ((const float*)xdbl_s)[i];
  {
    int d = t;
    f32x4 w0 = *(const f32x4*)&Wdt[d * 8];
    f32x4 w1 = *(const f32x4*)&Wdt[d * 8 + 4];
    float bias = dtb[d];
    float A[16], P[16], Q[16];
#pragma unroll
    for (int g = 0; g < 4; ++g) {
      f32x4 al = *(const f32x4*)&Alog[d * 16 + g * 4];
#pragma unroll
      for (int j = 0; j < 4; ++j) {
        A[g * 4 + j] = -__expf(al[j]);
        P[g * 4 + j] = 1.f;
        Q[g * 4 + j] = 0.f;
      }
    }
#pragma unroll 2
    for (int s = 0; s < 32; ++s) {
      f32x4 x0 = *(const f32x4*)&xdbl_s[s][0];
      f32x4 x1 = *(const f32x4*)&xdbl_s[s][4];
      float v = bias;
#pragma unroll
      for (int j = 0; j < 4; ++j) v = fmaf(x0[j], w0[j], v);
#pragma unroll
      for (int j = 0; j < 4; ++j) v = fmaf(x1[j], w1[j], v);
      float ex = __expf(v);
      float dtv = (v > 20.f) ? v : __logf(1.f + ex);
      float du = dtv * xas[s][d];
      f32x4 bm[4];
#pragma unroll
      for (int g = 0; g < 4; ++g) bm[g] = *(const f32x4*)&xdbl_s[s][8 + g * 4];
#pragma unroll
      for (int n = 0; n < 16; ++n) {
        float e = __expf(dtv * A[n]);
        Q[n] = fmaf(e, Q[n], du * bm[n >> 2][n & 3]);
        P[n] *= e;
      }
    }
    size_t ob = (size_t)ch * 16384 + b * 4096 + d * 16;
#pragma unroll
    for (int g = 0; g < 4; ++g) {
      *(f32x4*)&Pb[ob + g * 4] = *(f32x4*)&P[g * 4];
      *(f32x4*)&Qb[ob + g * 4] = *(f32x4*)&Q[g * 4];
    }
  }
}

// ---------------- scan phase 2: serial combine, 1 thread per (b,d,n) ----------------
__global__ __launch_bounds__(256) void k_scan_p2(const float* __restrict__ Pb,
                                                 const float* __restrict__ Qb,
                                                 float* __restrict__ Hin) {
  int t = blockIdx.x * 256 + threadIdx.x;   // 16384
  float h = 0.f;
  size_t o = t;
#pragma unroll 8
  for (int ch = 0; ch < 128; ++ch) {
    Hin[o] = h;
    h = fmaf(Pb[o], h, Qb[o]);
    o += 16384;
  }
}

// ---------------- scan phase 3: conv recompute + scan + y*silu(z) -> ym (bf16) ----------------
__global__ __launch_bounds__(256) void k_scan_p3(const float* __restrict__ xz,
                                                 const float* __restrict__ convw,
                                                 const float* __restrict__ convb,
                                                 const float* __restrict__ xdbl_g,
                                                 const float* __restrict__ Wdt,
                                                 const float* __restrict__ dtb,
                                                 const float* __restrict__ Alog,
                                                 const float* __restrict__ Hin,
                                                 const float* __restrict__ Dp,
                                                 unsigned short* __restrict__ ym) {
  __shared__ float xcs[9100];          // [35][260]
  __shared__ float xas[32][260];
  __shared__ float xrow[1280];         // [32][40]
  int t = threadIdx.x;
  int blk = blockIdx.x;
  int ch = blk & 127, b = blk >> 7;
  size_t row0 = (size_t)b * 4096 + ch * 32;

  for (int i = t; i < 8960; i += 256) {
    int rr = i >> 8, c = i & 255;
    float v = 0.f;
    if (ch > 0 || rr >= 3) v = xz[(row0 - 3 + rr) * 512 + c];
    xcs[rr * 260 + c] = v;
  }
  for (int i = t; i < 1280; i += 256) xrow[i] = xdbl_g[row0 * 40 + i];
  __syncthreads();
  {
    int s = t >> 3, dg = t & 7;
#pragma unroll 8
    for (int j = 0; j < 32; ++j) {
      int d = dg + 8 * j;
      float4 w = *(const float4*)&convw[d * 4];
      float acc = convb[d];
      acc = fmaf(w.x, xcs[(s + 0) * 260 + d], acc);
      acc = fmaf(w.y, xcs[(s + 1) * 260 + d], acc);
      acc = fmaf(w.z, xcs[(s + 2) * 260 + d], acc);
      acc = fmaf(w.w, xcs[(s + 3) * 260 + d], acc);
      xas[s][d] = siluf(acc);
    }
  }
  __syncthreads();
  int d = t;
  f32x4 w0 = *(const f32x4*)&Wdt[d * 8];
  f32x4 w1 = *(const f32x4*)&Wdt[d * 8 + 4];
  float bias = dtb[d];
  float Dd = Dp[d];
  float A[16], h[16];
  size_t hb = (size_t)ch * 16384 + b * 4096 + d * 16;
#pragma unroll
  for (int g = 0; g < 4; ++g) {
    f32x4 al = *(const f32x4*)&Alog[d * 16 + g * 4];
    f32x4 hv = *(const f32x4*)&Hin[hb + g * 4];
#pragma unroll
    for (int j = 0; j < 4; ++j) {
      A[g * 4 + j] = -__expf(al[j]);
      h[g * 4 + j] = hv[j];
    }
  }
  const float* zp = xz + row0 * 512 + 256 + d;
  unsigned short* yo = ym + row0 * 256 + d;
#pragma unroll 2
  for (int s = 0; s < 32; ++s) {
    f32x4 x0 = *(const f32x4*)&xrow[s * 40];
    f32x4 x1 = *(const f32x4*)&xrow[s * 40 + 4];
    float v = bias;
#pragma unroll
    for (int j = 0; j < 4; ++j) v = fmaf(x0[j], w0[j], v);
#pragma unroll
    for (int j = 0; j < 4; ++j) v = fmaf(x1[j], w1[j], v);
    float ex = __expf(v);
    float dtv = (v > 20.f) ? v : __logf(1.f + ex);
    float xav = xas[s][d];
    float du = dtv * xav;
    float y0 = 0.f, y1 = 0.f, y2 = 0.f, y3 = 0.f;
#pragma unroll
    for (int n = 0; n < 16; n += 4) {
      f32x4 bv = *(const f32x4*)&xrow[s * 40 + 8 + n];
      f32x4 cv = *(const f32x4*)&xrow[s * 40 + 24 + n];
      float e0 = __expf(dtv * A[n]);
      float e1 = __expf(dtv * A[n + 1]);
      float e2 = __expf(dtv * A[n + 2]);
      float e3 = __expf(dtv * A[n + 3]);
      h[n]     = fmaf(e0, h[n],     du * bv[0]);
      h[n + 1] = fmaf(e1, h[n + 1], du * bv[1]);
      h[n + 2] = fmaf(e2, h[n + 2], du * bv[2]);
      h[n + 3] = fmaf(e3, h[n + 3], du * bv[3]);
      y0 = fmaf(h[n], cv[0], y0);
      y1 = fmaf(h[n + 1], cv[1], y1);
      y2 = fmaf(h[n + 2], cv[2], y2);
      y3 = fmaf(h[n + 3], cv[3], y3);
    }
    float y = (y0 + y1) + (y2 + y3) + Dd * xav;
    float z = zp[s * 512];
    yo[s * 256] = f2bf(y * siluf(z));
  }
}

// ---------------- gemm3+residual+foc: MFMA bf16, WoutEff fused, res & foc partials ----------------
// grid 256 (m-tiles of 64); block 256 = 4 waves, wave tile 16M x 32N
__global__ __launch_bounds__(256) void k_gemm3res(const unsigned short* __restrict__ ym,
                                                  const float* __restrict__ Wout,
                                                  const float* __restrict__ fo2,
                                                  float* __restrict__ res,
                                                  float* __restrict__ focp) {
  __shared__ unsigned short As[64][264];
  __shared__ unsigned short Bs[32][264];
  __shared__ float fred[4][32];
  int t = threadIdx.x;
  int bm = blockIdx.x * 64;
#pragma unroll
  for (int it = 0; it < 8; ++it) {
    int idx = t + it * 256;
    int r = idx >> 5, kc = idx & 31;
    *(short8v*)&As[r][kc * 8] = *(const short8v*)&ym[(size_t)(bm + r) * 256 + kc * 8];
  }
#pragma unroll
  for (int it = 0; it < 32; ++it) {
    int idx = t + it * 256;
    int n = idx >> 8, k = idx & 255;
    float wv = Wout[(size_t)n * 256 + k] + Wout[(size_t)(n + 32) * 256 + k] +
               Wout[(size_t)(n + 64) * 256 + k] + Wout[(size_t)(n + 96) * 256 + k];
    Bs[n][k] = f2bf(wv);
  }
  __syncthreads();
  int lane = t & 63, w = t >> 6;
  int lr = lane & 15, lg = lane >> 4;
  f32x4 acc0 = {}, acc1 = {};
#pragma unroll
  for (int k0 = 0; k0 < 256; k0 += 32) {
    short8v a  = *(const short8v*)&As[w * 16 + lr][k0 + lg * 8];
    short8v b0 = *(const short8v*)&Bs[lr][k0 + lg * 8];
    short8v b1 = *(const short8v*)&Bs[16 + lr][k0 + lg * 8];
    acc0 = __builtin_amdgcn_mfma_f32_16x16x32_bf16(a, b0, acc0, 0, 0, 0);
    acc1 = __builtin_amdgcn_mfma_f32_16x16x32_bf16(a, b1, acc1, 0, 0, 0);
  }
  int b = bm >> 12;
  float ps0 = 0.f, ps1 = 0.f;
#pragma unroll
  for (int r = 0; r < 4; ++r) {
    int l = (bm + w * 16 + lg * 4 + r) & 4095;
    size_t ri0 = ((size_t)(b * 32 + lr)) * 4096 + l;
    size_t ri1 = ((size_t)(b * 32 + 16 + lr)) * 4096 + l;
    float v0 = acc0[r] * fo2[ri0];
    float v1 = acc1[r] * fo2[ri1];
    res[ri0] = v0; ps0 += v0;
    res[ri1] = v1; ps1 += v1;
  }
  ps0 += __shfl_xor(ps0, 16); ps0 += __shfl_xor(ps0, 32);
  ps1 += __shfl_xor(ps1, 16); ps1 += __shfl_xor(ps1, 32);
  if (lane < 16) { fred[w][lane] = ps0; fred[w][16 + lane] = ps1; }
  __syncthreads();
  if (t < 32)
    focp[((size_t)(b * 32 + t)) * 64 + (blockIdx.x & 63)] =
        fred[0][t] + fred[1][t] + fred[2][t] + fred[3][t];
}

// ---------------- mamba2 (tiny): one block; foc = sum(focp)/4096 ----------------
__global__ __launch_bounds__(256) void k_mamba2(const float* __restrict__ focp,
                                                const float* __restrict__ Win2,
                                                const float* __restrict__ convw2,
                                                const float* __restrict__ convb2,
                                                const float* __restrict__ Wx2,
                                                const float* __restrict__ Wdt2,
                                                const float* __restrict__ dtb2,
                                                const float* __restrict__ Alog2,
                                                const float* __restrict__ D2,
                                                const float* __restrict__ Wout2,
                                                float* __restrict__ scale) {
  __shared__ float foc_s[128];
  __shared__ float xz2_s[4][32][8];
  __shared__ float xa2_s[4][32][4];
  __shared__ float xdbl2_s[4][32][33];
  __shared__ float dt2_s[4][32][4];
  __shared__ float ym2_s[4][32][4];
  int t = threadIdx.x;
  if (t < 128) {
    float s = 0.f;
    for (int k = 0; k < 64; ++k) s += focp[(size_t)t * 64 + k];
    foc_s[t] = s * (1.f / 4096.f);
  }
  __syncthreads();
  for (int i = t; i < 1024; i += 256) {
    int j = i & 7, l = (i >> 3) & 31, b = i >> 8;
    float x0 = foc_s[b * 32 + l], x1 = foc_s[b * 32 + 31 - l];
    xz2_s[b][l][j] = x0 * Win2[j * 2] + x1 * Win2[j * 2 + 1];
  }
  __syncthreads();
  for (int i = t; i < 512; i += 256) {
    int d = i & 3, l = (i >> 2) & 31, b = i >> 7;
    float acc = convb2[d];
#pragma unroll
    for (int k = 0; k < 4; ++k) {
      int ls = l + k - 3;
      if (ls >= 0) acc = fmaf(convw2[d * 4 + k], xz2_s[b][ls][d], acc);
    }
    xa2_s[b][l][d] = siluf(acc);
  }
  __syncthreads();
  for (int i = t; i < 4224; i += 256) {
    int r = i % 33, l = (i / 33) & 31, b = i / 1056;
    float s = 0.f;
#pragma unroll
    for (int d = 0; d < 4; ++d) s = fmaf(xa2_s[b][l][d], Wx2[r * 4 + d], s);
    xdbl2_s[b][l][r] = s;
  }
  __syncthreads();
  for (int i = t; i < 512; i += 256) {
    int d = i & 3, l = (i >> 2) & 31, b = i >> 7;
    float s = xdbl2_s[b][l][0] * Wdt2[d] + dtb2[d];
    dt2_s[b][l][d] = softplusf(s);
  }
  __syncthreads();
  {
    int n = t & 15, d = (t >> 4) & 3, b = t >> 6;
    float A = -__expf(Alog2[d * 16 + n]);
    float h = 0.f;
    for (int l = 0; l < 32; ++l) {
      float dtv = dt2_s[b][l][d];
      float xav = xa2_s[b][l][d];
      float e = __expf(dtv * A);
      h = fmaf(e, h, dtv * xdbl2_s[b][l][1 + n] * xav);
      float yp = h * xdbl2_s[b][l][17 + n];
      yp += __shfl_xor(yp, 1);
      yp += __shfl_xor(yp, 2);
      yp += __shfl_xor(yp, 4);
      yp += __shfl_xor(yp, 8);
      if (n == 0) {
        float z = xz2_s[b][l][4 + d];
        float y = yp + D2[d] * xav;
        ym2_s[b][l][d] = y * siluf(z);
      }
    }
  }
  __syncthreads();
  if (t < 128) {
    int l = t & 31, b = t >> 5;
    float s = 0.f;
#pragma unroll
    for (int d = 0; d < 4; ++d) s = fmaf(ym2_s[b][l][d], Wout2[d] + Wout2[4 + d], s);
    scale[t] = s;
  }
}

// ---------------- final: out = res * (1 + scale[b,c]) ----------------
__global__ __launch_bounds__(256) void k_final(const float* __restrict__ res,
                                               const float* __restrict__ scale,
                                               float* __restrict__ out) {
  int idx = blockIdx.x * 256 + threadIdx.x;
  out[idx] = res[idx] * (1.f + scale[idx >> 12]);
}

extern "C" void kernel_launch(void* const* d_in, const int* in_sizes, int n_in,
                              void* d_out, int out_size, void* d_ws, size_t ws_size,
                              hipStream_t stream) {
  const float* fo1    = (const float*)d_in[0];
  const float* fo2    = (const float*)d_in[1];
  const float* Win    = (const float*)d_in[2];
  const float* convw  = (const float*)d_in[3];
  const float* convb  = (const float*)d_in[4];
  const float* Wx     = (const float*)d_in[5];
  const float* Wdt    = (const float*)d_in[6];
  const float* dtb    = (const float*)d_in[7];
  const float* Alog   = (const float*)d_in[8];
  const float* Dp     = (const float*)d_in[9];
  const float* Wout   = (const float*)d_in[10];
  const float* Win2   = (const float*)d_in[11];
  const float* convw2 = (const float*)d_in[12];
  const float* convb2 = (const float*)d_in[13];
  const float* Wx2    = (const float*)d_in[14];
  const float* Wdt2   = (const float*)d_in[15];
  const float* dtb2   = (const float*)d_in[16];
  const float* Alog2  = (const float*)d_in[17];
  const float* D2     = (const float*)d_in[18];
  const float* Wout2  = (const float*)d_in[19];

  float* ws = (float*)d_ws;
  unsigned short* fopb = (unsigned short*)ws;   // 2M bf16 (dead after gemm1)
  float* xdbl = ws;                             // alias: 655,360 floats, written by k_front
  float* xz   = ws + 1048576;                   // 8,388,608
  float* Pb   = ws + 9437184;                   // 2,097,152  [ch][16384]
  float* Qb   = ws + 11534336;                  // 2,097,152
  float* Hin  = ws + 13631488;                  // 2,097,152
  unsigned short* ym = (unsigned short*)(ws + 15728640);  // 4,194,304 bf16 (2M float-slots)
  float* res  = ws + 17825792;                  //   524,288
  float* focp = ws + 18350080;                  //     8,192  [128][64]
  float* scl  = ws + 18358272;                  //       128
  if (ws_size < (size_t)18358400 * sizeof(float)) return;  // ~73 MB scratch

  hipLaunchKernelGGL(k_build_fop, dim3(8192), dim3(256), 0, stream, fo1, fopb);
  hipLaunchKernelGGL(k_gemm1_mfma, dim3(128, 8), dim3(256), 0, stream, fopb, Win, xz);
  hipLaunchKernelGGL(k_front, dim3(512), dim3(256), 0, stream,
                     xz, convw, convb, Wx, Wdt, dtb, Alog, xdbl, Pb, Qb);
  hipLaunchKernelGGL(k_scan_p2, dim3(64), dim3(256), 0, stream, Pb, Qb, Hin);
  hipLaunchKernelGGL(k_scan_p3, dim3(512), dim3(256), 0, stream,
                     xz, convw, convb, xdbl, Wdt, dtb, Alog, Hin, Dp, ym);
  hipLaunchKernelGGL(k_gemm3res, dim3(256), dim3(256), 0, stream, ym, Wout, fo2, res, focp);
  hipLaunchKernelGGL(k_mamba2, dim3(1), dim3(256), 0, stream, focp, Win2, convw2, convb2,
                     Wx2, Wdt2, dtb2, Alog2, D2, Wout2, scl);
  hipLaunchKernelGGL(k_final, dim3(2048), dim3(256), 0, stream, res, scl, (float*)d_out);
}

// Round 7
// 140.473 us; speedup vs baseline: 1.5813x; 1.0443x over previous
//
#include <hip/hip_runtime.h>
#include <cstddef>

// (B,C,H,W)=(4,32,64,64), D_STATE=16, D_CONV=4
// Mamba1: L=4096, d_model=128, d_in=256, dt_rank=8, xdbl width 40
// Round 7: round-5 front (separate conv/gemm2/p1, scan v4) + round-6 back half
//          (bf16 ym, MFMA gemm3 fused with residual/foc partials).

typedef __attribute__((ext_vector_type(8))) short short8v;
typedef __attribute__((ext_vector_type(4))) float f32x4;

__device__ __forceinline__ float siluf(float x) { return x / (1.f + __expf(-x)); }
__device__ __forceinline__ float softplusf(float x) { return (x > 20.f) ? x : log1pf(__expf(x)); }
__device__ __forceinline__ unsigned short f2bf(float f) {
  union { float f; unsigned int u; } v; v.f = f;
  unsigned int r = v.u + 0x7fff + ((v.u >> 16) & 1);
  return (unsigned short)(r >> 16);
}

// ---------------- K0: build fop (B, L, 128) bf16 from fo1 (B,C,H,W) ----------------
__global__ __launch_bounds__(256) void k_build_fop(const float* __restrict__ fo1,
                                                   unsigned short* __restrict__ fopb) {
  int idx = blockIdx.x * 256 + threadIdx.x;   // 2^21
  int j = idx & 127;
  int l = (idx >> 7) & 4095;
  int b = idx >> 19;
  int g = j >> 5, c = j & 31;
  const float* base = fo1 + (size_t)(b * 32 + c) * 4096;
  int li;
  if (g == 0)      li = l;
  else if (g == 1) li = 4095 - l;
  else if (g == 2) li = ((l & 63) << 6) + (l >> 6);
  else { int i2 = 4095 - l; li = ((i2 & 63) << 6) + (i2 >> 6); }
  fopb[idx] = f2bf(base[li]);
}

// ---------------- GEMM1: xz[16384][512] = fopb @ Win^T (bf16 MFMA) ----------------
__global__ __launch_bounds__(256) void k_gemm1_mfma(const unsigned short* __restrict__ A,
                                                    const float* __restrict__ Win,
                                                    float* __restrict__ C) {
  __shared__ unsigned short As[128][136];
  __shared__ unsigned short Bs[64][136];
  int t = threadIdx.x;
  int bm = blockIdx.x * 128, bn = blockIdx.y * 64;
#pragma unroll
  for (int it = 0; it < 8; ++it) {
    int idx = t + it * 256;
    int r = idx >> 4, kc = idx & 15;
    short8v v = *(const short8v*)&A[(size_t)(bm + r) * 128 + kc * 8];
    *(short8v*)&As[r][kc * 8] = v;
  }
#pragma unroll
  for (int it = 0; it < 8; ++it) {
    int idx = t + it * 256;
    int r = idx >> 5, kq = idx & 31;
    float4 w = *(const float4*)&Win[(size_t)(bn + r) * 128 + kq * 4];
    ushort4 h;
    h.x = f2bf(w.x); h.y = f2bf(w.y); h.z = f2bf(w.z); h.w = f2bf(w.w);
    *(ushort4*)&Bs[r][kq * 4] = h;
  }
  __syncthreads();
  int lane = t & 63, w = t >> 6;
  int wm = (w & 1) * 64, wn = (w >> 1) * 32;
  int lr = lane & 15, lg = lane >> 4;
  f32x4 acc[4][2] = {};
#pragma unroll
  for (int k0 = 0; k0 < 128; k0 += 32) {
    short8v a[4], b[2];
#pragma unroll
    for (int mf = 0; mf < 4; ++mf)
      a[mf] = *(const short8v*)&As[wm + mf * 16 + lr][k0 + lg * 8];
#pragma unroll
    for (int nf = 0; nf < 2; ++nf)
      b[nf] = *(const short8v*)&Bs[wn + nf * 16 + lr][k0 + lg * 8];
#pragma unroll
    for (int mf = 0; mf < 4; ++mf)
#pragma unroll
      for (int nf = 0; nf < 2; ++nf)
        acc[mf][nf] = __builtin_amdgcn_mfma_f32_16x16x32_bf16(a[mf], b[nf], acc[mf][nf], 0, 0, 0);
  }
#pragma unroll
  for (int mf = 0; mf < 4; ++mf)
#pragma unroll
    for (int nf = 0; nf < 2; ++nf)
#pragma unroll
      for (int r = 0; r < 4; ++r) {
        size_t row = bm + wm + mf * 16 + lg * 4 + r;
        C[row * 512 + bn + wn + nf * 16 + lr] = acc[mf][nf][r];
      }
}

// ---------------- generic fp32 GEMM (GEMM2) ----------------
__global__ __launch_bounds__(256) void k_gemm_nt(const float* __restrict__ A,
                                                 const float* __restrict__ W,
                                                 float* __restrict__ C,
                                                 int M, int N, int K, int lda) {
  __shared__ float As[32][68];
  __shared__ float Ws[32][68];
  int tid = threadIdx.x;
  int bm = blockIdx.x * 64;
  int bn = blockIdx.y * 64;
  int tx = tid & 15, ty = tid >> 4;
  float acc[4][4] = {};
  for (int k0 = 0; k0 < K; k0 += 32) {
#pragma unroll
    for (int it = 0; it < 2; ++it) {
      int idx = tid + it * 256;
      int r = idx >> 3;
      int kq = idx & 7;
      float4 v = *(const float4*)&A[(size_t)(bm + r) * lda + k0 + kq * 4];
      As[kq * 4 + 0][r] = v.x; As[kq * 4 + 1][r] = v.y;
      As[kq * 4 + 2][r] = v.z; As[kq * 4 + 3][r] = v.w;
      int n = bn + r;
      float4 w = make_float4(0.f, 0.f, 0.f, 0.f);
      if (n < N) w = *(const float4*)&W[(size_t)n * K + k0 + kq * 4];
      Ws[kq * 4 + 0][r] = w.x; Ws[kq * 4 + 1][r] = w.y;
      Ws[kq * 4 + 2][r] = w.z; Ws[kq * 4 + 3][r] = w.w;
    }
    __syncthreads();
#pragma unroll
    for (int k = 0; k < 32; ++k) {
      float4 a = *(const float4*)&As[k][ty * 4];
      float4 w = *(const float4*)&Ws[k][tx * 4];
      float av[4] = {a.x, a.y, a.z, a.w};
      float wv[4] = {w.x, w.y, w.z, w.w};
#pragma unroll
      for (int i = 0; i < 4; ++i)
#pragma unroll
        for (int j = 0; j < 4; ++j)
          acc[i][j] = fmaf(av[i], wv[j], acc[i][j]);
    }
    __syncthreads();
  }
#pragma unroll
  for (int i = 0; i < 4; ++i) {
    size_t m = bm + ty * 4 + i;
#pragma unroll
    for (int j = 0; j < 4; ++j) {
      int n = bn + tx * 4 + j;
      if (n < N) C[m * N + n] = acc[i][j];
    }
  }
}

// ---------------- conv K=4 causal + silu -> xa ----------------
__global__ __launch_bounds__(256) void k_conv_silu(const float* __restrict__ xz,
                                                   const float* __restrict__ convw,
                                                   const float* __restrict__ convb,
                                                   float* __restrict__ xa) {
  int row = blockIdx.x;
  int l = row & 4095;
  int d = threadIdx.x;
  float4 w = *(const float4*)&convw[d * 4];
  float acc = convb[d];
  const float* p = xz + (size_t)row * 512 + d;
  if (l >= 3) acc = fmaf(w.x, p[-3 * 512], acc);
  if (l >= 2) acc = fmaf(w.y, p[-2 * 512], acc);
  if (l >= 1) acc = fmaf(w.z, p[-1 * 512], acc);
  acc = fmaf(w.w, p[0], acc);
  xa[(size_t)row * 256 + d] = siluf(acc);
}

// ---------------- scan phase 1 (v4): one thread per d, 16 n in regs ----------------
// grid = 4b * 128ch = 512 blocks; Pb/Qb layout [ch][b*4096 + d*16 + n]
__global__ __launch_bounds__(256) void k_scan_p1(const float* __restrict__ xa,
                                                 const float* __restrict__ xdbl,
                                                 const float* __restrict__ Wdt,
                                                 const float* __restrict__ dtb,
                                                 const float* __restrict__ Alog,
                                                 float* __restrict__ Pb,
                                                 float* __restrict__ Qb) {
  __shared__ f32x4 xrow[32][10];     // xdbl rows: dt(8) | B(16) | C(16)
  __shared__ float xas[32][256];
  int t = threadIdx.x;
  int blk = blockIdx.x;
  int ch = blk & 127, b = blk >> 7;
  size_t row0 = (size_t)b * 4096 + ch * 32;
  for (int i = t; i < 320; i += 256) {
    int s = i / 10, q = i - s * 10;
    xrow[s][q] = *(const f32x4*)&xdbl[(row0 + s) * 40 + q * 4];
  }
#pragma unroll
  for (int it = 0; it < 8; ++it) {
    int i = t + it * 256;
    int s = i >> 6, q = i & 63;
    *(f32x4*)&xas[s][q * 4] = *(const f32x4*)&xa[(row0 + s) * 256 + q * 4];
  }
  __syncthreads();
  int d = t;
  f32x4 w0 = *(const f32x4*)&Wdt[d * 8];
  f32x4 w1 = *(const f32x4*)&Wdt[d * 8 + 4];
  float bias = dtb[d];
  float A[16], P[16], Q[16];
#pragma unroll
  for (int g = 0; g < 4; ++g) {
    f32x4 al = *(const f32x4*)&Alog[d * 16 + g * 4];
#pragma unroll
    for (int j = 0; j < 4; ++j) {
      A[g * 4 + j] = -__expf(al[j]);
      P[g * 4 + j] = 1.f;
      Q[g * 4 + j] = 0.f;
    }
  }
#pragma unroll 2
  for (int s = 0; s < 32; ++s) {
    f32x4 x0 = xrow[s][0], x1 = xrow[s][1];
    float v = bias;
#pragma unroll
    for (int j = 0; j < 4; ++j) v = fmaf(x0[j], w0[j], v);
#pragma unroll
    for (int j = 0; j < 4; ++j) v = fmaf(x1[j], w1[j], v);
    float ex = __expf(v);
    float dtv = (v > 20.f) ? v : __logf(1.f + ex);
    float du = dtv * xas[s][d];
    f32x4 bm[4];
#pragma unroll
    for (int g = 0; g < 4; ++g) bm[g] = xrow[s][2 + g];
#pragma unroll
    for (int n = 0; n < 16; ++n) {
      float e = __expf(dtv * A[n]);
      Q[n] = fmaf(e, Q[n], du * bm[n >> 2][n & 3]);
      P[n] *= e;
    }
  }
  size_t ob = (size_t)ch * 16384 + b * 4096 + d * 16;
#pragma unroll
  for (int g = 0; g < 4; ++g) {
    *(f32x4*)&Pb[ob + g * 4] = *(f32x4*)&P[g * 4];
    *(f32x4*)&Qb[ob + g * 4] = *(f32x4*)&Q[g * 4];
  }
}

// ---------------- scan phase 2: serial combine, 1 thread per (b,d,n) ----------------
__global__ __launch_bounds__(256) void k_scan_p2(const float* __restrict__ Pb,
                                                 const float* __restrict__ Qb,
                                                 float* __restrict__ Hin) {
  int t = blockIdx.x * 256 + threadIdx.x;   // 16384
  float h = 0.f;
  size_t o = t;
#pragma unroll 8
  for (int ch = 0; ch < 128; ++ch) {
    Hin[o] = h;
    h = fmaf(Pb[o], h, Qb[o]);
    o += 16384;
  }
}

// ---------------- scan phase 3 (v4): recompute; ym written bf16 ----------------
__global__ __launch_bounds__(256) void k_scan_p3(const float* __restrict__ xa,
                                                 const float* __restrict__ xdbl,
                                                 const float* __restrict__ Wdt,
                                                 const float* __restrict__ dtb,
                                                 const float* __restrict__ Alog,
                                                 const float* __restrict__ Hin,
                                                 const float* __restrict__ Dp,
                                                 const float* __restrict__ xz,
                                                 unsigned short* __restrict__ ym) {
  __shared__ f32x4 xrow[32][10];
  __shared__ float xas[32][256];
  int t = threadIdx.x;
  int blk = blockIdx.x;
  int ch = blk & 127, b = blk >> 7;
  size_t row0 = (size_t)b * 4096 + ch * 32;
  for (int i = t; i < 320; i += 256) {
    int s = i / 10, q = i - s * 10;
    xrow[s][q] = *(const f32x4*)&xdbl[(row0 + s) * 40 + q * 4];
  }
#pragma unroll
  for (int it = 0; it < 8; ++it) {
    int i = t + it * 256;
    int s = i >> 6, q = i & 63;
    *(f32x4*)&xas[s][q * 4] = *(const f32x4*)&xa[(row0 + s) * 256 + q * 4];
  }
  __syncthreads();
  int d = t;
  f32x4 w0 = *(const f32x4*)&Wdt[d * 8];
  f32x4 w1 = *(const f32x4*)&Wdt[d * 8 + 4];
  float bias = dtb[d];
  float Dd = Dp[d];
  float A[16], h[16];
  size_t hb = (size_t)ch * 16384 + b * 4096 + d * 16;
#pragma unroll
  for (int g = 0; g < 4; ++g) {
    f32x4 al = *(const f32x4*)&Alog[d * 16 + g * 4];
    f32x4 hv = *(const f32x4*)&Hin[hb + g * 4];
#pragma unroll
    for (int j = 0; j < 4; ++j) {
      A[g * 4 + j] = -__expf(al[j]);
      h[g * 4 + j] = hv[j];
    }
  }
  const float* zp = xz + row0 * 512 + 256 + d;
  unsigned short* yo = ym + row0 * 256 + d;
#pragma unroll 2
  for (int s = 0; s < 32; ++s) {
    f32x4 x0 = xrow[s][0], x1 = xrow[s][1];
    float v = bias;
#pragma unroll
    for (int j = 0; j < 4; ++j) v = fmaf(x0[j], w0[j], v);
#pragma unroll
    for (int j = 0; j < 4; ++j) v = fmaf(x1[j], w1[j], v);
    float ex = __expf(v);
    float dtv = (v > 20.f) ? v : __logf(1.f + ex);
    float xav = xas[s][d];
    float du = dtv * xav;
    f32x4 bm[4], cm[4];
#pragma unroll
    for (int g = 0; g < 4; ++g) { bm[g] = xrow[s][2 + g]; cm[g] = xrow[s][6 + g]; }
    float y0 = 0.f, y1 = 0.f, y2 = 0.f, y3 = 0.f;
#pragma unroll
    for (int n = 0; n < 16; n += 4) {
      float e0 = __expf(dtv * A[n]);
      float e1 = __expf(dtv * A[n + 1]);
      float e2 = __expf(dtv * A[n + 2]);
      float e3 = __expf(dtv * A[n + 3]);
      f32x4 bv = bm[n >> 2], cv = cm[n >> 2];
      h[n]     = fmaf(e0, h[n],     du * bv[0]);
      h[n + 1] = fmaf(e1, h[n + 1], du * bv[1]);
      h[n + 2] = fmaf(e2, h[n + 2], du * bv[2]);
      h[n + 3] = fmaf(e3, h[n + 3], du * bv[3]);
      y0 = fmaf(h[n], cv[0], y0);
      y1 = fmaf(h[n + 1], cv[1], y1);
      y2 = fmaf(h[n + 2], cv[2], y2);
      y3 = fmaf(h[n + 3], cv[3], y3);
    }
    float y = (y0 + y1) + (y2 + y3) + Dd * xav;
    float z = zp[s * 512];
    yo[s * 256] = f2bf(y * siluf(z));
  }
}

// ---------------- gemm3+residual+foc: MFMA bf16, WoutEff fused, res & foc partials ----------------
// grid 256 (m-tiles of 64); block 256 = 4 waves, wave tile 16M x 32N
__global__ __launch_bounds__(256) void k_gemm3res(const unsigned short* __restrict__ ym,
                                                  const float* __restrict__ Wout,
                                                  const float* __restrict__ fo2,
                                                  float* __restrict__ res,
                                                  float* __restrict__ focp) {
  __shared__ unsigned short As[64][264];
  __shared__ unsigned short Bs[32][264];
  __shared__ float fred[4][32];
  int t = threadIdx.x;
  int bm = blockIdx.x * 64;
#pragma unroll
  for (int it = 0; it < 8; ++it) {
    int idx = t + it * 256;
    int r = idx >> 5, kc = idx & 31;
    *(short8v*)&As[r][kc * 8] = *(const short8v*)&ym[(size_t)(bm + r) * 256 + kc * 8];
  }
#pragma unroll
  for (int it = 0; it < 32; ++it) {
    int idx = t + it * 256;
    int n = idx >> 8, k = idx & 255;
    float wv = Wout[(size_t)n * 256 + k] + Wout[(size_t)(n + 32) * 256 + k] +
               Wout[(size_t)(n + 64) * 256 + k] + Wout[(size_t)(n + 96) * 256 + k];
    Bs[n][k] = f2bf(wv);
  }
  __syncthreads();
  int lane = t & 63, w = t >> 6;
  int lr = lane & 15, lg = lane >> 4;
  f32x4 acc0 = {}, acc1 = {};
#pragma unroll
  for (int k0 = 0; k0 < 256; k0 += 32) {
    short8v a  = *(const short8v*)&As[w * 16 + lr][k0 + lg * 8];
    short8v b0 = *(const short8v*)&Bs[lr][k0 + lg * 8];
    short8v b1 = *(const short8v*)&Bs[16 + lr][k0 + lg * 8];
    acc0 = __builtin_amdgcn_mfma_f32_16x16x32_bf16(a, b0, acc0, 0, 0, 0);
    acc1 = __builtin_amdgcn_mfma_f32_16x16x32_bf16(a, b1, acc1, 0, 0, 0);
  }
  int b = bm >> 12;
  float ps0 = 0.f, ps1 = 0.f;
#pragma unroll
  for (int r = 0; r < 4; ++r) {
    int l = (bm + w * 16 + lg * 4 + r) & 4095;
    size_t ri0 = ((size_t)(b * 32 + lr)) * 4096 + l;
    size_t ri1 = ((size_t)(b * 32 + 16 + lr)) * 4096 + l;
    float v0 = acc0[r] * fo2[ri0];
    float v1 = acc1[r] * fo2[ri1];
    res[ri0] = v0; ps0 += v0;
    res[ri1] = v1; ps1 += v1;
  }
  ps0 += __shfl_xor(ps0, 16); ps0 += __shfl_xor(ps0, 32);
  ps1 += __shfl_xor(ps1, 16); ps1 += __shfl_xor(ps1, 32);
  if (lane < 16) { fred[w][lane] = ps0; fred[w][16 + lane] = ps1; }
  __syncthreads();
  if (t < 32)
    focp[((size_t)(b * 32 + t)) * 64 + (blockIdx.x & 63)] =
        fred[0][t] + fred[1][t] + fred[2][t] + fred[3][t];
}

// ---------------- mamba2 (tiny): one block; foc = sum(focp)/4096 ----------------
__global__ __launch_bounds__(256) void k_mamba2(const float* __restrict__ focp,
                                                const float* __restrict__ Win2,
                                                const float* __restrict__ convw2,
                                                const float* __restrict__ convb2,
                                                const float* __restrict__ Wx2,
                                                const float* __restrict__ Wdt2,
                                                const float* __restrict__ dtb2,
                                                const float* __restrict__ Alog2,
                                                const float* __restrict__ D2,
                                                const float* __restrict__ Wout2,
                                                float* __restrict__ scale) {
  __shared__ float foc_s[128];
  __shared__ float xz2_s[4][32][8];
  __shared__ float xa2_s[4][32][4];
  __shared__ float xdbl2_s[4][32][33];
  __shared__ float dt2_s[4][32][4];
  __shared__ float ym2_s[4][32][4];
  int t = threadIdx.x;
  if (t < 128) {
    float s = 0.f;
    for (int k = 0; k < 64; ++k) s += focp[(size_t)t * 64 + k];
    foc_s[t] = s * (1.f / 4096.f);
  }
  __syncthreads();
  for (int i = t; i < 1024; i += 256) {
    int j = i & 7, l = (i >> 3) & 31, b = i >> 8;
    float x0 = foc_s[b * 32 + l], x1 = foc_s[b * 32 + 31 - l];
    xz2_s[b][l][j] = x0 * Win2[j * 2] + x1 * Win2[j * 2 + 1];
  }
  __syncthreads();
  for (int i = t; i < 512; i += 256) {
    int d = i & 3, l = (i >> 2) & 31, b = i >> 7;
    float acc = convb2[d];
#pragma unroll
    for (int k = 0; k < 4; ++k) {
      int ls = l + k - 3;
      if (ls >= 0) acc = fmaf(convw2[d * 4 + k], xz2_s[b][ls][d], acc);
    }
    xa2_s[b][l][d] = siluf(acc);
  }
  __syncthreads();
  for (int i = t; i < 4224; i += 256) {
    int r = i % 33, l = (i / 33) & 31, b = i / 1056;
    float s = 0.f;
#pragma unroll
    for (int d = 0; d < 4; ++d) s = fmaf(xa2_s[b][l][d], Wx2[r * 4 + d], s);
    xdbl2_s[b][l][r] = s;
  }
  __syncthreads();
  for (int i = t; i < 512; i += 256) {
    int d = i & 3, l = (i >> 2) & 31, b = i >> 7;
    float s = xdbl2_s[b][l][0] * Wdt2[d] + dtb2[d];
    dt2_s[b][l][d] = softplusf(s);
  }
  __syncthreads();
  {
    int n = t & 15, d = (t >> 4) & 3, b = t >> 6;
    float A = -__expf(Alog2[d * 16 + n]);
    float h = 0.f;
    for (int l = 0; l < 32; ++l) {
      float dtv = dt2_s[b][l][d];
      float xav = xa2_s[b][l][d];
      float e = __expf(dtv * A);
      h = fmaf(e, h, dtv * xdbl2_s[b][l][1 + n] * xav);
      float yp = h * xdbl2_s[b][l][17 + n];
      yp += __shfl_xor(yp, 1);
      yp += __shfl_xor(yp, 2);
      yp += __shfl_xor(yp, 4);
      yp += __shfl_xor(yp, 8);
      if (n == 0) {
        float z = xz2_s[b][l][4 + d];
        float y = yp + D2[d] * xav;
        ym2_s[b][l][d] = y * siluf(z);
      }
    }
  }
  __syncthreads();
  if (t < 128) {
    int l = t & 31, b = t >> 5;
    float s = 0.f;
#pragma unroll
    for (int d = 0; d < 4; ++d) s = fmaf(ym2_s[b][l][d], Wout2[d] + Wout2[4 + d], s);
    scale[t] = s;
  }
}

// ---------------- final: out = res * (1 + scale[b,c]) ----------------
__global__ __launch_bounds__(256) void k_final(const float* __restrict__ res,
                                               const float* __restrict__ scale,
                                               float* __restrict__ out) {
  int idx = blockIdx.x * 256 + threadIdx.x;
  out[idx] = res[idx] * (1.f + scale[idx >> 12]);
}

extern "C" void kernel_launch(void* const* d_in, const int* in_sizes, int n_in,
                              void* d_out, int out_size, void* d_ws, size_t ws_size,
                              hipStream_t stream) {
  const float* fo1    = (const float*)d_in[0];
  const float* fo2    = (const float*)d_in[1];
  const float* Win    = (const float*)d_in[2];
  const float* convw  = (const float*)d_in[3];
  const float* convb  = (const float*)d_in[4];
  const float* Wx     = (const float*)d_in[5];
  const float* Wdt    = (const float*)d_in[6];
  const float* dtb    = (const float*)d_in[7];
  const float* Alog   = (const float*)d_in[8];
  const float* Dp     = (const float*)d_in[9];
  const float* Wout   = (const float*)d_in[10];
  const float* Win2   = (const float*)d_in[11];
  const float* convw2 = (const float*)d_in[12];
  const float* convb2 = (const float*)d_in[13];
  const float* Wx2    = (const float*)d_in[14];
  const float* Wdt2   = (const float*)d_in[15];
  const float* dtb2   = (const float*)d_in[16];
  const float* Alog2  = (const float*)d_in[17];
  const float* D2     = (const float*)d_in[18];
  const float* Wout2  = (const float*)d_in[19];

  float* ws = (float*)d_ws;
  unsigned short* fopb = (unsigned short*)ws;   // 2M bf16 (dead after gemm1)
  float* xdbl = ws;                             // alias: 655,360 floats (gemm2 out)
  float* xz   = ws + 1048576;                   // 8,388,608
  float* xa   = ws + 9437184;                   // 4,194,304
  float* Pb   = ws + 13631488;                  // 2,097,152  [ch][16384]
  float* Qb   = ws + 15728640;                  // 2,097,152
  float* Hin  = ws + 17825792;                  // 2,097,152
  unsigned short* ym = (unsigned short*)(ws + 19922944);  // 4M bf16 (2M float-slots)
  float* res  = ws + 22020096;                  //   524,288
  float* focp = ws + 22544384;                  //     8,192  [128][64]
  float* scl  = ws + 22552576;                  //       128
  if (ws_size < (size_t)22552704 * sizeof(float)) return;  // ~90 MB scratch

  hipLaunchKernelGGL(k_build_fop, dim3(8192), dim3(256), 0, stream, fo1, fopb);
  hipLaunchKernelGGL(k_gemm1_mfma, dim3(128, 8), dim3(256), 0, stream, fopb, Win, xz);
  hipLaunchKernelGGL(k_conv_silu, dim3(16384), dim3(256), 0, stream, xz, convw, convb, xa);
  hipLaunchKernelGGL(k_gemm_nt, dim3(256, 1), dim3(256), 0, stream,
                     xa, Wx, xdbl, 16384, 40, 256, 256);
  hipLaunchKernelGGL(k_scan_p1, dim3(512), dim3(256), 0, stream,
                     xa, xdbl, Wdt, dtb, Alog, Pb, Qb);
  hipLaunchKernelGGL(k_scan_p2, dim3(64), dim3(256), 0, stream, Pb, Qb, Hin);
  hipLaunchKernelGGL(k_scan_p3, dim3(512), dim3(256), 0, stream,
                     xa, xdbl, Wdt, dtb, Alog, Hin, Dp, xz, ym);
  hipLaunchKernelGGL(k_gemm3res, dim3(256), dim3(256), 0, stream, ym, Wout, fo2, res, focp);
  hipLaunchKernelGGL(k_mamba2, dim3(1), dim3(256), 0, stream, focp, Win2, convw2, convb2,
                     Wx2, Wdt2, dtb2, Alog2, D2, Wout2, scl);
  hipLaunchKernelGGL(k_final, dim3(2048), dim3(256), 0, stream, res, scl, (float*)d_out);
}

// Round 9
// 138.837 us; speedup vs baseline: 1.5999x; 1.0118x over previous
//
#include <hip/hip_runtime.h>
#include <cstddef>

// (B,C,H,W)=(4,32,64,64), D_STATE=16, D_CONV=4
// Mamba1: L=4096, d_model=128, d_in=256, dt_rank=8, xdbl width 40
// Round 9: round-7 launch structure + xz split (bf16 xc | fp32 z).

typedef __attribute__((ext_vector_type(8))) short short8v;
typedef __attribute__((ext_vector_type(4))) float f32x4;

__device__ __forceinline__ float siluf(float x) { return x / (1.f + __expf(-x)); }
__device__ __forceinline__ float softplusf(float x) { return (x > 20.f) ? x : log1pf(__expf(x)); }
__device__ __forceinline__ unsigned short f2bf(float f) {
  union { float f; unsigned int u; } v; v.f = f;
  unsigned int r = v.u + 0x7fff + ((v.u >> 16) & 1);
  return (unsigned short)(r >> 16);
}
__device__ __forceinline__ float bf2f(unsigned short u) {
  union { unsigned int i; float f; } v; v.i = ((unsigned int)u) << 16; return v.f;
}

// ---------------- K0: build fop (B, L, 128) bf16 from fo1 (B,C,H,W) ----------------
__global__ __launch_bounds__(256) void k_build_fop(const float* __restrict__ fo1,
                                                   unsigned short* __restrict__ fopb) {
  int idx = blockIdx.x * 256 + threadIdx.x;   // 2^21
  int j = idx & 127;
  int l = (idx >> 7) & 4095;
  int b = idx >> 19;
  int g = j >> 5, c = j & 31;
  const float* base = fo1 + (size_t)(b * 32 + c) * 4096;
  int li;
  if (g == 0)      li = l;
  else if (g == 1) li = 4095 - l;
  else if (g == 2) li = ((l & 63) << 6) + (l >> 6);
  else { int i2 = 4095 - l; li = ((i2 & 63) << 6) + (i2 >> 6); }
  fopb[idx] = f2bf(base[li]);
}

// ---------------- GEMM1: fopb @ Win^T (bf16 MFMA) -> xcb (bf16) | zbuf (fp32) ------
__global__ __launch_bounds__(256) void k_gemm1_mfma(const unsigned short* __restrict__ A,
                                                    const float* __restrict__ Win,
                                                    unsigned short* __restrict__ xcb,
                                                    float* __restrict__ zbuf) {
  __shared__ unsigned short As[128][136];
  __shared__ unsigned short Bs[64][136];
  int t = threadIdx.x;
  int bm = blockIdx.x * 128, bn = blockIdx.y * 64;
#pragma unroll
  for (int it = 0; it < 8; ++it) {
    int idx = t + it * 256;
    int r = idx >> 4, kc = idx & 15;
    short8v v = *(const short8v*)&A[(size_t)(bm + r) * 128 + kc * 8];
    *(short8v*)&As[r][kc * 8] = v;
  }
#pragma unroll
  for (int it = 0; it < 8; ++it) {
    int idx = t + it * 256;
    int r = idx >> 5, kq = idx & 31;
    float4 w = *(const float4*)&Win[(size_t)(bn + r) * 128 + kq * 4];
    ushort4 h;
    h.x = f2bf(w.x); h.y = f2bf(w.y); h.z = f2bf(w.z); h.w = f2bf(w.w);
    *(ushort4*)&Bs[r][kq * 4] = h;
  }
  __syncthreads();
  int lane = t & 63, w = t >> 6;
  int wm = (w & 1) * 64, wn = (w >> 1) * 32;
  int lr = lane & 15, lg = lane >> 4;
  f32x4 acc[4][2] = {};
#pragma unroll
  for (int k0 = 0; k0 < 128; k0 += 32) {
    short8v a[4], b[2];
#pragma unroll
    for (int mf = 0; mf < 4; ++mf)
      a[mf] = *(const short8v*)&As[wm + mf * 16 + lr][k0 + lg * 8];
#pragma unroll
    for (int nf = 0; nf < 2; ++nf)
      b[nf] = *(const short8v*)&Bs[wn + nf * 16 + lr][k0 + lg * 8];
#pragma unroll
    for (int mf = 0; mf < 4; ++mf)
#pragma unroll
      for (int nf = 0; nf < 2; ++nf)
        acc[mf][nf] = __builtin_amdgcn_mfma_f32_16x16x32_bf16(a[mf], b[nf], acc[mf][nf], 0, 0, 0);
  }
  if (bn < 256) {
#pragma unroll
    for (int mf = 0; mf < 4; ++mf)
#pragma unroll
      for (int nf = 0; nf < 2; ++nf)
#pragma unroll
        for (int r = 0; r < 4; ++r) {
          size_t row = bm + wm + mf * 16 + lg * 4 + r;
          xcb[row * 256 + bn + wn + nf * 16 + lr] = f2bf(acc[mf][nf][r]);
        }
  } else {
#pragma unroll
    for (int mf = 0; mf < 4; ++mf)
#pragma unroll
      for (int nf = 0; nf < 2; ++nf)
#pragma unroll
        for (int r = 0; r < 4; ++r) {
          size_t row = bm + wm + mf * 16 + lg * 4 + r;
          zbuf[row * 256 + (bn - 256) + wn + nf * 16 + lr] = acc[mf][nf][r];
        }
  }
}

// ---------------- generic fp32 GEMM (GEMM2) ----------------
__global__ __launch_bounds__(256) void k_gemm_nt(const float* __restrict__ A,
                                                 const float* __restrict__ W,
                                                 float* __restrict__ C,
                                                 int M, int N, int K, int lda) {
  __shared__ float As[32][68];
  __shared__ float Ws[32][68];
  int tid = threadIdx.x;
  int bm = blockIdx.x * 64;
  int bn = blockIdx.y * 64;
  int tx = tid & 15, ty = tid >> 4;
  float acc[4][4] = {};
  for (int k0 = 0; k0 < K; k0 += 32) {
#pragma unroll
    for (int it = 0; it < 2; ++it) {
      int idx = tid + it * 256;
      int r = idx >> 3;
      int kq = idx & 7;
      float4 v = *(const float4*)&A[(size_t)(bm + r) * lda + k0 + kq * 4];
      As[kq * 4 + 0][r] = v.x; As[kq * 4 + 1][r] = v.y;
      As[kq * 4 + 2][r] = v.z; As[kq * 4 + 3][r] = v.w;
      int n = bn + r;
      float4 w = make_float4(0.f, 0.f, 0.f, 0.f);
      if (n < N) w = *(const float4*)&W[(size_t)n * K + k0 + kq * 4];
      Ws[kq * 4 + 0][r] = w.x; Ws[kq * 4 + 1][r] = w.y;
      Ws[kq * 4 + 2][r] = w.z; Ws[kq * 4 + 3][r] = w.w;
    }
    __syncthreads();
#pragma unroll
    for (int k = 0; k < 32; ++k) {
      float4 a = *(const float4*)&As[k][ty * 4];
      float4 w = *(const float4*)&Ws[k][tx * 4];
      float av[4] = {a.x, a.y, a.z, a.w};
      float wv[4] = {w.x, w.y, w.z, w.w};
#pragma unroll
      for (int i = 0; i < 4; ++i)
#pragma unroll
        for (int j = 0; j < 4; ++j)
          acc[i][j] = fmaf(av[i], wv[j], acc[i][j]);
    }
    __syncthreads();
  }
#pragma unroll
  for (int i = 0; i < 4; ++i) {
    size_t m = bm + ty * 4 + i;
#pragma unroll
    for (int j = 0; j < 4; ++j) {
      int n = bn + tx * 4 + j;
      if (n < N) C[m * N + n] = acc[i][j];
    }
  }
}

// ---------------- conv K=4 causal + silu -> xa (reads bf16 xc) ----------------
__global__ __launch_bounds__(256) void k_conv_silu(const unsigned short* __restrict__ xcb,
                                                   const float* __restrict__ convw,
                                                   const float* __restrict__ convb,
                                                   float* __restrict__ xa) {
  int row = blockIdx.x;
  int l = row & 4095;
  int d = threadIdx.x;
  float4 w = *(const float4*)&convw[d * 4];
  float acc = convb[d];
  const unsigned short* p = xcb + (size_t)row * 256 + d;
  if (l >= 3) acc = fmaf(w.x, bf2f(p[-3 * 256]), acc);
  if (l >= 2) acc = fmaf(w.y, bf2f(p[-2 * 256]), acc);
  if (l >= 1) acc = fmaf(w.z, bf2f(p[-1 * 256]), acc);
  acc = fmaf(w.w, bf2f(p[0]), acc);
  xa[(size_t)row * 256 + d] = siluf(acc);
}

// ---------------- scan phase 1 (v4): one thread per d, 16 n in regs ----------------
// grid = 4b * 128ch = 512 blocks; Pb/Qb layout [ch][b*4096 + d*16 + n]
__global__ __launch_bounds__(256) void k_scan_p1(const float* __restrict__ xa,
                                                 const float* __restrict__ xdbl,
                                                 const float* __restrict__ Wdt,
                                                 const float* __restrict__ dtb,
                                                 const float* __restrict__ Alog,
                                                 float* __restrict__ Pb,
                                                 float* __restrict__ Qb) {
  __shared__ f32x4 xrow[32][10];     // xdbl rows: dt(8) | B(16) | C(16)
  __shared__ float xas[32][256];
  int t = threadIdx.x;
  int blk = blockIdx.x;
  int ch = blk & 127, b = blk >> 7;
  size_t row0 = (size_t)b * 4096 + ch * 32;
  for (int i = t; i < 320; i += 256) {
    int s = i / 10, q = i - s * 10;
    xrow[s][q] = *(const f32x4*)&xdbl[(row0 + s) * 40 + q * 4];
  }
#pragma unroll
  for (int it = 0; it < 8; ++it) {
    int i = t + it * 256;
    int s = i >> 6, q = i & 63;
    *(f32x4*)&xas[s][q * 4] = *(const f32x4*)&xa[(row0 + s) * 256 + q * 4];
  }
  __syncthreads();
  int d = t;
  f32x4 w0 = *(const f32x4*)&Wdt[d * 8];
  f32x4 w1 = *(const f32x4*)&Wdt[d * 8 + 4];
  float bias = dtb[d];
  float A[16], P[16], Q[16];
#pragma unroll
  for (int g = 0; g < 4; ++g) {
    f32x4 al = *(const f32x4*)&Alog[d * 16 + g * 4];
#pragma unroll
    for (int j = 0; j < 4; ++j) {
      A[g * 4 + j] = -__expf(al[j]);
      P[g * 4 + j] = 1.f;
      Q[g * 4 + j] = 0.f;
    }
  }
#pragma unroll 2
  for (int s = 0; s < 32; ++s) {
    f32x4 x0 = xrow[s][0], x1 = xrow[s][1];
    float v = bias;
#pragma unroll
    for (int j = 0; j < 4; ++j) v = fmaf(x0[j], w0[j], v);
#pragma unroll
    for (int j = 0; j < 4; ++j) v = fmaf(x1[j], w1[j], v);
    float ex = __expf(v);
    float dtv = (v > 20.f) ? v : __logf(1.f + ex);
    float du = dtv * xas[s][d];
    f32x4 bm[4];
#pragma unroll
    for (int g = 0; g < 4; ++g) bm[g] = xrow[s][2 + g];
#pragma unroll
    for (int n = 0; n < 16; ++n) {
      float e = __expf(dtv * A[n]);
      Q[n] = fmaf(e, Q[n], du * bm[n >> 2][n & 3]);
      P[n] *= e;
    }
  }
  size_t ob = (size_t)ch * 16384 + b * 4096 + d * 16;
#pragma unroll
  for (int g = 0; g < 4; ++g) {
    *(f32x4*)&Pb[ob + g * 4] = *(f32x4*)&P[g * 4];
    *(f32x4*)&Qb[ob + g * 4] = *(f32x4*)&Q[g * 4];
  }
}

// ---------------- scan phase 2: serial combine, 1 thread per (b,d,n) ----------------
__global__ __launch_bounds__(256) void k_scan_p2(const float* __restrict__ Pb,
                                                 const float* __restrict__ Qb,
                                                 float* __restrict__ Hin) {
  int t = blockIdx.x * 256 + threadIdx.x;   // 16384
  float h = 0.f;
  size_t o = t;
#pragma unroll 8
  for (int ch = 0; ch < 128; ++ch) {
    Hin[o] = h;
    h = fmaf(Pb[o], h, Qb[o]);
    o += 16384;
  }
}

// ---------------- scan phase 3 (v4): recompute; z from zbuf; ym bf16 ----------------
__global__ __launch_bounds__(256) void k_scan_p3(const float* __restrict__ xa,
                                                 const float* __restrict__ xdbl,
                                                 const float* __restrict__ Wdt,
                                                 const float* __restrict__ dtb,
                                                 const float* __restrict__ Alog,
                                                 const float* __restrict__ Hin,
                                                 const float* __restrict__ Dp,
                                                 const float* __restrict__ zbuf,
                                                 unsigned short* __restrict__ ym) {
  __shared__ f32x4 xrow[32][10];
  __shared__ float xas[32][256];
  int t = threadIdx.x;
  int blk = blockIdx.x;
  int ch = blk & 127, b = blk >> 7;
  size_t row0 = (size_t)b * 4096 + ch * 32;
  for (int i = t; i < 320; i += 256) {
    int s = i / 10, q = i - s * 10;
    xrow[s][q] = *(const f32x4*)&xdbl[(row0 + s) * 40 + q * 4];
  }
#pragma unroll
  for (int it = 0; it < 8; ++it) {
    int i = t + it * 256;
    int s = i >> 6, q = i & 63;
    *(f32x4*)&xas[s][q * 4] = *(const f32x4*)&xa[(row0 + s) * 256 + q * 4];
  }
  __syncthreads();
  int d = t;
  f32x4 w0 = *(const f32x4*)&Wdt[d * 8];
  f32x4 w1 = *(const f32x4*)&Wdt[d * 8 + 4];
  float bias = dtb[d];
  float Dd = Dp[d];
  float A[16], h[16];
  size_t hb = (size_t)ch * 16384 + b * 4096 + d * 16;
#pragma unroll
  for (int g = 0; g < 4; ++g) {
    f32x4 al = *(const f32x4*)&Alog[d * 16 + g * 4];
    f32x4 hv = *(const f32x4*)&Hin[hb + g * 4];
#pragma unroll
    for (int j = 0; j < 4; ++j) {
      A[g * 4 + j] = -__expf(al[j]);
      h[g * 4 + j] = hv[j];
    }
  }
  const float* zp = zbuf + row0 * 256 + d;
  unsigned short* yo = ym + row0 * 256 + d;
#pragma unroll 2
  for (int s = 0; s < 32; ++s) {
    f32x4 x0 = xrow[s][0], x1 = xrow[s][1];
    float v = bias;
#pragma unroll
    for (int j = 0; j < 4; ++j) v = fmaf(x0[j], w0[j], v);
#pragma unroll
    for (int j = 0; j < 4; ++j) v = fmaf(x1[j], w1[j], v);
    float ex = __expf(v);
    float dtv = (v > 20.f) ? v : __logf(1.f + ex);
    float xav = xas[s][d];
    float du = dtv * xav;
    f32x4 bm[4], cm[4];
#pragma unroll
    for (int g = 0; g < 4; ++g) { bm[g] = xrow[s][2 + g]; cm[g] = xrow[s][6 + g]; }
    float y0 = 0.f, y1 = 0.f, y2 = 0.f, y3 = 0.f;
#pragma unroll
    for (int n = 0; n < 16; n += 4) {
      float e0 = __expf(dtv * A[n]);
      float e1 = __expf(dtv * A[n + 1]);
      float e2 = __expf(dtv * A[n + 2]);
      float e3 = __expf(dtv * A[n + 3]);
      f32x4 bv = bm[n >> 2], cv = cm[n >> 2];
      h[n]     = fmaf(e0, h[n],     du * bv[0]);
      h[n + 1] = fmaf(e1, h[n + 1], du * bv[1]);
      h[n + 2] = fmaf(e2, h[n + 2], du * bv[2]);
      h[n + 3] = fmaf(e3, h[n + 3], du * bv[3]);
      y0 = fmaf(h[n], cv[0], y0);
      y1 = fmaf(h[n + 1], cv[1], y1);
      y2 = fmaf(h[n + 2], cv[2], y2);
      y3 = fmaf(h[n + 3], cv[3], y3);
    }
    float y = (y0 + y1) + (y2 + y3) + Dd * xav;
    float z = zp[s * 256];
    yo[s * 256] = f2bf(y * siluf(z));
  }
}

// ---------------- gemm3+residual+foc: MFMA bf16, WoutEff fused ----------------
__global__ __launch_bounds__(256) void k_gemm3res(const unsigned short* __restrict__ ym,
                                                  const float* __restrict__ Wout,
                                                  const float* __restrict__ fo2,
                                                  float* __restrict__ res,
                                                  float* __restrict__ focp) {
  __shared__ unsigned short As[64][264];
  __shared__ unsigned short Bs[32][264];
  __shared__ float fred[4][32];
  int t = threadIdx.x;
  int bm = blockIdx.x * 64;
#pragma unroll
  for (int it = 0; it < 8; ++it) {
    int idx = t + it * 256;
    int r = idx >> 5, kc = idx & 31;
    *(short8v*)&As[r][kc * 8] = *(const short8v*)&ym[(size_t)(bm + r) * 256 + kc * 8];
  }
#pragma unroll
  for (int it = 0; it < 32; ++it) {
    int idx = t + it * 256;
    int n = idx >> 8, k = idx & 255;
    float wv = Wout[(size_t)n * 256 + k] + Wout[(size_t)(n + 32) * 256 + k] +
               Wout[(size_t)(n + 64) * 256 + k] + Wout[(size_t)(n + 96) * 256 + k];
    Bs[n][k] = f2bf(wv);
  }
  __syncthreads();
  int lane = t & 63, w = t >> 6;
  int lr = lane & 15, lg = lane >> 4;
  f32x4 acc0 = {}, acc1 = {};
#pragma unroll
  for (int k0 = 0; k0 < 256; k0 += 32) {
    short8v a  = *(const short8v*)&As[w * 16 + lr][k0 + lg * 8];
    short8v b0 = *(const short8v*)&Bs[lr][k0 + lg * 8];
    short8v b1 = *(const short8v*)&Bs[16 + lr][k0 + lg * 8];
    acc0 = __builtin_amdgcn_mfma_f32_16x16x32_bf16(a, b0, acc0, 0, 0, 0);
    acc1 = __builtin_amdgcn_mfma_f32_16x16x32_bf16(a, b1, acc1, 0, 0, 0);
  }
  int b = bm >> 12;
  float ps0 = 0.f, ps1 = 0.f;
#pragma unroll
  for (int r = 0; r < 4; ++r) {
    int l = (bm + w * 16 + lg * 4 + r) & 4095;
    size_t ri0 = ((size_t)(b * 32 + lr)) * 4096 + l;
    size_t ri1 = ((size_t)(b * 32 + 16 + lr)) * 4096 + l;
    float v0 = acc0[r] * fo2[ri0];
    float v1 = acc1[r] * fo2[ri1];
    res[ri0] = v0; ps0 += v0;
    res[ri1] = v1; ps1 += v1;
  }
  ps0 += __shfl_xor(ps0, 16); ps0 += __shfl_xor(ps0, 32);
  ps1 += __shfl_xor(ps1, 16); ps1 += __shfl_xor(ps1, 32);
  if (lane < 16) { fred[w][lane] = ps0; fred[w][16 + lane] = ps1; }
  __syncthreads();
  if (t < 32)
    focp[((size_t)(b * 32 + t)) * 64 + (blockIdx.x & 63)] =
        fred[0][t] + fred[1][t] + fred[2][t] + fred[3][t];
}

// ---------------- mamba2 (tiny): one block; foc = sum(focp)/4096 ----------------
__global__ __launch_bounds__(256) void k_mamba2(const float* __restrict__ focp,
                                                const float* __restrict__ Win2,
                                                const float* __restrict__ convw2,
                                                const float* __restrict__ convb2,
                                                const float* __restrict__ Wx2,
                                                const float* __restrict__ Wdt2,
                                                const float* __restrict__ dtb2,
                                                const float* __restrict__ Alog2,
                                                const float* __restrict__ D2,
                                                const float* __restrict__ Wout2,
                                                float* __restrict__ scale) {
  __shared__ float foc_s[128];
  __shared__ float xz2_s[4][32][8];
  __shared__ float xa2_s[4][32][4];
  __shared__ float xdbl2_s[4][32][33];
  __shared__ float dt2_s[4][32][4];
  __shared__ float ym2_s[4][32][4];
  int t = threadIdx.x;
  if (t < 128) {
    float s = 0.f;
    for (int k = 0; k < 64; ++k) s += focp[(size_t)t * 64 + k];
    foc_s[t] = s * (1.f / 4096.f);
  }
  __syncthreads();
  for (int i = t; i < 1024; i += 256) {
    int j = i & 7, l = (i >> 3) & 31, b = i >> 8;
    float x0 = foc_s[b * 32 + l], x1 = foc_s[b * 32 + 31 - l];
    xz2_s[b][l][j] = x0 * Win2[j * 2] + x1 * Win2[j * 2 + 1];
  }
  __syncthreads();
  for (int i = t; i < 512; i += 256) {
    int d = i & 3, l = (i >> 2) & 31, b = i >> 7;
    float acc = convb2[d];
#pragma unroll
    for (int k = 0; k < 4; ++k) {
      int ls = l + k - 3;
      if (ls >= 0) acc = fmaf(convw2[d * 4 + k], xz2_s[b][ls][d], acc);
    }
    xa2_s[b][l][d] = siluf(acc);
  }
  __syncthreads();
  for (int i = t; i < 4224; i += 256) {
    int r = i % 33, l = (i / 33) & 31, b = i / 1056;
    float s = 0.f;
#pragma unroll
    for (int d = 0; d < 4; ++d) s = fmaf(xa2_s[b][l][d], Wx2[r * 4 + d], s);
    xdbl2_s[b][l][r] = s;
  }
  __syncthreads();
  for (int i = t; i < 512; i += 256) {
    int d = i & 3, l = (i >> 2) & 31, b = i >> 7;
    float s = xdbl2_s[b][l][0] * Wdt2[d] + dtb2[d];
    dt2_s[b][l][d] = softplusf(s);
  }
  __syncthreads();
  {
    int n = t & 15, d = (t >> 4) & 3, b = t >> 6;
    float A = -__expf(Alog2[d * 16 + n]);
    float h = 0.f;
    for (int l = 0; l < 32; ++l) {
      float dtv = dt2_s[b][l][d];
      float xav = xa2_s[b][l][d];
      float e = __expf(dtv * A);
      h = fmaf(e, h, dtv * xdbl2_s[b][l][1 + n] * xav);
      float yp = h * xdbl2_s[b][l][17 + n];
      yp += __shfl_xor(yp, 1);
      yp += __shfl_xor(yp, 2);
      yp += __shfl_xor(yp, 4);
      yp += __shfl_xor(yp, 8);
      if (n == 0) {
        float z = xz2_s[b][l][4 + d];
        float y = yp + D2[d] * xav;
        ym2_s[b][l][d] = y * siluf(z);
      }
    }
  }
  __syncthreads();
  if (t < 128) {
    int l = t & 31, b = t >> 5;
    float s = 0.f;
#pragma unroll
    for (int d = 0; d < 4; ++d) s = fmaf(ym2_s[b][l][d], Wout2[d] + Wout2[4 + d], s);
    scale[t] = s;
  }
}

// ---------------- final: out = res * (1 + scale[b,c]) ----------------
__global__ __launch_bounds__(256) void k_final(const float* __restrict__ res,
                                               const float* __restrict__ scale,
                                               float* __restrict__ out) {
  int idx = blockIdx.x * 256 + threadIdx.x;
  out[idx] = res[idx] * (1.f + scale[idx >> 12]);
}

extern "C" void kernel_launch(void* const* d_in, const int* in_sizes, int n_in,
                              void* d_out, int out_size, void* d_ws, size_t ws_size,
                              hipStream_t stream) {
  const float* fo1    = (const float*)d_in[0];
  const float* fo2    = (const float*)d_in[1];
  const float* Win    = (const float*)d_in[2];
  const float* convw  = (const float*)d_in[3];
  const float* convb  = (const float*)d_in[4];
  const float* Wx     = (const float*)d_in[5];
  const float* Wdt    = (const float*)d_in[6];
  const float* dtb    = (const float*)d_in[7];
  const float* Alog   = (const float*)d_in[8];
  const float* Dp     = (const float*)d_in[9];
  const float* Wout   = (const float*)d_in[10];
  const float* Win2   = (const float*)d_in[11];
  const float* convw2 = (const float*)d_in[12];
  const float* convb2 = (const float*)d_in[13];
  const float* Wx2    = (const float*)d_in[14];
  const float* Wdt2   = (const float*)d_in[15];
  const float* dtb2   = (const float*)d_in[16];
  const float* Alog2  = (const float*)d_in[17];
  const float* D2     = (const float*)d_in[18];
  const float* Wout2  = (const float*)d_in[19];

  float* ws = (float*)d_ws;
  unsigned short* fopb = (unsigned short*)ws;     // 2M bf16 (dead after gemm1)
  float* xdbl = ws;                               // alias: 655,360 floats (gemm2 out)
  unsigned short* xcb = (unsigned short*)(ws + 1048576);  // 4,194,304 bf16
  float* zbuf = ws + 3145728;                     // 4,194,304
  float* xa   = ws + 7340032;                     // 4,194,304
  float* Pb   = ws + 11534336;                    // 2,097,152  [ch][16384]
  float* Qb   = ws + 13631488;                    // 2,097,152
  float* Hin  = ws + 15728640;                    // 2,097,152
  unsigned short* ym = (unsigned short*)(ws + 17825792);  // 4,194,304 bf16
  float* res  = ws + 19922944;                    //   524,288
  float* focp = ws + 20447232;                    //     8,192  [128][64]
  float* scl  = ws + 20455424;                    //       128
  if (ws_size < (size_t)20455552 * sizeof(float)) return;  // ~82 MB scratch

  hipLaunchKernelGGL(k_build_fop, dim3(8192), dim3(256), 0, stream, fo1, fopb);
  hipLaunchKernelGGL(k_gemm1_mfma, dim3(128, 8), dim3(256), 0, stream, fopb, Win, xcb, zbuf);
  hipLaunchKernelGGL(k_conv_silu, dim3(16384), dim3(256), 0, stream, xcb, convw, convb, xa);
  hipLaunchKernelGGL(k_gemm_nt, dim3(256, 1), dim3(256), 0, stream,
                     xa, Wx, xdbl, 16384, 40, 256, 256);
  hipLaunchKernelGGL(k_scan_p1, dim3(512), dim3(256), 0, stream,
                     xa, xdbl, Wdt, dtb, Alog, Pb, Qb);
  hipLaunchKernelGGL(k_scan_p2, dim3(64), dim3(256), 0, stream, Pb, Qb, Hin);
  hipLaunchKernelGGL(k_scan_p3, dim3(512), dim3(256), 0, stream,
                     xa, xdbl, Wdt, dtb, Alog, Hin, Dp, zbuf, ym);
  hipLaunchKernelGGL(k_gemm3res, dim3(256), dim3(256), 0, stream, ym, Wout, fo2, res, focp);
  hipLaunchKernelGGL(k_mamba2, dim3(1), dim3(256), 0, stream, focp, Win2, convw2, convb2,
                     Wx2, Wdt2, dtb2, Alog2, D2, Wout2, scl);
  hipLaunchKernelGGL(k_final, dim3(2048), dim3(256), 0, stream, res, scl, (float*)d_out);
}